// Round 1
// baseline (1642.496 us; speedup 1.0000x reference)
//
#include <hip/hip_runtime.h>
#include <hip/hip_bf16.h>

// Problem constants (match reference)
#define TB   128          // batch B
#define NN   512          // nodes per graph
#define INC  128          // IN_C
#define HH   32           // HID
#define KP1  100          // K1
#define KP2  10           // K2
#define OC   10           // OUT_C
#define EPER 8192         // edges per graph
#define NT   (TB*NN)      // 65536 total nodes
#define ET   (TB*EPER)    // 1048576 total edges
#define ZS   236          // gram Z tile stride (100 t + 32 h + 100 s + 4 pad)

// ---------------------------------------------------------------- init
__global__ void k_init(float* __restrict__ deg, float* __restrict__ odeg, float* __restrict__ aux) {
    int i = blockIdx.x * 256 + threadIdx.x;
    if (i < NT) { deg[i] = 1.0f; odeg[i] = 0.0f; }   // deg starts at 1 (self loop)
    if (i < 1024) aux[i] = 0.0f;                      // den1 / loss1 / loss2 accumulators
}

// ------------------------------------------------------- edge degrees
__global__ void k_edeg(const int* __restrict__ ei, float* __restrict__ deg, float* __restrict__ odeg) {
    int e = blockIdx.x * 256 + threadIdx.x;
    if (e < ET) {
        atomicAdd(&deg[ei[ET + e]], 1.0f);   // in-degree on dst (GCN norm)
        atomicAdd(&odeg[ei[e]], 1.0f);       // out-degree on src (= adj.sum(-1))
    }
}

__global__ void k_rsq(float* __restrict__ deg) {
    int i = blockIdx.x * 256 + threadIdx.x;
    if (i < NT) deg[i] = rsqrtf(deg[i]);     // deg >= 1 always
}

// ------------------------------------------------ xw = x @ conv1_W  [NT,32]
__global__ __launch_bounds__(256) void k_xw(const float* __restrict__ x, const float* __restrict__ W,
                                            float* __restrict__ xw) {
    __shared__ float sWT[32][132];           // W^T, padded stride
    int tid = threadIdx.x;
    for (int i = tid; i < INC * HH; i += 256) { int k = i >> 5, c = i & 31; sWT[c][k] = W[i]; }
    __syncthreads();
    int id = blockIdx.x * 256 + tid;
    int row = id >> 5, c = id & 31;
    const float4* xp = (const float4*)(x + (size_t)row * INC);
    float acc = 0.f;
#pragma unroll
    for (int kq = 0; kq < INC / 4; kq++) {
        float4 xv = xp[kq];
        float4 wv = *(const float4*)&sWT[c][kq * 4];
        acc += xv.x * wv.x + xv.y * wv.y + xv.z * wv.z + xv.w * wv.w;
    }
    xw[id] = acc;
}

// ----------------------- GCN aggregate: h = relu(scatter(norm*xw) + b)
__global__ __launch_bounds__(512) void k_gcn(const int* __restrict__ ei,
                                             const float* __restrict__ xw, const float* __restrict__ dis,
                                             const float* __restrict__ bias, float* __restrict__ h) {
    __shared__ float acc[NN * HH];           // 64 KB
    int g = blockIdx.x, goff = g * NN, tid = threadIdx.x;
    for (int i = tid; i < NN * HH; i += 512) {
        int n = i >> 5;
        float d = dis[goff + n];
        acc[i] = d * d * xw[(size_t)goff * HH + i];   // self-loop term
    }
    __syncthreads();
    const int* es = ei + (size_t)g * EPER;
    const int* ed = ei + ET + (size_t)g * EPER;
    int c = tid & 31, slot = tid >> 5;       // 16 edges in flight, 32 channels each
    for (int e = slot; e < EPER; e += 16) {
        int s = es[e], d = ed[e];
        float w = dis[s] * dis[d];
        atomicAdd(&acc[(d - goff) * HH + c], w * xw[(size_t)s * HH + c]);
    }
    __syncthreads();
    for (int i = tid; i < NN * HH; i += 512) {
        float v = acc[i] + bias[i & 31];
        h[(size_t)goff * HH + i] = fmaxf(v, 0.f);
    }
}

// ---------------- s1 = softmax(h @ pool1_W + b) per row; den1 atomics
__global__ __launch_bounds__(128) void k_s1(const float* __restrict__ h, const float* __restrict__ W,
                                            const float* __restrict__ bias, const float* __restrict__ odeg,
                                            float* __restrict__ s1, float* __restrict__ den1) {
    __shared__ float hr[HH];
    __shared__ float red[128], red2[128];
    int row = blockIdx.x, tid = threadIdx.x;
    if (tid < HH) hr[tid] = h[(size_t)row * HH + tid];
    __syncthreads();
    float v = -1e30f;
    if (tid < KP1) {
        float a = bias[tid];
#pragma unroll
        for (int k = 0; k < HH; k++) a = fmaf(hr[k], W[k * KP1 + tid], a);
        v = a;
    }
    red[tid] = v; __syncthreads();
#pragma unroll
    for (int s = 64; s > 0; s >>= 1) { if (tid < s) red[tid] = fmaxf(red[tid], red[tid + s]); __syncthreads(); }
    float m = red[0]; __syncthreads();
    float e = (tid < KP1) ? __expf(v - m) : 0.f;
    red[tid] = e; red2[tid] = e * e; __syncthreads();
#pragma unroll
    for (int s = 64; s > 0; s >>= 1) { if (tid < s) { red[tid] += red[tid + s]; red2[tid] += red2[tid + s]; } __syncthreads(); }
    float inv = 1.f / red[0];
    if (tid < KP1) s1[(size_t)row * KP1 + tid] = e * inv;
    if (tid == 0) atomicAdd(&den1[row >> 9], odeg[row] * red2[0] * inv * inv);
}

// ------------- t1 = adj @ s1 via edge scatter, K chunked by 25 (4 passes)
__global__ __launch_bounds__(512) void k_t1(const int* __restrict__ ei,
                                            const float* __restrict__ s1, float* __restrict__ t1) {
    __shared__ float acc[NN * 25];           // 51.2 KB
    int g = blockIdx.x >> 2, c0 = (blockIdx.x & 3) * 25;
    int goff = g * NN, tid = threadIdx.x;
    for (int i = tid; i < NN * 25; i += 512) acc[i] = 0.f;
    __syncthreads();
    const int* es = ei + (size_t)g * EPER;
    const int* ed = ei + ET + (size_t)g * EPER;
    if (tid < 500) {
        int c = tid % 25, slot = tid / 25;   // 20 edges in flight
        for (int e = slot; e < EPER; e += 20) {
            int s = es[e], d = ed[e];
            atomicAdd(&acc[(s - goff) * 25 + c], s1[(size_t)d * KP1 + c0 + c]);
        }
    }
    __syncthreads();
    for (int i = tid; i < NN * 25; i += 512)
        t1[(size_t)(goff + i / 25) * KP1 + c0 + i % 25] = acc[i];
}

// --- gram: C = s1^T [t1 | h | s1]  (100 x 232) per (graph, n-half) partial
__global__ __launch_bounds__(512) void k_gram(const float* __restrict__ s1, const float* __restrict__ t1,
                                              const float* __restrict__ h, float* __restrict__ Cp) {
    __shared__ float sZ[32 * ZS];            // 30.2 KB
    int g = blockIdx.x >> 1, half = blockIdx.x & 1;
    int n0base = half * 256;
    int goff = g * NN;
    int tid = threadIdx.x;
    int wave = tid >> 6, lane = tid & 63;
    int wr = wave >> 1, wc = wave & 1;       // 4 x 2 wave grid
    int kg = wr * 4 + (lane >> 4);           // 0..15, need <13
    int lg = wc * 16 + (lane & 15);          // 0..31, need <29
    bool act = (kg < 13) && (lg < 29);
    int k0 = kg * 8, l0 = lg * 8;
    float accm[8][8];
#pragma unroll
    for (int i = 0; i < 8; i++)
#pragma unroll
        for (int j = 0; j < 8; j++) accm[i][j] = 0.f;

    for (int nt = 0; nt < 8; nt++) {
        int n0 = n0base + nt * 32;
        for (int i = tid; i < 32 * ZS; i += 512) {
            int r = i / ZS, cc = i % ZS;
            int n = goff + n0 + r;
            float val;
            if (cc < 100)      val = t1[(size_t)n * KP1 + cc];
            else if (cc < 132) val = h[(size_t)n * HH + (cc - 100)];
            else if (cc < 232) val = s1[(size_t)n * KP1 + (cc - 132)];
            else               val = 0.f;
            sZ[r * ZS + cc] = val;
        }
        __syncthreads();
        if (act) {
            for (int r = 0; r < 32; r++) {
                const float* zr = &sZ[r * ZS];
                float4 a0 = *(const float4*)&zr[132 + k0];
                float4 a1 = *(const float4*)&zr[132 + k0 + 4];
                float4 b0 = *(const float4*)&zr[l0];
                float4 b1 = *(const float4*)&zr[l0 + 4];
                float av[8] = {a0.x, a0.y, a0.z, a0.w, a1.x, a1.y, a1.z, a1.w};
                float bv[8] = {b0.x, b0.y, b0.z, b0.w, b1.x, b1.y, b1.z, b1.w};
#pragma unroll
                for (int i = 0; i < 8; i++)
#pragma unroll
                    for (int j = 0; j < 8; j++) accm[i][j] = fmaf(av[i], bv[j], accm[i][j]);
            }
        }
        __syncthreads();
    }
    if (act) {
        float* out = Cp + ((size_t)half * TB + g) * (KP1 * 232);
#pragma unroll
        for (int i = 0; i < 8; i++) {
            int k = k0 + i;
            if (k < KP1) {
#pragma unroll
                for (int j = 0; j < 8; j++) out[k * 232 + l0 + j] = accm[i][j];
            }
        }
    }
}

// ---- finalize stage 1: sum halves, losses, normalize out_adj, emit P1
__global__ __launch_bounds__(128) void k_fin1(const float* __restrict__ Cp, const float* __restrict__ den1,
                                              float* __restrict__ A1n, float* __restrict__ P1,
                                              float* __restrict__ aux) {
    __shared__ float sA[KP1 * KP1];          // 40 KB
    __shared__ float sd[KP1];
    __shared__ float r1[128], r2[128], r3[128];
    int g = blockIdx.x, tid = threadIdx.x;
    const float* c0 = Cp + (size_t)g * (KP1 * 232);
    const float* c1 = Cp + ((size_t)TB + g) * (KP1 * 232);
    float ssq = 0.f, troa = 0.f, trss = 0.f;
    if (tid < KP1) {
        int k = tid;
        float rs = 0.f;
        for (int l = 0; l < KP1; l++) {
            float oa = c0[k * 232 + l] + c1[k * 232 + l];
            sA[k * KP1 + l] = oa;
            if (l != k) rs += oa; else troa += oa;
            float ssv = c0[k * 232 + 132 + l] + c1[k * 232 + 132 + l];
            ssq += ssv * ssv;
            if (l == k) trss += ssv;
        }
        sd[k] = sqrtf(rs) + 1e-15f;
        for (int cc = 0; cc < HH; cc++)
            P1[((size_t)g * KP1 + k) * HH + cc] = c0[k * 232 + 100 + cc] + c1[k * 232 + 100 + cc];
    }
    r1[tid] = ssq; r2[tid] = troa; r3[tid] = trss; __syncthreads();
#pragma unroll
    for (int s = 64; s > 0; s >>= 1) {
        if (tid < s) { r1[tid] += r1[tid + s]; r2[tid] += r2[tid + s]; r3[tid] += r3[tid + s]; }
        __syncthreads();
    }
    if (tid == 0) {
        float ssF = sqrtf(r1[0]);
        float o1 = sqrtf(fmaxf(2.f - 2.f * r3[0] / (ssF * 10.f), 0.f));  // sqrt(K1)=10
        aux[128 + g] = -(r2[0] / den1[g]) + o1;
    }
    __syncthreads();
    for (int i = tid; i < KP1 * KP1; i += 128) {
        int k = i / KP1, l = i % KP1;
        A1n[(size_t)g * (KP1 * KP1) + i] = (k == l) ? 0.f : sA[i] / (sd[k] * sd[l]);
    }
}

// ------- stage 2a: conv2 + pool2 (per graph); A read from global (L2)
__global__ __launch_bounds__(512) void k_s2a(const float* __restrict__ A1n, const float* __restrict__ P1,
                                             const float* __restrict__ relW, const float* __restrict__ relB,
                                             const float* __restrict__ rootW,
                                             const float* __restrict__ p2W, const float* __restrict__ p2B,
                                             float* __restrict__ P2, float* __restrict__ A2n,
                                             float* __restrict__ aux) {
    __shared__ float sX[KP1 * HH];           // x1p then x2
    __shared__ float sY[KP1 * HH];           // y = A @ x1p
    __shared__ float sS2[KP1 * KP2];
    __shared__ float sT2[KP1 * KP2];
    __shared__ float sA2[100], sB2[100], sdd[10], red[100];
    int g = blockIdx.x, tid = threadIdx.x;
    const float* Ag = A1n + (size_t)g * (KP1 * KP1);
    for (int i = tid; i < KP1 * HH; i += 512) sX[i] = P1[(size_t)g * (KP1 * HH) + i];
    __syncthreads();

    int n = tid >> 2, cq = tid & 3;          // 400 active threads for y / x2
    // y = A @ x1p
    if (tid < 400) {
        float yv[8];
#pragma unroll
        for (int j = 0; j < 8; j++) yv[j] = 0.f;
        for (int mq = 0; mq < 25; mq++) {
            float4 a4 = *(const float4*)&Ag[n * KP1 + mq * 4];
            const float* xb = &sX[(mq * 4) * HH + cq * 8];
            float aa[4] = {a4.x, a4.y, a4.z, a4.w};
#pragma unroll
            for (int mm = 0; mm < 4; mm++) {
                const float* xr = xb + mm * HH;
#pragma unroll
                for (int j = 0; j < 8; j++) yv[j] = fmaf(aa[mm], xr[j], yv[j]);
            }
        }
#pragma unroll
        for (int j = 0; j < 8; j++) sY[n * HH + cq * 8 + j] = yv[j];
    }
    __syncthreads();
    // x2 = relu(y @ relW + relB + x1p @ rootW)
    float x2v[8];
    if (tid < 400) {
#pragma unroll
        for (int j = 0; j < 8; j++) x2v[j] = relB[cq * 8 + j];
        for (int j = 0; j < 32; j++) {
            float yj = sY[n * HH + j];
            float xj = sX[n * HH + j];
            float4 r0 = *(const float4*)&relW[j * 32 + cq * 8];
            float4 r1v = *(const float4*)&relW[j * 32 + cq * 8 + 4];
            float4 q0 = *(const float4*)&rootW[j * 32 + cq * 8];
            float4 q1 = *(const float4*)&rootW[j * 32 + cq * 8 + 4];
            x2v[0] += yj * r0.x + xj * q0.x;  x2v[1] += yj * r0.y + xj * q0.y;
            x2v[2] += yj * r0.z + xj * q0.z;  x2v[3] += yj * r0.w + xj * q0.w;
            x2v[4] += yj * r1v.x + xj * q1.x; x2v[5] += yj * r1v.y + xj * q1.y;
            x2v[6] += yj * r1v.z + xj * q1.z; x2v[7] += yj * r1v.w + xj * q1.w;
        }
    }
    __syncthreads();
    if (tid < 400) {
#pragma unroll
        for (int j = 0; j < 8; j++) sX[n * HH + cq * 8 + j] = fmaxf(x2v[j], 0.f);
    }
    __syncthreads();
    // s2 = softmax(x2 @ p2W + p2B); d2 and den2 partials
    if (tid < KP1) {
        float lg[10];
#pragma unroll
        for (int j = 0; j < 10; j++) lg[j] = p2B[j];
        for (int c = 0; c < 32; c++) {
            float xv = sX[tid * HH + c];
#pragma unroll
            for (int j = 0; j < 10; j++) lg[j] = fmaf(xv, p2W[c * 10 + j], lg[j]);
        }
        float mx = lg[0];
#pragma unroll
        for (int j = 1; j < 10; j++) mx = fmaxf(mx, lg[j]);
        float se = 0.f;
#pragma unroll
        for (int j = 0; j < 10; j++) { lg[j] = __expf(lg[j] - mx); se += lg[j]; }
        float inv = 1.f / se, sq = 0.f;
#pragma unroll
        for (int j = 0; j < 10; j++) { float sv = lg[j] * inv; sS2[tid * 10 + j] = sv; sq += sv * sv; }
        float d2 = 0.f;
        for (int mq = 0; mq < 25; mq++) {
            float4 a4 = *(const float4*)&Ag[tid * KP1 + mq * 4];
            d2 += a4.x + a4.y + a4.z + a4.w;
        }
        red[tid] = d2 * sq;
    }
    __syncthreads();
    // t2 = A @ s2 ; P2 = s2^T x2
    for (int p = tid; p < KP1 * KP2; p += 512) {
        int n2 = p / 10, jj = p % 10;
        float a = 0.f;
        for (int m = 0; m < KP1; m++) a = fmaf(Ag[n2 * KP1 + m], sS2[m * 10 + jj], a);
        sT2[p] = a;
    }
    if (tid < KP2 * HH) {
        int k = tid >> 5, cc = tid & 31;
        float a = 0.f;
        for (int n2 = 0; n2 < KP1; n2++) a = fmaf(sS2[n2 * 10 + k], sX[n2 * HH + cc], a);
        P2[(size_t)g * (KP2 * HH) + tid] = a;
    }
    __syncthreads();
    // oa2, ss2
    if (tid < 100) {
        int k = tid / 10, l = tid % 10;
        float oa = 0.f, ss = 0.f;
        for (int n2 = 0; n2 < KP1; n2++) {
            float sk = sS2[n2 * 10 + k];
            oa = fmaf(sk, sT2[n2 * 10 + l], oa);
            ss = fmaf(sk, sS2[n2 * 10 + l], ss);
        }
        sA2[tid] = oa; sB2[tid] = ss;
    }
    __syncthreads();
    if (tid == 0) {
        float den2 = 0.f;
        for (int i = 0; i < 100; i++) den2 += red[i];
        float troa = 0.f, trss = 0.f, ssq = 0.f;
        for (int k = 0; k < 10; k++) { troa += sA2[k * 10 + k]; trss += sB2[k * 10 + k]; }
        for (int i = 0; i < 100; i++) ssq += sB2[i] * sB2[i];
        float o2 = sqrtf(fmaxf(2.f - 2.f * trss / (sqrtf(ssq) * 3.16227766f), 0.f)); // sqrt(10)
        aux[256 + g] = -(troa / den2) + o2;
    }
    if (tid < 10) {
        float rs = 0.f;
        for (int l = 0; l < 10; l++) if (l != tid) rs += sA2[tid * 10 + l];
        sdd[tid] = sqrtf(rs) + 1e-15f;
    }
    __syncthreads();
    if (tid < 100) {
        int k = tid / 10, l = tid % 10;
        A2n[(size_t)g * 100 + tid] = (k == l) ? 0.f : sA2[tid] / (sdd[k] * sdd[l]);
    }
}

// ---------------- stage 2b: conv3 + mean + MLP head + log_softmax
__global__ __launch_bounds__(64) void k_s2b(const float* __restrict__ P2, const float* __restrict__ A2n,
                                            const float* __restrict__ relW3, const float* __restrict__ relb3,
                                            const float* __restrict__ rootW3,
                                            const float* __restrict__ l1W, const float* __restrict__ l1b,
                                            const float* __restrict__ l2W, const float* __restrict__ l2b,
                                            float* __restrict__ out) {
    __shared__ float sP[KP2 * HH], sA2[100], sY3[KP2 * HH], sG[32], sG1[32], sL[10], sLse;
    int g = blockIdx.x, tid = threadIdx.x;
    for (int i = tid; i < KP2 * HH; i += 64) sP[i] = P2[(size_t)g * (KP2 * HH) + i];
    for (int i = tid; i < 100; i += 64) sA2[i] = A2n[(size_t)g * 100 + i];
    if (tid < 32) sG[tid] = 0.f;
    __syncthreads();
    for (int p = tid; p < KP2 * HH; p += 64) {
        int k = p >> 5, cc = p & 31;
        float a = 0.f;
#pragma unroll
        for (int m = 0; m < 10; m++) a = fmaf(sA2[k * 10 + m], sP[m * HH + cc], a);
        sY3[p] = a;
    }
    __syncthreads();
    for (int p = tid; p < KP2 * HH; p += 64) {
        int k = p >> 5, cc = p & 31;
        float v = relb3[cc];
        for (int j = 0; j < 32; j++)
            v += sY3[k * HH + j] * relW3[j * 32 + cc] + sP[k * HH + j] * rootW3[j * 32 + cc];
        atomicAdd(&sG[cc], v * 0.1f);        // mean over 10 nodes
    }
    __syncthreads();
    if (tid < 32) {
        float v = l1b[tid];
        for (int j = 0; j < 32; j++) v = fmaf(sG[j], l1W[j * 32 + tid], v);
        sG1[tid] = fmaxf(v, 0.f);
    }
    __syncthreads();
    if (tid < 10) {
        float v = l2b[tid];
        for (int j = 0; j < 32; j++) v = fmaf(sG1[j], l2W[j * 10 + tid], v);
        sL[tid] = v;
    }
    __syncthreads();
    if (tid == 0) {
        float mx = sL[0];
        for (int j = 1; j < 10; j++) mx = fmaxf(mx, sL[j]);
        float se = 0.f;
        for (int j = 0; j < 10; j++) se += expf(sL[j] - mx);
        sLse = mx + logf(se);
    }
    __syncthreads();
    if (tid < 10) out[(size_t)g * 10 + tid] = sL[tid] - sLse;
}

// ------------------------------------------------------ total loss
__global__ void k_loss(const float* __restrict__ aux, float* __restrict__ out) {
    __shared__ float red[128];
    int tid = threadIdx.x;
    red[tid] = aux[128 + tid] + aux[256 + tid];
    __syncthreads();
#pragma unroll
    for (int s = 64; s > 0; s >>= 1) { if (tid < s) red[tid] += red[tid + s]; __syncthreads(); }
    if (tid == 0) out[1280] = red[0] * (1.f / 128.f);
}

extern "C" void kernel_launch(void* const* d_in, const int* in_sizes, int n_in,
                              void* d_out, int out_size, void* d_ws, size_t ws_size,
                              hipStream_t stream) {
    const float* x    = (const float*)d_in[0];
    const int*   ei   = (const int*)d_in[1];
    const float* c1W  = (const float*)d_in[3];
    const float* c1b  = (const float*)d_in[4];
    const float* p1W  = (const float*)d_in[5];
    const float* p1b  = (const float*)d_in[6];
    const float* relW2  = (const float*)d_in[7];
    const float* relb2  = (const float*)d_in[8];
    const float* rootW2 = (const float*)d_in[9];
    const float* p2W  = (const float*)d_in[10];
    const float* p2b  = (const float*)d_in[11];
    const float* relW3  = (const float*)d_in[12];
    const float* relb3  = (const float*)d_in[13];
    const float* rootW3 = (const float*)d_in[14];
    const float* l1W  = (const float*)d_in[15];
    const float* l1b  = (const float*)d_in[16];
    const float* l2W  = (const float*)d_in[17];
    const float* l2b  = (const float*)d_in[18];
    float* out = (float*)d_out;

    float* ws  = (float*)d_ws;
    float* deg  = ws;                                 // NT
    float* odeg = deg + NT;                           // NT
    float* xw   = odeg + NT;                          // NT*HH
    float* h    = xw + (size_t)NT * HH;               // NT*HH
    float* s1   = h + (size_t)NT * HH;                // NT*KP1
    float* t1   = s1 + (size_t)NT * KP1;              // NT*KP1
    float* Cp   = t1 + (size_t)NT * KP1;              // 2*TB*KP1*232
    float* A1n  = Cp + (size_t)2 * TB * (KP1 * 232);  // TB*KP1*KP1
    float* P1   = A1n + (size_t)TB * KP1 * KP1;       // TB*KP1*HH
    float* P2   = P1 + (size_t)TB * KP1 * HH;         // TB*KP2*HH
    float* A2n  = P2 + (size_t)TB * KP2 * HH;         // TB*100
    float* aux  = A2n + (size_t)TB * 100;             // 1024: den1|loss1|loss2

    k_init<<<NT / 256, 256, 0, stream>>>(deg, odeg, aux);
    k_edeg<<<ET / 256, 256, 0, stream>>>(ei, deg, odeg);
    k_rsq<<<NT / 256, 256, 0, stream>>>(deg);
    k_xw<<<(NT * HH) / 256, 256, 0, stream>>>(x, c1W, xw);
    k_gcn<<<TB, 512, 0, stream>>>(ei, xw, deg, c1b, h);
    k_s1<<<NT, 128, 0, stream>>>(h, p1W, p1b, odeg, s1, aux /*den1*/);
    k_t1<<<TB * 4, 512, 0, stream>>>(ei, s1, t1);
    k_gram<<<TB * 2, 512, 0, stream>>>(s1, t1, h, Cp);
    k_fin1<<<TB, 128, 0, stream>>>(Cp, aux /*den1*/, A1n, P1, aux);
    k_s2a<<<TB, 512, 0, stream>>>(A1n, P1, relW2, relb2, rootW2, p2W, p2b, P2, A2n, aux);
    k_s2b<<<TB, 64, 0, stream>>>(P2, A2n, relW3, relb3, rootW3, l1W, l1b, l2W, l2b, out);
    k_loss<<<1, 128, 0, stream>>>(aux, out);
}

// Round 2
// 984.595 us; speedup vs baseline: 1.6682x; 1.6682x over previous
//
#include <hip/hip_runtime.h>
#include <hip/hip_bf16.h>

// Problem constants (match reference)
#define TB   128          // batch B
#define NN   512          // nodes per graph
#define INC  128          // IN_C
#define HH   32           // HID
#define KP1  100          // K1
#define KP2  10           // K2
#define OC   10           // OUT_C
#define EPER 8192         // edges per graph
#define NT   (TB*NN)      // 65536 total nodes
#define ET   (TB*EPER)    // 1048576 total edges
#define ZS   236          // gram Z tile stride (100 t + 32 h + 100 s + 4 pad)

// ---------------------------------------------------------------- init
__global__ void k_init(int* __restrict__ cs, int* __restrict__ cd, float* __restrict__ aux) {
    int i = blockIdx.x * 256 + threadIdx.x;
    if (i < NT) { cs[i] = 0; cd[i] = 0; }
    if (i < 1024) aux[i] = 0.0f;              // den1 / loss1 / loss2 accumulators
}

// ---------------------------------------------- edge degree histograms
__global__ void k_cnt(const int* __restrict__ ei, int* __restrict__ cs, int* __restrict__ cd) {
    int e = blockIdx.x * 256 + threadIdx.x;
    if (e < ET) {
        atomicAdd(&cs[ei[e]], 1);             // out-degree (src)  = adj.sum(-1)
        atomicAdd(&cd[ei[ET + e]], 1);        // in-degree  (dst)  for GCN norm
    }
}

// ---------------- per-graph exclusive scan of both degree histograms
__global__ __launch_bounds__(512) void k_scan(const int* __restrict__ cs, const int* __restrict__ cd,
                                              int* __restrict__ os, int* __restrict__ od,
                                              int* __restrict__ curs, int* __restrict__ curd) {
    __shared__ int sa[512], sb[512];
    int g = blockIdx.x, tid = threadIdx.x, i = g * NN + tid;
    int vs = cs[i], vd = cd[i];
    sa[tid] = vs; sb[tid] = vd; __syncthreads();
    for (int off = 1; off < 512; off <<= 1) {
        int xa = sa[tid], xb = sb[tid];
        if (tid >= off) { xa += sa[tid - off]; xb += sb[tid - off]; }
        __syncthreads(); sa[tid] = xa; sb[tid] = xb; __syncthreads();
    }
    int es = g * EPER + sa[tid] - vs;         // exclusive scan, global position
    int ed = g * EPER + sb[tid] - vd;
    os[i] = es; od[i] = ed; curs[i] = es; curd[i] = ed;
}

// ----------------- counting-sort scatter: edges by src and by dst
__global__ void k_scatter(const int* __restrict__ ei, int* __restrict__ curs, int* __restrict__ curd,
                          int* __restrict__ sdst, int* __restrict__ ssrc) {
    int e = blockIdx.x * 256 + threadIdx.x;
    if (e < ET) {
        int s = ei[e], d = ei[ET + e];
        int p = atomicAdd(&curs[s], 1); sdst[p] = d;   // src-sorted: store dst
        int q = atomicAdd(&curd[d], 1); ssrc[q] = s;   // dst-sorted: store src
    }
}

__global__ void k_dis(const int* __restrict__ cd, float* __restrict__ dis) {
    int i = blockIdx.x * 256 + threadIdx.x;
    if (i < NT) dis[i] = rsqrtf(1.0f + (float)cd[i]);  // +1 self loop
}

// ------------------------------------------------ xw = x @ conv1_W  [NT,32]
__global__ __launch_bounds__(256) void k_xw(const float* __restrict__ x, const float* __restrict__ W,
                                            float* __restrict__ xw) {
    __shared__ float sWT[32][132];           // W^T, padded stride
    int tid = threadIdx.x;
    for (int i = tid; i < INC * HH; i += 256) { int k = i >> 5, c = i & 31; sWT[c][k] = W[i]; }
    __syncthreads();
    int id = blockIdx.x * 256 + tid;
    int row = id >> 5, c = id & 31;
    const float4* xp = (const float4*)(x + (size_t)row * INC);
    float acc = 0.f;
#pragma unroll
    for (int kq = 0; kq < INC / 4; kq++) {
        float4 xv = xp[kq];
        float4 wv = *(const float4*)&sWT[c][kq * 4];
        acc += xv.x * wv.x + xv.y * wv.y + xv.z * wv.z + xv.w * wv.w;
    }
    xw[id] = acc;
}

// -------- GCN gather: h[d] = relu(dis[d]*(sum_in dis[s]*xw[s] + dis[d]*xw[d]) + b)
__global__ __launch_bounds__(256) void k_gcng(const int* __restrict__ ssrc, const int* __restrict__ od,
                                              const int* __restrict__ cd, const float* __restrict__ xw,
                                              const float* __restrict__ dis, const float* __restrict__ bias,
                                              float* __restrict__ h) {
    int tid = threadIdx.x;
    int n = blockIdx.x * 8 + (tid >> 5), c = tid & 31;
    int base = od[n], cnt = cd[n];
    float dn = dis[n];
    float acc = dn * xw[(size_t)n * HH + c];  // self-loop term (before outer dn)
    int i = 0;
    for (; i + 4 <= cnt; i += 4) {
        int s0 = ssrc[base + i], s1v = ssrc[base + i + 1];
        int s2 = ssrc[base + i + 2], s3 = ssrc[base + i + 3];
        float a0 = dis[s0] * xw[(size_t)s0 * HH + c];
        float a1 = dis[s1v] * xw[(size_t)s1v * HH + c];
        float a2 = dis[s2] * xw[(size_t)s2 * HH + c];
        float a3 = dis[s3] * xw[(size_t)s3 * HH + c];
        acc += (a0 + a1) + (a2 + a3);
    }
    for (; i < cnt; i++) { int s0 = ssrc[base + i]; acc += dis[s0] * xw[(size_t)s0 * HH + c]; }
    h[(size_t)n * HH + c] = fmaxf(dn * acc + bias[c], 0.f);
}

// ---------------- s1 = softmax(h @ pool1_W + b) per row; den1 atomics
__global__ __launch_bounds__(128) void k_s1(const float* __restrict__ h, const float* __restrict__ W,
                                            const float* __restrict__ bias, const int* __restrict__ csrc,
                                            float* __restrict__ s1, float* __restrict__ den1) {
    __shared__ float hr[HH];
    __shared__ float red[128], red2[128];
    int row = blockIdx.x, tid = threadIdx.x;
    if (tid < HH) hr[tid] = h[(size_t)row * HH + tid];
    __syncthreads();
    float v = -1e30f;
    if (tid < KP1) {
        float a = bias[tid];
#pragma unroll
        for (int k = 0; k < HH; k++) a = fmaf(hr[k], W[k * KP1 + tid], a);
        v = a;
    }
    red[tid] = v; __syncthreads();
#pragma unroll
    for (int s = 64; s > 0; s >>= 1) { if (tid < s) red[tid] = fmaxf(red[tid], red[tid + s]); __syncthreads(); }
    float m = red[0]; __syncthreads();
    float e = (tid < KP1) ? __expf(v - m) : 0.f;
    red[tid] = e; red2[tid] = e * e; __syncthreads();
#pragma unroll
    for (int s = 64; s > 0; s >>= 1) { if (tid < s) { red[tid] += red[tid + s]; red2[tid] += red2[tid + s]; } __syncthreads(); }
    float inv = 1.f / red[0];
    if (tid < KP1) s1[(size_t)row * KP1 + tid] = e * inv;
    if (tid == 0) atomicAdd(&den1[row >> 9], (float)csrc[row] * red2[0] * inv * inv);
}

// ------------- t1 gather: t1[s] = sum_{e: src=s} s1[dst_e]   (all 100 ch, 1 pass)
__global__ __launch_bounds__(256) void k_t1g(const int* __restrict__ sdst, const int* __restrict__ osr,
                                             const int* __restrict__ csr, const float* __restrict__ s1,
                                             float* __restrict__ t1) {
    int tid = threadIdx.x;
    int n = blockIdx.x * 2 + (tid >> 7), lane = tid & 127;
    if (lane >= KP1) return;
    int base = osr[n], cnt = csr[n];
    float acc = 0.f;
    int i = 0;
    for (; i + 4 <= cnt; i += 4) {
        int d0 = sdst[base + i], d1 = sdst[base + i + 1];
        int d2 = sdst[base + i + 2], d3 = sdst[base + i + 3];
        float a0 = s1[(size_t)d0 * KP1 + lane];
        float a1 = s1[(size_t)d1 * KP1 + lane];
        float a2 = s1[(size_t)d2 * KP1 + lane];
        float a3 = s1[(size_t)d3 * KP1 + lane];
        acc += (a0 + a1) + (a2 + a3);
    }
    for (; i < cnt; i++) { int d0 = sdst[base + i]; acc += s1[(size_t)d0 * KP1 + lane]; }
    t1[(size_t)n * KP1 + lane] = acc;
}

// --- gram: C = s1^T [t1 | h | s1]  (100 x 232) per (graph, n-half) partial
__global__ __launch_bounds__(512) void k_gram(const float* __restrict__ s1, const float* __restrict__ t1,
                                              const float* __restrict__ h, float* __restrict__ Cp) {
    __shared__ float sZ[32 * ZS];            // 30.2 KB
    int g = blockIdx.x >> 1, half = blockIdx.x & 1;
    int n0base = half * 256;
    int goff = g * NN;
    int tid = threadIdx.x;
    int wave = tid >> 6, lane = tid & 63;
    int wr = wave >> 1, wc = wave & 1;       // 4 x 2 wave grid
    int kg = wr * 4 + (lane >> 4);           // 0..15, need <13
    int lg = wc * 16 + (lane & 15);          // 0..31, need <29
    bool act = (kg < 13) && (lg < 29);
    int k0 = kg * 8, l0 = lg * 8;
    float accm[8][8];
#pragma unroll
    for (int i = 0; i < 8; i++)
#pragma unroll
        for (int j = 0; j < 8; j++) accm[i][j] = 0.f;

    for (int nt = 0; nt < 8; nt++) {
        int n0 = n0base + nt * 32;
        for (int i = tid; i < 32 * ZS; i += 512) {
            int r = i / ZS, cc = i % ZS;
            int n = goff + n0 + r;
            float val;
            if (cc < 100)      val = t1[(size_t)n * KP1 + cc];
            else if (cc < 132) val = h[(size_t)n * HH + (cc - 100)];
            else if (cc < 232) val = s1[(size_t)n * KP1 + (cc - 132)];
            else               val = 0.f;
            sZ[r * ZS + cc] = val;
        }
        __syncthreads();
        if (act) {
            for (int r = 0; r < 32; r++) {
                const float* zr = &sZ[r * ZS];
                float4 a0 = *(const float4*)&zr[132 + k0];
                float4 a1 = *(const float4*)&zr[132 + k0 + 4];
                float4 b0 = *(const float4*)&zr[l0];
                float4 b1 = *(const float4*)&zr[l0 + 4];
                float av[8] = {a0.x, a0.y, a0.z, a0.w, a1.x, a1.y, a1.z, a1.w};
                float bv[8] = {b0.x, b0.y, b0.z, b0.w, b1.x, b1.y, b1.z, b1.w};
#pragma unroll
                for (int i = 0; i < 8; i++)
#pragma unroll
                    for (int j = 0; j < 8; j++) accm[i][j] = fmaf(av[i], bv[j], accm[i][j]);
            }
        }
        __syncthreads();
    }
    if (act) {
        float* out = Cp + ((size_t)half * TB + g) * (KP1 * 232);
#pragma unroll
        for (int i = 0; i < 8; i++) {
            int k = k0 + i;
            if (k < KP1) {
#pragma unroll
                for (int j = 0; j < 8; j++) out[k * 232 + l0 + j] = accm[i][j];
            }
        }
    }
}

// ---- finalize stage 1: sum halves, losses, normalize out_adj, emit P1
__global__ __launch_bounds__(128) void k_fin1(const float* __restrict__ Cp, const float* __restrict__ den1,
                                              float* __restrict__ A1n, float* __restrict__ P1,
                                              float* __restrict__ aux) {
    __shared__ float sA[KP1 * KP1];          // 40 KB
    __shared__ float sd[KP1];
    __shared__ float r1[128], r2[128], r3[128];
    int g = blockIdx.x, tid = threadIdx.x;
    const float* c0 = Cp + (size_t)g * (KP1 * 232);
    const float* c1 = Cp + ((size_t)TB + g) * (KP1 * 232);
    float ssq = 0.f, troa = 0.f, trss = 0.f;
    if (tid < KP1) {
        int k = tid;
        float rs = 0.f;
        for (int l = 0; l < KP1; l++) {
            float oa = c0[k * 232 + l] + c1[k * 232 + l];
            sA[k * KP1 + l] = oa;
            if (l != k) rs += oa; else troa += oa;
            float ssv = c0[k * 232 + 132 + l] + c1[k * 232 + 132 + l];
            ssq += ssv * ssv;
            if (l == k) trss += ssv;
        }
        sd[k] = sqrtf(rs) + 1e-15f;
        for (int cc = 0; cc < HH; cc++)
            P1[((size_t)g * KP1 + k) * HH + cc] = c0[k * 232 + 100 + cc] + c1[k * 232 + 100 + cc];
    }
    r1[tid] = ssq; r2[tid] = troa; r3[tid] = trss; __syncthreads();
#pragma unroll
    for (int s = 64; s > 0; s >>= 1) {
        if (tid < s) { r1[tid] += r1[tid + s]; r2[tid] += r2[tid + s]; r3[tid] += r3[tid + s]; }
        __syncthreads();
    }
    if (tid == 0) {
        float ssF = sqrtf(r1[0]);
        float o1 = sqrtf(fmaxf(2.f - 2.f * r3[0] / (ssF * 10.f), 0.f));  // sqrt(K1)=10
        aux[128 + g] = -(r2[0] / den1[g]) + o1;
    }
    __syncthreads();
    for (int i = tid; i < KP1 * KP1; i += 128) {
        int k = i / KP1, l = i % KP1;
        A1n[(size_t)g * (KP1 * KP1) + i] = (k == l) ? 0.f : sA[i] / (sd[k] * sd[l]);
    }
}

// ------- stage 2a: conv2 + pool2 (per graph); A read from global (L2)
__global__ __launch_bounds__(512) void k_s2a(const float* __restrict__ A1n, const float* __restrict__ P1,
                                             const float* __restrict__ relW, const float* __restrict__ relB,
                                             const float* __restrict__ rootW,
                                             const float* __restrict__ p2W, const float* __restrict__ p2B,
                                             float* __restrict__ P2, float* __restrict__ A2n,
                                             float* __restrict__ aux) {
    __shared__ float sX[KP1 * HH];           // x1p then x2
    __shared__ float sY[KP1 * HH];           // y = A @ x1p
    __shared__ float sS2[KP1 * KP2];
    __shared__ float sT2[KP1 * KP2];
    __shared__ float sA2[100], sB2[100], sdd[10], red[100];
    int g = blockIdx.x, tid = threadIdx.x;
    const float* Ag = A1n + (size_t)g * (KP1 * KP1);
    for (int i = tid; i < KP1 * HH; i += 512) sX[i] = P1[(size_t)g * (KP1 * HH) + i];
    __syncthreads();

    int n = tid >> 2, cq = tid & 3;          // 400 active threads for y / x2
    // y = A @ x1p
    if (tid < 400) {
        float yv[8];
#pragma unroll
        for (int j = 0; j < 8; j++) yv[j] = 0.f;
        for (int mq = 0; mq < 25; mq++) {
            float4 a4 = *(const float4*)&Ag[n * KP1 + mq * 4];
            const float* xb = &sX[(mq * 4) * HH + cq * 8];
            float aa[4] = {a4.x, a4.y, a4.z, a4.w};
#pragma unroll
            for (int mm = 0; mm < 4; mm++) {
                const float* xr = xb + mm * HH;
#pragma unroll
                for (int j = 0; j < 8; j++) yv[j] = fmaf(aa[mm], xr[j], yv[j]);
            }
        }
#pragma unroll
        for (int j = 0; j < 8; j++) sY[n * HH + cq * 8 + j] = yv[j];
    }
    __syncthreads();
    // x2 = relu(y @ relW + relB + x1p @ rootW)
    float x2v[8];
    if (tid < 400) {
#pragma unroll
        for (int j = 0; j < 8; j++) x2v[j] = relB[cq * 8 + j];
        for (int j = 0; j < 32; j++) {
            float yj = sY[n * HH + j];
            float xj = sX[n * HH + j];
            float4 r0 = *(const float4*)&relW[j * 32 + cq * 8];
            float4 r1v = *(const float4*)&relW[j * 32 + cq * 8 + 4];
            float4 q0 = *(const float4*)&rootW[j * 32 + cq * 8];
            float4 q1 = *(const float4*)&rootW[j * 32 + cq * 8 + 4];
            x2v[0] += yj * r0.x + xj * q0.x;  x2v[1] += yj * r0.y + xj * q0.y;
            x2v[2] += yj * r0.z + xj * q0.z;  x2v[3] += yj * r0.w + xj * q0.w;
            x2v[4] += yj * r1v.x + xj * q1.x; x2v[5] += yj * r1v.y + xj * q1.y;
            x2v[6] += yj * r1v.z + xj * q1.z; x2v[7] += yj * r1v.w + xj * q1.w;
        }
    }
    __syncthreads();
    if (tid < 400) {
#pragma unroll
        for (int j = 0; j < 8; j++) sX[n * HH + cq * 8 + j] = fmaxf(x2v[j], 0.f);
    }
    __syncthreads();
    // s2 = softmax(x2 @ p2W + p2B); d2 and den2 partials
    if (tid < KP1) {
        float lg[10];
#pragma unroll
        for (int j = 0; j < 10; j++) lg[j] = p2B[j];
        for (int c = 0; c < 32; c++) {
            float xv = sX[tid * HH + c];
#pragma unroll
            for (int j = 0; j < 10; j++) lg[j] = fmaf(xv, p2W[c * 10 + j], lg[j]);
        }
        float mx = lg[0];
#pragma unroll
        for (int j = 1; j < 10; j++) mx = fmaxf(mx, lg[j]);
        float se = 0.f;
#pragma unroll
        for (int j = 0; j < 10; j++) { lg[j] = __expf(lg[j] - mx); se += lg[j]; }
        float inv = 1.f / se, sq = 0.f;
#pragma unroll
        for (int j = 0; j < 10; j++) { float sv = lg[j] * inv; sS2[tid * 10 + j] = sv; sq += sv * sv; }
        float d2 = 0.f;
        for (int mq = 0; mq < 25; mq++) {
            float4 a4 = *(const float4*)&Ag[tid * KP1 + mq * 4];
            d2 += a4.x + a4.y + a4.z + a4.w;
        }
        red[tid] = d2 * sq;
    }
    __syncthreads();
    // t2 = A @ s2 ; P2 = s2^T x2
    for (int p = tid; p < KP1 * KP2; p += 512) {
        int n2 = p / 10, jj = p % 10;
        float a = 0.f;
        for (int m = 0; m < KP1; m++) a = fmaf(Ag[n2 * KP1 + m], sS2[m * 10 + jj], a);
        sT2[p] = a;
    }
    if (tid < KP2 * HH) {
        int k = tid >> 5, cc = tid & 31;
        float a = 0.f;
        for (int n2 = 0; n2 < KP1; n2++) a = fmaf(sS2[n2 * 10 + k], sX[n2 * HH + cc], a);
        P2[(size_t)g * (KP2 * HH) + tid] = a;
    }
    __syncthreads();
    // oa2, ss2
    if (tid < 100) {
        int k = tid / 10, l = tid % 10;
        float oa = 0.f, ss = 0.f;
        for (int n2 = 0; n2 < KP1; n2++) {
            float sk = sS2[n2 * 10 + k];
            oa = fmaf(sk, sT2[n2 * 10 + l], oa);
            ss = fmaf(sk, sS2[n2 * 10 + l], ss);
        }
        sA2[tid] = oa; sB2[tid] = ss;
    }
    __syncthreads();
    if (tid == 0) {
        float den2 = 0.f;
        for (int i = 0; i < 100; i++) den2 += red[i];
        float troa = 0.f, trss = 0.f, ssq = 0.f;
        for (int k = 0; k < 10; k++) { troa += sA2[k * 10 + k]; trss += sB2[k * 10 + k]; }
        for (int i = 0; i < 100; i++) ssq += sB2[i] * sB2[i];
        float o2 = sqrtf(fmaxf(2.f - 2.f * trss / (sqrtf(ssq) * 3.16227766f), 0.f)); // sqrt(10)
        aux[256 + g] = -(troa / den2) + o2;
    }
    if (tid < 10) {
        float rs = 0.f;
        for (int l = 0; l < 10; l++) if (l != tid) rs += sA2[tid * 10 + l];
        sdd[tid] = sqrtf(rs) + 1e-15f;
    }
    __syncthreads();
    if (tid < 100) {
        int k = tid / 10, l = tid % 10;
        A2n[(size_t)g * 100 + tid] = (k == l) ? 0.f : sA2[tid] / (sdd[k] * sdd[l]);
    }
}

// ---------------- stage 2b: conv3 + mean + MLP head + log_softmax
__global__ __launch_bounds__(64) void k_s2b(const float* __restrict__ P2, const float* __restrict__ A2n,
                                            const float* __restrict__ relW3, const float* __restrict__ relb3,
                                            const float* __restrict__ rootW3,
                                            const float* __restrict__ l1W, const float* __restrict__ l1b,
                                            const float* __restrict__ l2W, const float* __restrict__ l2b,
                                            float* __restrict__ out) {
    __shared__ float sP[KP2 * HH], sA2[100], sY3[KP2 * HH], sG[32], sG1[32], sL[10], sLse;
    int g = blockIdx.x, tid = threadIdx.x;
    for (int i = tid; i < KP2 * HH; i += 64) sP[i] = P2[(size_t)g * (KP2 * HH) + i];
    for (int i = tid; i < 100; i += 64) sA2[i] = A2n[(size_t)g * 100 + i];
    if (tid < 32) sG[tid] = 0.f;
    __syncthreads();
    for (int p = tid; p < KP2 * HH; p += 64) {
        int k = p >> 5, cc = p & 31;
        float a = 0.f;
#pragma unroll
        for (int m = 0; m < 10; m++) a = fmaf(sA2[k * 10 + m], sP[m * HH + cc], a);
        sY3[p] = a;
    }
    __syncthreads();
    for (int p = tid; p < KP2 * HH; p += 64) {
        int k = p >> 5, cc = p & 31;
        float v = relb3[cc];
        for (int j = 0; j < 32; j++)
            v += sY3[k * HH + j] * relW3[j * 32 + cc] + sP[k * HH + j] * rootW3[j * 32 + cc];
        atomicAdd(&sG[cc], v * 0.1f);        // mean over 10 nodes
    }
    __syncthreads();
    if (tid < 32) {
        float v = l1b[tid];
        for (int j = 0; j < 32; j++) v = fmaf(sG[j], l1W[j * 32 + tid], v);
        sG1[tid] = fmaxf(v, 0.f);
    }
    __syncthreads();
    if (tid < 10) {
        float v = l2b[tid];
        for (int j = 0; j < 32; j++) v = fmaf(sG1[j], l2W[j * 10 + tid], v);
        sL[tid] = v;
    }
    __syncthreads();
    if (tid == 0) {
        float mx = sL[0];
        for (int j = 1; j < 10; j++) mx = fmaxf(mx, sL[j]);
        float se = 0.f;
        for (int j = 0; j < 10; j++) se += expf(sL[j] - mx);
        sLse = mx + logf(se);
    }
    __syncthreads();
    if (tid < 10) out[(size_t)g * 10 + tid] = sL[tid] - sLse;
}

// ------------------------------------------------------ total loss
__global__ void k_loss(const float* __restrict__ aux, float* __restrict__ out) {
    __shared__ float red[128];
    int tid = threadIdx.x;
    red[tid] = aux[128 + tid] + aux[256 + tid];
    __syncthreads();
#pragma unroll
    for (int s = 64; s > 0; s >>= 1) { if (tid < s) red[tid] += red[tid + s]; __syncthreads(); }
    if (tid == 0) out[1280] = red[0] * (1.f / 128.f);
}

extern "C" void kernel_launch(void* const* d_in, const int* in_sizes, int n_in,
                              void* d_out, int out_size, void* d_ws, size_t ws_size,
                              hipStream_t stream) {
    const float* x    = (const float*)d_in[0];
    const int*   ei   = (const int*)d_in[1];
    const float* c1W  = (const float*)d_in[3];
    const float* c1b  = (const float*)d_in[4];
    const float* p1W  = (const float*)d_in[5];
    const float* p1b  = (const float*)d_in[6];
    const float* relW2  = (const float*)d_in[7];
    const float* relb2  = (const float*)d_in[8];
    const float* rootW2 = (const float*)d_in[9];
    const float* p2W  = (const float*)d_in[10];
    const float* p2b  = (const float*)d_in[11];
    const float* relW3  = (const float*)d_in[12];
    const float* relb3  = (const float*)d_in[13];
    const float* rootW3 = (const float*)d_in[14];
    const float* l1W  = (const float*)d_in[15];
    const float* l1b  = (const float*)d_in[16];
    const float* l2W  = (const float*)d_in[17];
    const float* l2b  = (const float*)d_in[18];
    float* out = (float*)d_out;

    // ---- workspace layout
    int*  cnt_src = (int*)d_ws;                       // NT
    int*  cnt_dst = cnt_src + NT;                     // NT
    int*  off_src = cnt_dst + NT;                     // NT
    int*  off_dst = off_src + NT;                     // NT
    int*  cur_src = off_dst + NT;                     // NT
    int*  cur_dst = cur_src + NT;                     // NT
    int*  srt_dst = cur_dst + NT;                     // ET (src-sorted, stores dst)
    int*  srt_src = srt_dst + ET;                     // ET (dst-sorted, stores src)
    float* dis = (float*)(srt_src + ET);              // NT
    float* xw   = dis + NT;                           // NT*HH
    float* h    = xw + (size_t)NT * HH;               // NT*HH
    float* s1   = h + (size_t)NT * HH;                // NT*KP1
    float* t1   = s1 + (size_t)NT * KP1;              // NT*KP1
    float* Cp   = t1 + (size_t)NT * KP1;              // 2*TB*KP1*232
    float* A1n  = Cp + (size_t)2 * TB * (KP1 * 232);  // TB*KP1*KP1
    float* P1   = A1n + (size_t)TB * KP1 * KP1;       // TB*KP1*HH
    float* P2   = P1 + (size_t)TB * KP1 * HH;         // TB*KP2*HH
    float* A2n  = P2 + (size_t)TB * KP2 * HH;         // TB*100
    float* aux  = A2n + (size_t)TB * 100;             // 1024: den1|loss1|loss2

    k_init<<<NT / 256, 256, 0, stream>>>(cnt_src, cnt_dst, aux);
    k_cnt<<<ET / 256, 256, 0, stream>>>(ei, cnt_src, cnt_dst);
    k_scan<<<TB, 512, 0, stream>>>(cnt_src, cnt_dst, off_src, off_dst, cur_src, cur_dst);
    k_scatter<<<ET / 256, 256, 0, stream>>>(ei, cur_src, cur_dst, srt_dst, srt_src);
    k_dis<<<NT / 256, 256, 0, stream>>>(cnt_dst, dis);
    k_xw<<<(NT * HH) / 256, 256, 0, stream>>>(x, c1W, xw);
    k_gcng<<<NT / 8, 256, 0, stream>>>(srt_src, off_dst, cnt_dst, xw, dis, c1b, h);
    k_s1<<<NT, 128, 0, stream>>>(h, p1W, p1b, cnt_src, s1, aux /*den1*/);
    k_t1g<<<NT / 2, 256, 0, stream>>>(srt_dst, off_src, cnt_src, s1, t1);
    k_gram<<<TB * 2, 512, 0, stream>>>(s1, t1, h, Cp);
    k_fin1<<<TB, 128, 0, stream>>>(Cp, aux /*den1*/, A1n, P1, aux);
    k_s2a<<<TB, 512, 0, stream>>>(A1n, P1, relW2, relb2, rootW2, p2W, p2b, P2, A2n, aux);
    k_s2b<<<TB, 64, 0, stream>>>(P2, A2n, relW3, relb3, rootW3, l1W, l1b, l2W, l2b, out);
    k_loss<<<1, 128, 0, stream>>>(aux, out);
}

// Round 3
// 721.834 us; speedup vs baseline: 2.2754x; 1.3640x over previous
//
#include <hip/hip_runtime.h>
#include <hip/hip_bf16.h>

// Problem constants (match reference)
#define TB   128          // batch B
#define NN   512          // nodes per graph
#define INC  128          // IN_C
#define HH   32           // HID
#define KP1  100          // K1
#define KP2  10           // K2
#define OC   10           // OUT_C
#define EPER 8192         // edges per graph
#define NT   (TB*NN)      // 65536 total nodes
#define ET   (TB*EPER)    // 1048576 total edges
#define ZS   236          // gram Z tile stride (100 t + 32 h + 100 s + 4 pad)

// ---------------------------------------------------------------- init
__global__ void k_init(int* __restrict__ cs, int* __restrict__ cd, float* __restrict__ aux) {
    int i = blockIdx.x * 256 + threadIdx.x;
    if (i < NT) { cs[i] = 0; cd[i] = 0; }
    if (i < 1024) aux[i] = 0.0f;              // den1 / loss1 / loss2 accumulators
}

// ---------------------------------------------- edge degree histograms
__global__ void k_cnt(const int* __restrict__ ei, int* __restrict__ cs, int* __restrict__ cd) {
    int e = blockIdx.x * 256 + threadIdx.x;
    if (e < ET) {
        atomicAdd(&cs[ei[e]], 1);             // out-degree (src)  = adj.sum(-1)
        atomicAdd(&cd[ei[ET + e]], 1);        // in-degree  (dst)  for GCN norm
    }
}

// ---------------- per-graph exclusive scan of both degree histograms
__global__ __launch_bounds__(512) void k_scan(const int* __restrict__ cs, const int* __restrict__ cd,
                                              int* __restrict__ os, int* __restrict__ od,
                                              int* __restrict__ curs, int* __restrict__ curd) {
    __shared__ int sa[512], sb[512];
    int g = blockIdx.x, tid = threadIdx.x, i = g * NN + tid;
    int vs = cs[i], vd = cd[i];
    sa[tid] = vs; sb[tid] = vd; __syncthreads();
    for (int off = 1; off < 512; off <<= 1) {
        int xa = sa[tid], xb = sb[tid];
        if (tid >= off) { xa += sa[tid - off]; xb += sb[tid - off]; }
        __syncthreads(); sa[tid] = xa; sb[tid] = xb; __syncthreads();
    }
    int es = g * EPER + sa[tid] - vs;         // exclusive scan, global position
    int ed = g * EPER + sb[tid] - vd;
    os[i] = es; od[i] = ed; curs[i] = es; curd[i] = ed;
}

// ----------------- counting-sort scatter: edges by src and by dst
__global__ void k_scatter(const int* __restrict__ ei, int* __restrict__ curs, int* __restrict__ curd,
                          int* __restrict__ sdst, int* __restrict__ ssrc) {
    int e = blockIdx.x * 256 + threadIdx.x;
    if (e < ET) {
        int s = ei[e], d = ei[ET + e];
        int p = atomicAdd(&curs[s], 1); sdst[p] = d;   // src-sorted: store dst
        int q = atomicAdd(&curd[d], 1); ssrc[q] = s;   // dst-sorted: store src
    }
}

__global__ void k_dis(const int* __restrict__ cd, float* __restrict__ dis) {
    int i = blockIdx.x * 256 + threadIdx.x;
    if (i < NT) dis[i] = rsqrtf(1.0f + (float)cd[i]);  // +1 self loop
}

// ------------------------------------------------ xw = x @ conv1_W  [NT,32]
__global__ __launch_bounds__(256) void k_xw(const float* __restrict__ x, const float* __restrict__ W,
                                            float* __restrict__ xw) {
    __shared__ float sWT[32][132];           // W^T, padded stride
    int tid = threadIdx.x;
    for (int i = tid; i < INC * HH; i += 256) { int k = i >> 5, c = i & 31; sWT[c][k] = W[i]; }
    __syncthreads();
    int id = blockIdx.x * 256 + tid;
    int row = id >> 5, c = id & 31;
    const float4* xp = (const float4*)(x + (size_t)row * INC);
    float acc = 0.f;
#pragma unroll
    for (int kq = 0; kq < INC / 4; kq++) {
        float4 xv = xp[kq];
        float4 wv = *(const float4*)&sWT[c][kq * 4];
        acc += xv.x * wv.x + xv.y * wv.y + xv.z * wv.z + xv.w * wv.w;
    }
    xw[id] = acc;
}

// -------- GCN gather: h[d] = relu(dis[d]*(sum_in dis[s]*xw[s] + dis[d]*xw[d]) + b)
__global__ __launch_bounds__(256) void k_gcng(const int* __restrict__ ssrc, const int* __restrict__ od,
                                              const int* __restrict__ cd, const float* __restrict__ xw,
                                              const float* __restrict__ dis, const float* __restrict__ bias,
                                              float* __restrict__ h) {
    int tid = threadIdx.x;
    int n = blockIdx.x * 8 + (tid >> 5), c = tid & 31;
    int base = od[n], cnt = cd[n];
    float dn = dis[n];
    float acc = dn * xw[(size_t)n * HH + c];  // self-loop term (before outer dn)
    int i = 0;
    for (; i + 4 <= cnt; i += 4) {
        int s0 = ssrc[base + i], s1v = ssrc[base + i + 1];
        int s2 = ssrc[base + i + 2], s3 = ssrc[base + i + 3];
        float a0 = dis[s0] * xw[(size_t)s0 * HH + c];
        float a1 = dis[s1v] * xw[(size_t)s1v * HH + c];
        float a2 = dis[s2] * xw[(size_t)s2 * HH + c];
        float a3 = dis[s3] * xw[(size_t)s3 * HH + c];
        acc += (a0 + a1) + (a2 + a3);
    }
    for (; i < cnt; i++) { int s0 = ssrc[base + i]; acc += dis[s0] * xw[(size_t)s0 * HH + c]; }
    h[(size_t)n * HH + c] = fmaxf(dn * acc + bias[c], 0.f);
}

// ------- s1 = softmax(h @ pool1_W + b): wave-per-2-rows, shuffle reductions
__global__ __launch_bounds__(256) void k_s1(const float* __restrict__ h, const float* __restrict__ W,
                                            const float* __restrict__ bias, const int* __restrict__ csrc,
                                            float* __restrict__ s1, float* __restrict__ den1) {
    __shared__ float sW[INC + HH * KP1];     // bias[100] padded to 128, then W[32][100]
    int tid = threadIdx.x;
    if (tid < KP1) sW[tid] = bias[tid];
    for (int i = tid; i < HH * KP1; i += 256) sW[INC + i] = W[i];
    __syncthreads();
    int wave = tid >> 6, lane = tid & 63;
    int row0 = blockIdx.x * 8 + wave * 2;    // this wave: rows row0, row0+1
    // h rows into registers (wave-uniform broadcast loads)
    float h0[HH], h1[HH];
    const float4* hp0 = (const float4*)(h + (size_t)row0 * HH);
    const float4* hp1 = (const float4*)(h + (size_t)(row0 + 1) * HH);
#pragma unroll
    for (int q = 0; q < HH / 4; q++) {
        float4 a = hp0[q]; h0[4*q] = a.x; h0[4*q+1] = a.y; h0[4*q+2] = a.z; h0[4*q+3] = a.w;
        float4 b = hp1[q]; h1[4*q] = b.x; h1[4*q+1] = b.y; h1[4*q+2] = b.z; h1[4*q+3] = b.w;
    }
    bool two = lane < (KP1 - 64);            // lane owns channels lane and 64+lane
    float b0v = sW[lane], b1v = sW[(lane + 64) & 127];   // &127 keeps in-range for idle lanes
    float a00 = b0v, a01 = b1v, a10 = b0v, a11 = b1v;    // [row][chanpart]
#pragma unroll
    for (int k = 0; k < HH; k++) {
        float w0 = sW[INC + k * KP1 + lane];
        float w1 = sW[INC + k * KP1 + 64 + ((lane < 36) ? lane : 35)];
        a00 = fmaf(h0[k], w0, a00); a10 = fmaf(h1[k], w0, a10);
        a01 = fmaf(h0[k], w1, a01); a11 = fmaf(h1[k], w1, a11);
    }
    // row 0 softmax
    float m0 = fmaxf(a00, two ? a01 : -1e30f);
    float m1 = fmaxf(a10, two ? a11 : -1e30f);
#pragma unroll
    for (int off = 32; off >= 1; off >>= 1) {
        m0 = fmaxf(m0, __shfl_xor(m0, off));
        m1 = fmaxf(m1, __shfl_xor(m1, off));
    }
    float e00 = __expf(a00 - m0), e01 = two ? __expf(a01 - m0) : 0.f;
    float e10 = __expf(a10 - m1), e11 = two ? __expf(a11 - m1) : 0.f;
    float s0 = e00 + e01, s1v = e10 + e11;
    float q0 = e00 * e00 + e01 * e01, q1 = e10 * e10 + e11 * e11;
#pragma unroll
    for (int off = 32; off >= 1; off >>= 1) {
        s0 += __shfl_xor(s0, off); s1v += __shfl_xor(s1v, off);
        q0 += __shfl_xor(q0, off); q1 += __shfl_xor(q1, off);
    }
    float i0 = 1.f / s0, i1 = 1.f / s1v;
    float* r0 = s1 + (size_t)row0 * KP1;
    float* r1 = s1 + (size_t)(row0 + 1) * KP1;
    r0[lane] = e00 * i0; r1[lane] = e10 * i1;
    if (two) { r0[64 + lane] = e01 * i0; r1[64 + lane] = e11 * i1; }
    if (lane == 0) {
        int g = row0 >> 9;
        atomicAdd(&den1[g], (float)csrc[row0] * q0 * i0 * i0
                          + (float)csrc[row0 + 1] * q1 * i1 * i1);
    }
}

// ------------- t1 gather: t1[s] = sum_{e: src=s} s1[dst_e]   (all 100 ch, 1 pass)
__global__ __launch_bounds__(256) void k_t1g(const int* __restrict__ sdst, const int* __restrict__ osr,
                                             const int* __restrict__ csr, const float* __restrict__ s1,
                                             float* __restrict__ t1) {
    int tid = threadIdx.x;
    int n = blockIdx.x * 2 + (tid >> 7), lane = tid & 127;
    if (lane >= KP1) return;
    int base = osr[n], cnt = csr[n];
    float acc = 0.f;
    int i = 0;
    for (; i + 4 <= cnt; i += 4) {
        int d0 = sdst[base + i], d1 = sdst[base + i + 1];
        int d2 = sdst[base + i + 2], d3 = sdst[base + i + 3];
        float a0 = s1[(size_t)d0 * KP1 + lane];
        float a1 = s1[(size_t)d1 * KP1 + lane];
        float a2 = s1[(size_t)d2 * KP1 + lane];
        float a3 = s1[(size_t)d3 * KP1 + lane];
        acc += (a0 + a1) + (a2 + a3);
    }
    for (; i < cnt; i++) { int d0 = sdst[base + i]; acc += s1[(size_t)d0 * KP1 + lane]; }
    t1[(size_t)n * KP1 + lane] = acc;
}

// --- gram: C = s1^T [t1 | h | s1]  (100 x 232) per (graph, n-half) partial
__global__ __launch_bounds__(512) void k_gram(const float* __restrict__ s1, const float* __restrict__ t1,
                                              const float* __restrict__ h, float* __restrict__ Cp) {
    __shared__ float sZ[32 * ZS];            // 30.2 KB
    int g = blockIdx.x >> 1, half = blockIdx.x & 1;
    int n0base = half * 256;
    int goff = g * NN;
    int tid = threadIdx.x;
    int wave = tid >> 6, lane = tid & 63;
    int wr = wave >> 1, wc = wave & 1;       // 4 x 2 wave grid
    int kg = wr * 4 + (lane >> 4);           // 0..15, need <13
    int lg = wc * 16 + (lane & 15);          // 0..31, need <29
    bool act = (kg < 13) && (lg < 29);
    int k0 = kg * 8, l0 = lg * 8;
    float accm[8][8];
#pragma unroll
    for (int i = 0; i < 8; i++)
#pragma unroll
        for (int j = 0; j < 8; j++) accm[i][j] = 0.f;

    for (int nt = 0; nt < 8; nt++) {
        int n0 = n0base + nt * 32;
        for (int i = tid; i < 32 * ZS; i += 512) {
            int r = i / ZS, cc = i % ZS;
            int n = goff + n0 + r;
            float val;
            if (cc < 100)      val = t1[(size_t)n * KP1 + cc];
            else if (cc < 132) val = h[(size_t)n * HH + (cc - 100)];
            else if (cc < 232) val = s1[(size_t)n * KP1 + (cc - 132)];
            else               val = 0.f;
            sZ[r * ZS + cc] = val;
        }
        __syncthreads();
        if (act) {
            for (int r = 0; r < 32; r++) {
                const float* zr = &sZ[r * ZS];
                float4 a0 = *(const float4*)&zr[132 + k0];
                float4 a1 = *(const float4*)&zr[132 + k0 + 4];
                float4 b0 = *(const float4*)&zr[l0];
                float4 b1 = *(const float4*)&zr[l0 + 4];
                float av[8] = {a0.x, a0.y, a0.z, a0.w, a1.x, a1.y, a1.z, a1.w};
                float bv[8] = {b0.x, b0.y, b0.z, b0.w, b1.x, b1.y, b1.z, b1.w};
#pragma unroll
                for (int i = 0; i < 8; i++)
#pragma unroll
                    for (int j = 0; j < 8; j++) accm[i][j] = fmaf(av[i], bv[j], accm[i][j]);
            }
        }
        __syncthreads();
    }
    if (act) {
        float* out = Cp + ((size_t)half * TB + g) * (KP1 * 232);
#pragma unroll
        for (int i = 0; i < 8; i++) {
            int k = k0 + i;
            if (k < KP1) {
#pragma unroll
                for (int j = 0; j < 8; j++) out[k * 232 + l0 + j] = accm[i][j];
            }
        }
    }
}

// ---- finalize stage 1: sum halves, losses, normalize out_adj, emit P1
__global__ __launch_bounds__(128) void k_fin1(const float* __restrict__ Cp, const float* __restrict__ den1,
                                              float* __restrict__ A1n, float* __restrict__ P1,
                                              float* __restrict__ aux) {
    __shared__ float sA[KP1 * KP1];          // 40 KB
    __shared__ float sd[KP1];
    __shared__ float r1[128], r2[128], r3[128];
    int g = blockIdx.x, tid = threadIdx.x;
    const float* c0 = Cp + (size_t)g * (KP1 * 232);
    const float* c1 = Cp + ((size_t)TB + g) * (KP1 * 232);
    float ssq = 0.f, troa = 0.f, trss = 0.f;
    if (tid < KP1) {
        int k = tid;
        float rs = 0.f;
        for (int l = 0; l < KP1; l++) {
            float oa = c0[k * 232 + l] + c1[k * 232 + l];
            sA[k * KP1 + l] = oa;
            if (l != k) rs += oa; else troa += oa;
            float ssv = c0[k * 232 + 132 + l] + c1[k * 232 + 132 + l];
            ssq += ssv * ssv;
            if (l == k) trss += ssv;
        }
        sd[k] = sqrtf(rs) + 1e-15f;
        for (int cc = 0; cc < HH; cc++)
            P1[((size_t)g * KP1 + k) * HH + cc] = c0[k * 232 + 100 + cc] + c1[k * 232 + 100 + cc];
    }
    r1[tid] = ssq; r2[tid] = troa; r3[tid] = trss; __syncthreads();
#pragma unroll
    for (int s = 64; s > 0; s >>= 1) {
        if (tid < s) { r1[tid] += r1[tid + s]; r2[tid] += r2[tid + s]; r3[tid] += r3[tid + s]; }
        __syncthreads();
    }
    if (tid == 0) {
        float ssF = sqrtf(r1[0]);
        float o1 = sqrtf(fmaxf(2.f - 2.f * r3[0] / (ssF * 10.f), 0.f));  // sqrt(K1)=10
        aux[128 + g] = -(r2[0] / den1[g]) + o1;
    }
    __syncthreads();
    for (int i = tid; i < KP1 * KP1; i += 128) {
        int k = i / KP1, l = i % KP1;
        A1n[(size_t)g * (KP1 * KP1) + i] = (k == l) ? 0.f : sA[i] / (sd[k] * sd[l]);
    }
}

// ------- stage 2a: conv2 + pool2 (per graph); A read from global (L2)
__global__ __launch_bounds__(512) void k_s2a(const float* __restrict__ A1n, const float* __restrict__ P1,
                                             const float* __restrict__ relW, const float* __restrict__ relB,
                                             const float* __restrict__ rootW,
                                             const float* __restrict__ p2W, const float* __restrict__ p2B,
                                             float* __restrict__ P2, float* __restrict__ A2n,
                                             float* __restrict__ aux) {
    __shared__ float sX[KP1 * HH];           // x1p then x2
    __shared__ float sY[KP1 * HH];           // y = A @ x1p
    __shared__ float sS2[KP1 * KP2];
    __shared__ float sT2[KP1 * KP2];
    __shared__ float sA2[100], sB2[100], sdd[10], red[100];
    int g = blockIdx.x, tid = threadIdx.x;
    const float* Ag = A1n + (size_t)g * (KP1 * KP1);
    for (int i = tid; i < KP1 * HH; i += 512) sX[i] = P1[(size_t)g * (KP1 * HH) + i];
    __syncthreads();

    int n = tid >> 2, cq = tid & 3;          // 400 active threads for y / x2
    // y = A @ x1p
    if (tid < 400) {
        float yv[8];
#pragma unroll
        for (int j = 0; j < 8; j++) yv[j] = 0.f;
        for (int mq = 0; mq < 25; mq++) {
            float4 a4 = *(const float4*)&Ag[n * KP1 + mq * 4];
            const float* xb = &sX[(mq * 4) * HH + cq * 8];
            float aa[4] = {a4.x, a4.y, a4.z, a4.w};
#pragma unroll
            for (int mm = 0; mm < 4; mm++) {
                const float* xr = xb + mm * HH;
#pragma unroll
                for (int j = 0; j < 8; j++) yv[j] = fmaf(aa[mm], xr[j], yv[j]);
            }
        }
#pragma unroll
        for (int j = 0; j < 8; j++) sY[n * HH + cq * 8 + j] = yv[j];
    }
    __syncthreads();
    // x2 = relu(y @ relW + relB + x1p @ rootW)
    float x2v[8];
    if (tid < 400) {
#pragma unroll
        for (int j = 0; j < 8; j++) x2v[j] = relB[cq * 8 + j];
        for (int j = 0; j < 32; j++) {
            float yj = sY[n * HH + j];
            float xj = sX[n * HH + j];
            float4 r0 = *(const float4*)&relW[j * 32 + cq * 8];
            float4 r1v = *(const float4*)&relW[j * 32 + cq * 8 + 4];
            float4 q0 = *(const float4*)&rootW[j * 32 + cq * 8];
            float4 q1 = *(const float4*)&rootW[j * 32 + cq * 8 + 4];
            x2v[0] += yj * r0.x + xj * q0.x;  x2v[1] += yj * r0.y + xj * q0.y;
            x2v[2] += yj * r0.z + xj * q0.z;  x2v[3] += yj * r0.w + xj * q0.w;
            x2v[4] += yj * r1v.x + xj * q1.x; x2v[5] += yj * r1v.y + xj * q1.y;
            x2v[6] += yj * r1v.z + xj * q1.z; x2v[7] += yj * r1v.w + xj * q1.w;
        }
    }
    __syncthreads();
    if (tid < 400) {
#pragma unroll
        for (int j = 0; j < 8; j++) sX[n * HH + cq * 8 + j] = fmaxf(x2v[j], 0.f);
    }
    __syncthreads();
    // s2 = softmax(x2 @ p2W + p2B); d2 and den2 partials
    if (tid < KP1) {
        float lg[10];
#pragma unroll
        for (int j = 0; j < 10; j++) lg[j] = p2B[j];
        for (int c = 0; c < 32; c++) {
            float xv = sX[tid * HH + c];
#pragma unroll
            for (int j = 0; j < 10; j++) lg[j] = fmaf(xv, p2W[c * 10 + j], lg[j]);
        }
        float mx = lg[0];
#pragma unroll
        for (int j = 1; j < 10; j++) mx = fmaxf(mx, lg[j]);
        float se = 0.f;
#pragma unroll
        for (int j = 0; j < 10; j++) { lg[j] = __expf(lg[j] - mx); se += lg[j]; }
        float inv = 1.f / se, sq = 0.f;
#pragma unroll
        for (int j = 0; j < 10; j++) { float sv = lg[j] * inv; sS2[tid * 10 + j] = sv; sq += sv * sv; }
        float d2 = 0.f;
        for (int mq = 0; mq < 25; mq++) {
            float4 a4 = *(const float4*)&Ag[tid * KP1 + mq * 4];
            d2 += a4.x + a4.y + a4.z + a4.w;
        }
        red[tid] = d2 * sq;
    }
    __syncthreads();
    // t2 = A @ s2 ; P2 = s2^T x2
    for (int p = tid; p < KP1 * KP2; p += 512) {
        int n2 = p / 10, jj = p % 10;
        float a = 0.f;
        for (int m = 0; m < KP1; m++) a = fmaf(Ag[n2 * KP1 + m], sS2[m * 10 + jj], a);
        sT2[p] = a;
    }
    if (tid < KP2 * HH) {
        int k = tid >> 5, cc = tid & 31;
        float a = 0.f;
        for (int n2 = 0; n2 < KP1; n2++) a = fmaf(sS2[n2 * 10 + k], sX[n2 * HH + cc], a);
        P2[(size_t)g * (KP2 * HH) + tid] = a;
    }
    __syncthreads();
    // oa2, ss2
    if (tid < 100) {
        int k = tid / 10, l = tid % 10;
        float oa = 0.f, ss = 0.f;
        for (int n2 = 0; n2 < KP1; n2++) {
            float sk = sS2[n2 * 10 + k];
            oa = fmaf(sk, sT2[n2 * 10 + l], oa);
            ss = fmaf(sk, sS2[n2 * 10 + l], ss);
        }
        sA2[tid] = oa; sB2[tid] = ss;
    }
    __syncthreads();
    if (tid == 0) {
        float den2 = 0.f;
        for (int i = 0; i < 100; i++) den2 += red[i];
        float troa = 0.f, trss = 0.f, ssq = 0.f;
        for (int k = 0; k < 10; k++) { troa += sA2[k * 10 + k]; trss += sB2[k * 10 + k]; }
        for (int i = 0; i < 100; i++) ssq += sB2[i] * sB2[i];
        float o2 = sqrtf(fmaxf(2.f - 2.f * trss / (sqrtf(ssq) * 3.16227766f), 0.f)); // sqrt(10)
        aux[256 + g] = -(troa / den2) + o2;
    }
    if (tid < 10) {
        float rs = 0.f;
        for (int l = 0; l < 10; l++) if (l != tid) rs += sA2[tid * 10 + l];
        sdd[tid] = sqrtf(rs) + 1e-15f;
    }
    __syncthreads();
    if (tid < 100) {
        int k = tid / 10, l = tid % 10;
        A2n[(size_t)g * 100 + tid] = (k == l) ? 0.f : sA2[tid] / (sdd[k] * sdd[l]);
    }
}

// ---------------- stage 2b: conv3 + mean + MLP head + log_softmax
__global__ __launch_bounds__(64) void k_s2b(const float* __restrict__ P2, const float* __restrict__ A2n,
                                            const float* __restrict__ relW3, const float* __restrict__ relb3,
                                            const float* __restrict__ rootW3,
                                            const float* __restrict__ l1W, const float* __restrict__ l1b,
                                            const float* __restrict__ l2W, const float* __restrict__ l2b,
                                            float* __restrict__ out) {
    __shared__ float sP[KP2 * HH], sA2[100], sY3[KP2 * HH], sG[32], sG1[32], sL[10], sLse;
    int g = blockIdx.x, tid = threadIdx.x;
    for (int i = tid; i < KP2 * HH; i += 64) sP[i] = P2[(size_t)g * (KP2 * HH) + i];
    for (int i = tid; i < 100; i += 64) sA2[i] = A2n[(size_t)g * 100 + i];
    if (tid < 32) sG[tid] = 0.f;
    __syncthreads();
    for (int p = tid; p < KP2 * HH; p += 64) {
        int k = p >> 5, cc = p & 31;
        float a = 0.f;
#pragma unroll
        for (int m = 0; m < 10; m++) a = fmaf(sA2[k * 10 + m], sP[m * HH + cc], a);
        sY3[p] = a;
    }
    __syncthreads();
    for (int p = tid; p < KP2 * HH; p += 64) {
        int k = p >> 5, cc = p & 31;
        float v = relb3[cc];
        for (int j = 0; j < 32; j++)
            v += sY3[k * HH + j] * relW3[j * 32 + cc] + sP[k * HH + j] * rootW3[j * 32 + cc];
        atomicAdd(&sG[cc], v * 0.1f);        // mean over 10 nodes
    }
    __syncthreads();
    if (tid < 32) {
        float v = l1b[tid];
        for (int j = 0; j < 32; j++) v = fmaf(sG[j], l1W[j * 32 + tid], v);
        sG1[tid] = fmaxf(v, 0.f);
    }
    __syncthreads();
    if (tid < 10) {
        float v = l2b[tid];
        for (int j = 0; j < 32; j++) v = fmaf(sG1[j], l2W[j * 10 + tid], v);
        sL[tid] = v;
    }
    __syncthreads();
    if (tid == 0) {
        float mx = sL[0];
        for (int j = 1; j < 10; j++) mx = fmaxf(mx, sL[j]);
        float se = 0.f;
        for (int j = 0; j < 10; j++) se += expf(sL[j] - mx);
        sLse = mx + logf(se);
    }
    __syncthreads();
    if (tid < 10) out[(size_t)g * 10 + tid] = sL[tid] - sLse;
}

// ------------------------------------------------------ total loss
__global__ void k_loss(const float* __restrict__ aux, float* __restrict__ out) {
    __shared__ float red[128];
    int tid = threadIdx.x;
    red[tid] = aux[128 + tid] + aux[256 + tid];
    __syncthreads();
#pragma unroll
    for (int s = 64; s > 0; s >>= 1) { if (tid < s) red[tid] += red[tid + s]; __syncthreads(); }
    if (tid == 0) out[1280] = red[0] * (1.f / 128.f);
}

extern "C" void kernel_launch(void* const* d_in, const int* in_sizes, int n_in,
                              void* d_out, int out_size, void* d_ws, size_t ws_size,
                              hipStream_t stream) {
    const float* x    = (const float*)d_in[0];
    const int*   ei   = (const int*)d_in[1];
    const float* c1W  = (const float*)d_in[3];
    const float* c1b  = (const float*)d_in[4];
    const float* p1W  = (const float*)d_in[5];
    const float* p1b  = (const float*)d_in[6];
    const float* relW2  = (const float*)d_in[7];
    const float* relb2  = (const float*)d_in[8];
    const float* rootW2 = (const float*)d_in[9];
    const float* p2W  = (const float*)d_in[10];
    const float* p2b  = (const float*)d_in[11];
    const float* relW3  = (const float*)d_in[12];
    const float* relb3  = (const float*)d_in[13];
    const float* rootW3 = (const float*)d_in[14];
    const float* l1W  = (const float*)d_in[15];
    const float* l1b  = (const float*)d_in[16];
    const float* l2W  = (const float*)d_in[17];
    const float* l2b  = (const float*)d_in[18];
    float* out = (float*)d_out;

    // ---- workspace layout
    int*  cnt_src = (int*)d_ws;                       // NT
    int*  cnt_dst = cnt_src + NT;                     // NT
    int*  off_src = cnt_dst + NT;                     // NT
    int*  off_dst = off_src + NT;                     // NT
    int*  cur_src = off_dst + NT;                     // NT
    int*  cur_dst = cur_src + NT;                     // NT
    int*  srt_dst = cur_dst + NT;                     // ET (src-sorted, stores dst)
    int*  srt_src = srt_dst + ET;                     // ET (dst-sorted, stores src)
    float* dis = (float*)(srt_src + ET);              // NT
    float* xw   = dis + NT;                           // NT*HH
    float* h    = xw + (size_t)NT * HH;               // NT*HH
    float* s1   = h + (size_t)NT * HH;                // NT*KP1
    float* t1   = s1 + (size_t)NT * KP1;              // NT*KP1
    float* Cp   = t1 + (size_t)NT * KP1;              // 2*TB*KP1*232
    float* A1n  = Cp + (size_t)2 * TB * (KP1 * 232);  // TB*KP1*KP1
    float* P1   = A1n + (size_t)TB * KP1 * KP1;       // TB*KP1*HH
    float* P2   = P1 + (size_t)TB * KP1 * HH;         // TB*KP2*HH
    float* A2n  = P2 + (size_t)TB * KP2 * HH;         // TB*100
    float* aux  = A2n + (size_t)TB * 100;             // 1024: den1|loss1|loss2

    k_init<<<NT / 256, 256, 0, stream>>>(cnt_src, cnt_dst, aux);
    k_cnt<<<ET / 256, 256, 0, stream>>>(ei, cnt_src, cnt_dst);
    k_scan<<<TB, 512, 0, stream>>>(cnt_src, cnt_dst, off_src, off_dst, cur_src, cur_dst);
    k_scatter<<<ET / 256, 256, 0, stream>>>(ei, cur_src, cur_dst, srt_dst, srt_src);
    k_dis<<<NT / 256, 256, 0, stream>>>(cnt_dst, dis);
    k_xw<<<(NT * HH) / 256, 256, 0, stream>>>(x, c1W, xw);
    k_gcng<<<NT / 8, 256, 0, stream>>>(srt_src, off_dst, cnt_dst, xw, dis, c1b, h);
    k_s1<<<NT / 8, 256, 0, stream>>>(h, p1W, p1b, cnt_src, s1, aux /*den1*/);
    k_t1g<<<NT / 2, 256, 0, stream>>>(srt_dst, off_src, cnt_src, s1, t1);
    k_gram<<<TB * 2, 512, 0, stream>>>(s1, t1, h, Cp);
    k_fin1<<<TB, 128, 0, stream>>>(Cp, aux /*den1*/, A1n, P1, aux);
    k_s2a<<<TB, 512, 0, stream>>>(A1n, P1, relW2, relb2, rootW2, p2W, p2b, P2, A2n, aux);
    k_s2b<<<TB, 64, 0, stream>>>(P2, A2n, relW3, relb3, rootW3, l1W, l1b, l2W, l2b, out);
    k_loss<<<1, 128, 0, stream>>>(aux, out);
}

// Round 4
// 585.848 us; speedup vs baseline: 2.8036x; 1.2321x over previous
//
#include <hip/hip_runtime.h>
#include <hip/hip_bf16.h>

// Problem constants (match reference)
#define TB   128          // batch B
#define NN   512          // nodes per graph
#define INC  128          // IN_C
#define HH   32           // HID
#define KP1  100          // K1
#define KP2  10           // K2
#define OC   10           // OUT_C
#define EPER 8192         // edges per graph
#define NT   (TB*NN)      // 65536 total nodes
#define ET   (TB*EPER)    // 1048576 total edges
#define ZS   236          // gram Z tile stride (100 t + 32 h + 100 s + 4 pad)

// ---------------------------------------------------------------- init
__global__ void k_init(int* __restrict__ cs, int* __restrict__ cd, float* __restrict__ aux) {
    int i = blockIdx.x * 256 + threadIdx.x;
    if (i < NT) { cs[i] = 0; cd[i] = 0; }
    if (i < 1024) aux[i] = 0.0f;              // den1 / loss1 / loss2 accumulators
}

// ---------------------------------------------- edge degree histograms
__global__ void k_cnt(const int* __restrict__ ei, int* __restrict__ cs, int* __restrict__ cd) {
    int e = blockIdx.x * 256 + threadIdx.x;
    if (e < ET) {
        atomicAdd(&cs[ei[e]], 1);             // out-degree (src)  = adj.sum(-1)
        atomicAdd(&cd[ei[ET + e]], 1);        // in-degree  (dst)  for GCN norm
    }
}

// ---------------- per-graph exclusive scan of both degree histograms
__global__ __launch_bounds__(512) void k_scan(const int* __restrict__ cs, const int* __restrict__ cd,
                                              int* __restrict__ os, int* __restrict__ od,
                                              int* __restrict__ curs, int* __restrict__ curd) {
    __shared__ int sa[512], sb[512];
    int g = blockIdx.x, tid = threadIdx.x, i = g * NN + tid;
    int vs = cs[i], vd = cd[i];
    sa[tid] = vs; sb[tid] = vd; __syncthreads();
    for (int off = 1; off < 512; off <<= 1) {
        int xa = sa[tid], xb = sb[tid];
        if (tid >= off) { xa += sa[tid - off]; xb += sb[tid - off]; }
        __syncthreads(); sa[tid] = xa; sb[tid] = xb; __syncthreads();
    }
    int es = g * EPER + sa[tid] - vs;         // exclusive scan, global position
    int ed = g * EPER + sb[tid] - vd;
    os[i] = es; od[i] = ed; curs[i] = es; curd[i] = ed;
}

// ----------------- counting-sort scatter: edges by src and by dst
__global__ void k_scatter(const int* __restrict__ ei, int* __restrict__ curs, int* __restrict__ curd,
                          int* __restrict__ sdst, int* __restrict__ ssrc) {
    int e = blockIdx.x * 256 + threadIdx.x;
    if (e < ET) {
        int s = ei[e], d = ei[ET + e];
        int p = atomicAdd(&curs[s], 1); sdst[p] = d;   // src-sorted: store dst
        int q = atomicAdd(&curd[d], 1); ssrc[q] = s;   // dst-sorted: store src
    }
}

__global__ void k_dis(const int* __restrict__ cd, float* __restrict__ dis) {
    int i = blockIdx.x * 256 + threadIdx.x;
    if (i < NT) dis[i] = rsqrtf(1.0f + (float)cd[i]);  // +1 self loop
}

// ------------------------------------------------ xw = x @ conv1_W  [NT,32]
__global__ __launch_bounds__(256) void k_xw(const float* __restrict__ x, const float* __restrict__ W,
                                            float* __restrict__ xw) {
    __shared__ float sWT[32][132];           // W^T, padded stride
    int tid = threadIdx.x;
    for (int i = tid; i < INC * HH; i += 256) { int k = i >> 5, c = i & 31; sWT[c][k] = W[i]; }
    __syncthreads();
    int id = blockIdx.x * 256 + tid;
    int row = id >> 5, c = id & 31;
    const float4* xp = (const float4*)(x + (size_t)row * INC);
    float acc = 0.f;
#pragma unroll
    for (int kq = 0; kq < INC / 4; kq++) {
        float4 xv = xp[kq];
        float4 wv = *(const float4*)&sWT[c][kq * 4];
        acc += xv.x * wv.x + xv.y * wv.y + xv.z * wv.z + xv.w * wv.w;
    }
    xw[id] = acc;
}

// -------- GCN gather: h[d] = relu(dis[d]*(sum_in dis[s]*xw[s] + dis[d]*xw[d]) + b)
__global__ __launch_bounds__(256) void k_gcng(const int* __restrict__ ssrc, const int* __restrict__ od,
                                              const int* __restrict__ cd, const float* __restrict__ xw,
                                              const float* __restrict__ dis, const float* __restrict__ bias,
                                              float* __restrict__ h) {
    int tid = threadIdx.x;
    int n = blockIdx.x * 8 + (tid >> 5), c = tid & 31;
    int base = od[n], cnt = cd[n];
    float dn = dis[n];
    float acc = dn * xw[(size_t)n * HH + c];  // self-loop term (before outer dn)
    int i = 0;
    for (; i + 4 <= cnt; i += 4) {
        int s0 = ssrc[base + i], s1v = ssrc[base + i + 1];
        int s2 = ssrc[base + i + 2], s3 = ssrc[base + i + 3];
        float a0 = dis[s0] * xw[(size_t)s0 * HH + c];
        float a1 = dis[s1v] * xw[(size_t)s1v * HH + c];
        float a2 = dis[s2] * xw[(size_t)s2 * HH + c];
        float a3 = dis[s3] * xw[(size_t)s3 * HH + c];
        acc += (a0 + a1) + (a2 + a3);
    }
    for (; i < cnt; i++) { int s0 = ssrc[base + i]; acc += dis[s0] * xw[(size_t)s0 * HH + c]; }
    h[(size_t)n * HH + c] = fmaxf(dn * acc + bias[c], 0.f);
}

// ------- s1 = softmax(h @ pool1_W + b): THREAD-per-row, W via uniform loads
// No explicit max-subtraction (logits O(1) in fp32; ratios identical).
__global__ __launch_bounds__(128) void k_s1(const float* __restrict__ h, const float* __restrict__ W,
                                            const float* __restrict__ bias, const int* __restrict__ csrc,
                                            float* __restrict__ s1, float* __restrict__ den1) {
    int tid = threadIdx.x;
    int row = blockIdx.x * 128 + tid;
    // own h row -> 32 registers (per-lane contiguous; wave covers 8KB contiguous)
    float hr[HH];
    const float4* hp = (const float4*)(h + (size_t)row * HH);
#pragma unroll
    for (int q = 0; q < HH / 4; q++) {
        float4 a = hp[q];
        hr[4*q] = a.x; hr[4*q+1] = a.y; hr[4*q+2] = a.z; hr[4*q+3] = a.w;
    }
    float e[KP1];
    float sum = 0.f, qq = 0.f;
    // 12 groups of 8 channels (wave-uniform W/bias addresses -> scalar loads)
#pragma unroll
    for (int g8 = 0; g8 < 12; g8++) {
        const int c0 = g8 * 8;
        float a[8];
#pragma unroll
        for (int j = 0; j < 8; j++) a[j] = bias[c0 + j];
#pragma unroll
        for (int k = 0; k < HH; k++) {
            const float* wr = W + k * KP1 + c0;
#pragma unroll
            for (int j = 0; j < 8; j++) a[j] = fmaf(hr[k], wr[j], a[j]);
        }
#pragma unroll
        for (int j = 0; j < 8; j++) {
            float ev = __expf(a[j]);
            e[c0 + j] = ev; sum += ev; qq = fmaf(ev, ev, qq);
        }
    }
    { // tail group: channels 96..99
        const int c0 = 96;
        float a[4];
#pragma unroll
        for (int j = 0; j < 4; j++) a[j] = bias[c0 + j];
#pragma unroll
        for (int k = 0; k < HH; k++) {
            const float* wr = W + k * KP1 + c0;
#pragma unroll
            for (int j = 0; j < 4; j++) a[j] = fmaf(hr[k], wr[j], a[j]);
        }
#pragma unroll
        for (int j = 0; j < 4; j++) {
            float ev = __expf(a[j]);
            e[c0 + j] = ev; sum += ev; qq = fmaf(ev, ev, qq);
        }
    }
    float inv = 1.f / sum;
    float4* sp = (float4*)(s1 + (size_t)row * KP1);   // row*400B is 16B-aligned
#pragma unroll
    for (int q = 0; q < KP1 / 4; q++) {
        float4 v;
        v.x = e[4*q] * inv; v.y = e[4*q+1] * inv;
        v.z = e[4*q+2] * inv; v.w = e[4*q+3] * inv;
        sp[q] = v;
    }
    // den1 contribution: deg_out[row] * sum(s^2); wave-reduce, one atomic/wave
    float contrib = (float)csrc[row] * qq * inv * inv;
#pragma unroll
    for (int off = 32; off >= 1; off >>= 1) contrib += __shfl_xor(contrib, off);
    if ((tid & 63) == 0) atomicAdd(&den1[row >> 9], contrib);   // wave's 64 rows share a graph
}

// ------------- t1 gather: t1[s] = sum_{e: src=s} s1[dst_e]   (all 100 ch, 1 pass)
__global__ __launch_bounds__(256) void k_t1g(const int* __restrict__ sdst, const int* __restrict__ osr,
                                             const int* __restrict__ csr, const float* __restrict__ s1,
                                             float* __restrict__ t1) {
    int tid = threadIdx.x;
    int n = blockIdx.x * 2 + (tid >> 7), lane = tid & 127;
    if (lane >= KP1) return;
    int base = osr[n], cnt = csr[n];
    float acc = 0.f;
    int i = 0;
    for (; i + 4 <= cnt; i += 4) {
        int d0 = sdst[base + i], d1 = sdst[base + i + 1];
        int d2 = sdst[base + i + 2], d3 = sdst[base + i + 3];
        float a0 = s1[(size_t)d0 * KP1 + lane];
        float a1 = s1[(size_t)d1 * KP1 + lane];
        float a2 = s1[(size_t)d2 * KP1 + lane];
        float a3 = s1[(size_t)d3 * KP1 + lane];
        acc += (a0 + a1) + (a2 + a3);
    }
    for (; i < cnt; i++) { int d0 = sdst[base + i]; acc += s1[(size_t)d0 * KP1 + lane]; }
    t1[(size_t)n * KP1 + lane] = acc;
}

// --- gram: C = s1^T [t1 | h | s1]  (100 x 232) per (graph, n-half) partial
__global__ __launch_bounds__(512) void k_gram(const float* __restrict__ s1, const float* __restrict__ t1,
                                              const float* __restrict__ h, float* __restrict__ Cp) {
    __shared__ float sZ[32 * ZS];            // 30.2 KB
    int g = blockIdx.x >> 1, half = blockIdx.x & 1;
    int n0base = half * 256;
    int goff = g * NN;
    int tid = threadIdx.x;
    int wave = tid >> 6, lane = tid & 63;
    int wr = wave >> 1, wc = wave & 1;       // 4 x 2 wave grid
    int kg = wr * 4 + (lane >> 4);           // 0..15, need <13
    int lg = wc * 16 + (lane & 15);          // 0..31, need <29
    bool act = (kg < 13) && (lg < 29);
    int k0 = kg * 8, l0 = lg * 8;
    float accm[8][8];
#pragma unroll
    for (int i = 0; i < 8; i++)
#pragma unroll
        for (int j = 0; j < 8; j++) accm[i][j] = 0.f;

    for (int nt = 0; nt < 8; nt++) {
        int n0 = n0base + nt * 32;
        for (int i = tid; i < 32 * ZS; i += 512) {
            int r = i / ZS, cc = i % ZS;
            int n = goff + n0 + r;
            float val;
            if (cc < 100)      val = t1[(size_t)n * KP1 + cc];
            else if (cc < 132) val = h[(size_t)n * HH + (cc - 100)];
            else if (cc < 232) val = s1[(size_t)n * KP1 + (cc - 132)];
            else               val = 0.f;
            sZ[r * ZS + cc] = val;
        }
        __syncthreads();
        if (act) {
            for (int r = 0; r < 32; r++) {
                const float* zr = &sZ[r * ZS];
                float4 a0 = *(const float4*)&zr[132 + k0];
                float4 a1 = *(const float4*)&zr[132 + k0 + 4];
                float4 b0 = *(const float4*)&zr[l0];
                float4 b1 = *(const float4*)&zr[l0 + 4];
                float av[8] = {a0.x, a0.y, a0.z, a0.w, a1.x, a1.y, a1.z, a1.w};
                float bv[8] = {b0.x, b0.y, b0.z, b0.w, b1.x, b1.y, b1.z, b1.w};
#pragma unroll
                for (int i = 0; i < 8; i++)
#pragma unroll
                    for (int j = 0; j < 8; j++) accm[i][j] = fmaf(av[i], bv[j], accm[i][j]);
            }
        }
        __syncthreads();
    }
    if (act) {
        float* out = Cp + ((size_t)half * TB + g) * (KP1 * 232);
#pragma unroll
        for (int i = 0; i < 8; i++) {
            int k = k0 + i;
            if (k < KP1) {
#pragma unroll
                for (int j = 0; j < 8; j++) out[k * 232 + l0 + j] = accm[i][j];
            }
        }
    }
}

// ---- finalize stage 1: sum halves, losses, normalize out_adj, emit P1
__global__ __launch_bounds__(128) void k_fin1(const float* __restrict__ Cp, const float* __restrict__ den1,
                                              float* __restrict__ A1n, float* __restrict__ P1,
                                              float* __restrict__ aux) {
    __shared__ float sA[KP1 * KP1];          // 40 KB
    __shared__ float sd[KP1];
    __shared__ float r1[128], r2[128], r3[128];
    int g = blockIdx.x, tid = threadIdx.x;
    const float* c0 = Cp + (size_t)g * (KP1 * 232);
    const float* c1 = Cp + ((size_t)TB + g) * (KP1 * 232);
    float ssq = 0.f, troa = 0.f, trss = 0.f;
    if (tid < KP1) {
        int k = tid;
        float rs = 0.f;
        for (int l = 0; l < KP1; l++) {
            float oa = c0[k * 232 + l] + c1[k * 232 + l];
            sA[k * KP1 + l] = oa;
            if (l != k) rs += oa; else troa += oa;
            float ssv = c0[k * 232 + 132 + l] + c1[k * 232 + 132 + l];
            ssq += ssv * ssv;
            if (l == k) trss += ssv;
        }
        sd[k] = sqrtf(rs) + 1e-15f;
        for (int cc = 0; cc < HH; cc++)
            P1[((size_t)g * KP1 + k) * HH + cc] = c0[k * 232 + 100 + cc] + c1[k * 232 + 100 + cc];
    }
    r1[tid] = ssq; r2[tid] = troa; r3[tid] = trss; __syncthreads();
#pragma unroll
    for (int s = 64; s > 0; s >>= 1) {
        if (tid < s) { r1[tid] += r1[tid + s]; r2[tid] += r2[tid + s]; r3[tid] += r3[tid + s]; }
        __syncthreads();
    }
    if (tid == 0) {
        float ssF = sqrtf(r1[0]);
        float o1 = sqrtf(fmaxf(2.f - 2.f * r3[0] / (ssF * 10.f), 0.f));  // sqrt(K1)=10
        aux[128 + g] = -(r2[0] / den1[g]) + o1;
    }
    __syncthreads();
    for (int i = tid; i < KP1 * KP1; i += 128) {
        int k = i / KP1, l = i % KP1;
        A1n[(size_t)g * (KP1 * KP1) + i] = (k == l) ? 0.f : sA[i] / (sd[k] * sd[l]);
    }
}

// ------- stage 2a: conv2 + pool2 (per graph); A read from global (L2)
__global__ __launch_bounds__(512) void k_s2a(const float* __restrict__ A1n, const float* __restrict__ P1,
                                             const float* __restrict__ relW, const float* __restrict__ relB,
                                             const float* __restrict__ rootW,
                                             const float* __restrict__ p2W, const float* __restrict__ p2B,
                                             float* __restrict__ P2, float* __restrict__ A2n,
                                             float* __restrict__ aux) {
    __shared__ float sX[KP1 * HH];           // x1p then x2
    __shared__ float sY[KP1 * HH];           // y = A @ x1p
    __shared__ float sS2[KP1 * KP2];
    __shared__ float sT2[KP1 * KP2];
    __shared__ float sA2[100], sB2[100], sdd[10], red[100];
    int g = blockIdx.x, tid = threadIdx.x;
    const float* Ag = A1n + (size_t)g * (KP1 * KP1);
    for (int i = tid; i < KP1 * HH; i += 512) sX[i] = P1[(size_t)g * (KP1 * HH) + i];
    __syncthreads();

    int n = tid >> 2, cq = tid & 3;          // 400 active threads for y / x2
    // y = A @ x1p
    if (tid < 400) {
        float yv[8];
#pragma unroll
        for (int j = 0; j < 8; j++) yv[j] = 0.f;
        for (int mq = 0; mq < 25; mq++) {
            float4 a4 = *(const float4*)&Ag[n * KP1 + mq * 4];
            const float* xb = &sX[(mq * 4) * HH + cq * 8];
            float aa[4] = {a4.x, a4.y, a4.z, a4.w};
#pragma unroll
            for (int mm = 0; mm < 4; mm++) {
                const float* xr = xb + mm * HH;
#pragma unroll
                for (int j = 0; j < 8; j++) yv[j] = fmaf(aa[mm], xr[j], yv[j]);
            }
        }
#pragma unroll
        for (int j = 0; j < 8; j++) sY[n * HH + cq * 8 + j] = yv[j];
    }
    __syncthreads();
    // x2 = relu(y @ relW + relB + x1p @ rootW)
    float x2v[8];
    if (tid < 400) {
#pragma unroll
        for (int j = 0; j < 8; j++) x2v[j] = relB[cq * 8 + j];
        for (int j = 0; j < 32; j++) {
            float yj = sY[n * HH + j];
            float xj = sX[n * HH + j];
            float4 r0 = *(const float4*)&relW[j * 32 + cq * 8];
            float4 r1v = *(const float4*)&relW[j * 32 + cq * 8 + 4];
            float4 q0 = *(const float4*)&rootW[j * 32 + cq * 8];
            float4 q1 = *(const float4*)&rootW[j * 32 + cq * 8 + 4];
            x2v[0] += yj * r0.x + xj * q0.x;  x2v[1] += yj * r0.y + xj * q0.y;
            x2v[2] += yj * r0.z + xj * q0.z;  x2v[3] += yj * r0.w + xj * q0.w;
            x2v[4] += yj * r1v.x + xj * q1.x; x2v[5] += yj * r1v.y + xj * q1.y;
            x2v[6] += yj * r1v.z + xj * q1.z; x2v[7] += yj * r1v.w + xj * q1.w;
        }
    }
    __syncthreads();
    if (tid < 400) {
#pragma unroll
        for (int j = 0; j < 8; j++) sX[n * HH + cq * 8 + j] = fmaxf(x2v[j], 0.f);
    }
    __syncthreads();
    // s2 = softmax(x2 @ p2W + p2B); d2 and den2 partials
    if (tid < KP1) {
        float lg[10];
#pragma unroll
        for (int j = 0; j < 10; j++) lg[j] = p2B[j];
        for (int c = 0; c < 32; c++) {
            float xv = sX[tid * HH + c];
#pragma unroll
            for (int j = 0; j < 10; j++) lg[j] = fmaf(xv, p2W[c * 10 + j], lg[j]);
        }
        float mx = lg[0];
#pragma unroll
        for (int j = 1; j < 10; j++) mx = fmaxf(mx, lg[j]);
        float se = 0.f;
#pragma unroll
        for (int j = 0; j < 10; j++) { lg[j] = __expf(lg[j] - mx); se += lg[j]; }
        float inv = 1.f / se, sq = 0.f;
#pragma unroll
        for (int j = 0; j < 10; j++) { float sv = lg[j] * inv; sS2[tid * 10 + j] = sv; sq += sv * sv; }
        float d2 = 0.f;
        for (int mq = 0; mq < 25; mq++) {
            float4 a4 = *(const float4*)&Ag[tid * KP1 + mq * 4];
            d2 += a4.x + a4.y + a4.z + a4.w;
        }
        red[tid] = d2 * sq;
    }
    __syncthreads();
    // t2 = A @ s2 ; P2 = s2^T x2
    for (int p = tid; p < KP1 * KP2; p += 512) {
        int n2 = p / 10, jj = p % 10;
        float a = 0.f;
        for (int m = 0; m < KP1; m++) a = fmaf(Ag[n2 * KP1 + m], sS2[m * 10 + jj], a);
        sT2[p] = a;
    }
    if (tid < KP2 * HH) {
        int k = tid >> 5, cc = tid & 31;
        float a = 0.f;
        for (int n2 = 0; n2 < KP1; n2++) a = fmaf(sS2[n2 * 10 + k], sX[n2 * HH + cc], a);
        P2[(size_t)g * (KP2 * HH) + tid] = a;
    }
    __syncthreads();
    // oa2, ss2
    if (tid < 100) {
        int k = tid / 10, l = tid % 10;
        float oa = 0.f, ss = 0.f;
        for (int n2 = 0; n2 < KP1; n2++) {
            float sk = sS2[n2 * 10 + k];
            oa = fmaf(sk, sT2[n2 * 10 + l], oa);
            ss = fmaf(sk, sS2[n2 * 10 + l], ss);
        }
        sA2[tid] = oa; sB2[tid] = ss;
    }
    __syncthreads();
    if (tid == 0) {
        float den2 = 0.f;
        for (int i = 0; i < 100; i++) den2 += red[i];
        float troa = 0.f, trss = 0.f, ssq = 0.f;
        for (int k = 0; k < 10; k++) { troa += sA2[k * 10 + k]; trss += sB2[k * 10 + k]; }
        for (int i = 0; i < 100; i++) ssq += sB2[i] * sB2[i];
        float o2 = sqrtf(fmaxf(2.f - 2.f * trss / (sqrtf(ssq) * 3.16227766f), 0.f)); // sqrt(10)
        aux[256 + g] = -(troa / den2) + o2;
    }
    if (tid < 10) {
        float rs = 0.f;
        for (int l = 0; l < 10; l++) if (l != tid) rs += sA2[tid * 10 + l];
        sdd[tid] = sqrtf(rs) + 1e-15f;
    }
    __syncthreads();
    if (tid < 100) {
        int k = tid / 10, l = tid % 10;
        A2n[(size_t)g * 100 + tid] = (k == l) ? 0.f : sA2[tid] / (sdd[k] * sdd[l]);
    }
}

// ---------------- stage 2b: conv3 + mean + MLP head + log_softmax
__global__ __launch_bounds__(64) void k_s2b(const float* __restrict__ P2, const float* __restrict__ A2n,
                                            const float* __restrict__ relW3, const float* __restrict__ relb3,
                                            const float* __restrict__ rootW3,
                                            const float* __restrict__ l1W, const float* __restrict__ l1b,
                                            const float* __restrict__ l2W, const float* __restrict__ l2b,
                                            float* __restrict__ out) {
    __shared__ float sP[KP2 * HH], sA2[100], sY3[KP2 * HH], sG[32], sG1[32], sL[10], sLse;
    int g = blockIdx.x, tid = threadIdx.x;
    for (int i = tid; i < KP2 * HH; i += 64) sP[i] = P2[(size_t)g * (KP2 * HH) + i];
    for (int i = tid; i < 100; i += 64) sA2[i] = A2n[(size_t)g * 100 + i];
    if (tid < 32) sG[tid] = 0.f;
    __syncthreads();
    for (int p = tid; p < KP2 * HH; p += 64) {
        int k = p >> 5, cc = p & 31;
        float a = 0.f;
#pragma unroll
        for (int m = 0; m < 10; m++) a = fmaf(sA2[k * 10 + m], sP[m * HH + cc], a);
        sY3[p] = a;
    }
    __syncthreads();
    for (int p = tid; p < KP2 * HH; p += 64) {
        int k = p >> 5, cc = p & 31;
        float v = relb3[cc];
        for (int j = 0; j < 32; j++)
            v += sY3[k * HH + j] * relW3[j * 32 + cc] + sP[k * HH + j] * rootW3[j * 32 + cc];
        atomicAdd(&sG[cc], v * 0.1f);        // mean over 10 nodes
    }
    __syncthreads();
    if (tid < 32) {
        float v = l1b[tid];
        for (int j = 0; j < 32; j++) v = fmaf(sG[j], l1W[j * 32 + tid], v);
        sG1[tid] = fmaxf(v, 0.f);
    }
    __syncthreads();
    if (tid < 10) {
        float v = l2b[tid];
        for (int j = 0; j < 32; j++) v = fmaf(sG1[j], l2W[j * 10 + tid], v);
        sL[tid] = v;
    }
    __syncthreads();
    if (tid == 0) {
        float mx = sL[0];
        for (int j = 1; j < 10; j++) mx = fmaxf(mx, sL[j]);
        float se = 0.f;
        for (int j = 0; j < 10; j++) se += expf(sL[j] - mx);
        sLse = mx + logf(se);
    }
    __syncthreads();
    if (tid < 10) out[(size_t)g * 10 + tid] = sL[tid] - sLse;
}

// ------------------------------------------------------ total loss
__global__ void k_loss(const float* __restrict__ aux, float* __restrict__ out) {
    __shared__ float red[128];
    int tid = threadIdx.x;
    red[tid] = aux[128 + tid] + aux[256 + tid];
    __syncthreads();
#pragma unroll
    for (int s = 64; s > 0; s >>= 1) { if (tid < s) red[tid] += red[tid + s]; __syncthreads(); }
    if (tid == 0) out[1280] = red[0] * (1.f / 128.f);
}

extern "C" void kernel_launch(void* const* d_in, const int* in_sizes, int n_in,
                              void* d_out, int out_size, void* d_ws, size_t ws_size,
                              hipStream_t stream) {
    const float* x    = (const float*)d_in[0];
    const int*   ei   = (const int*)d_in[1];
    const float* c1W  = (const float*)d_in[3];
    const float* c1b  = (const float*)d_in[4];
    const float* p1W  = (const float*)d_in[5];
    const float* p1b  = (const float*)d_in[6];
    const float* relW2  = (const float*)d_in[7];
    const float* relb2  = (const float*)d_in[8];
    const float* rootW2 = (const float*)d_in[9];
    const float* p2W  = (const float*)d_in[10];
    const float* p2b  = (const float*)d_in[11];
    const float* relW3  = (const float*)d_in[12];
    const float* relb3  = (const float*)d_in[13];
    const float* rootW3 = (const float*)d_in[14];
    const float* l1W  = (const float*)d_in[15];
    const float* l1b  = (const float*)d_in[16];
    const float* l2W  = (const float*)d_in[17];
    const float* l2b  = (const float*)d_in[18];
    float* out = (float*)d_out;

    // ---- workspace layout
    int*  cnt_src = (int*)d_ws;                       // NT
    int*  cnt_dst = cnt_src + NT;                     // NT
    int*  off_src = cnt_dst + NT;                     // NT
    int*  off_dst = off_src + NT;                     // NT
    int*  cur_src = off_dst + NT;                     // NT
    int*  cur_dst = cur_src + NT;                     // NT
    int*  srt_dst = cur_dst + NT;                     // ET (src-sorted, stores dst)
    int*  srt_src = srt_dst + ET;                     // ET (dst-sorted, stores src)
    float* dis = (float*)(srt_src + ET);              // NT
    float* xw   = dis + NT;                           // NT*HH
    float* h    = xw + (size_t)NT * HH;               // NT*HH
    float* s1   = h + (size_t)NT * HH;                // NT*KP1
    float* t1   = s1 + (size_t)NT * KP1;              // NT*KP1
    float* Cp   = t1 + (size_t)NT * KP1;              // 2*TB*KP1*232
    float* A1n  = Cp + (size_t)2 * TB * (KP1 * 232);  // TB*KP1*KP1
    float* P1   = A1n + (size_t)TB * KP1 * KP1;       // TB*KP1*HH
    float* P2   = P1 + (size_t)TB * KP1 * HH;         // TB*KP2*HH
    float* A2n  = P2 + (size_t)TB * KP2 * HH;         // TB*100
    float* aux  = A2n + (size_t)TB * 100;             // 1024: den1|loss1|loss2

    k_init<<<NT / 256, 256, 0, stream>>>(cnt_src, cnt_dst, aux);
    k_cnt<<<ET / 256, 256, 0, stream>>>(ei, cnt_src, cnt_dst);
    k_scan<<<TB, 512, 0, stream>>>(cnt_src, cnt_dst, off_src, off_dst, cur_src, cur_dst);
    k_scatter<<<ET / 256, 256, 0, stream>>>(ei, cur_src, cur_dst, srt_dst, srt_src);
    k_dis<<<NT / 256, 256, 0, stream>>>(cnt_dst, dis);
    k_xw<<<(NT * HH) / 256, 256, 0, stream>>>(x, c1W, xw);
    k_gcng<<<NT / 8, 256, 0, stream>>>(srt_src, off_dst, cnt_dst, xw, dis, c1b, h);
    k_s1<<<NT / 128, 128, 0, stream>>>(h, p1W, p1b, cnt_src, s1, aux /*den1*/);
    k_t1g<<<NT / 2, 256, 0, stream>>>(srt_dst, off_src, cnt_src, s1, t1);
    k_gram<<<TB * 2, 512, 0, stream>>>(s1, t1, h, Cp);
    k_fin1<<<TB, 128, 0, stream>>>(Cp, aux /*den1*/, A1n, P1, aux);
    k_s2a<<<TB, 512, 0, stream>>>(A1n, P1, relW2, relb2, rootW2, p2W, p2b, P2, A2n, aux);
    k_s2b<<<TB, 64, 0, stream>>>(P2, A2n, relW3, relb3, rootW3, l1W, l1b, l2W, l2b, out);
    k_loss<<<1, 128, 0, stream>>>(aux, out);
}

// Round 5
// 573.385 us; speedup vs baseline: 2.8646x; 1.0217x over previous
//
#include <hip/hip_runtime.h>
#include <hip/hip_bf16.h>

// Problem constants (match reference)
#define TB   128          // batch B
#define NN   512          // nodes per graph
#define INC  128          // IN_C
#define HH   32           // HID
#define KP1  100          // K1
#define KP2  10           // K2
#define OC   10           // OUT_C
#define EPER 8192         // edges per graph
#define NT   (TB*NN)      // 65536 total nodes
#define ET   (TB*EPER)    // 1048576 total edges
#define ZS   236          // gram Z tile stride (100 t + 32 h + 100 s + 4 pad)
#define ZF4  59           // float4s per Z row (25 t1 + 8 h + 25 s1 + 1 pad)

// ---------------------------------------------------------------- init
__global__ void k_init(int* __restrict__ cs, int* __restrict__ cd, float* __restrict__ aux) {
    int i = blockIdx.x * 256 + threadIdx.x;
    if (i < NT) { cs[i] = 0; cd[i] = 0; }
    if (i < 1024) aux[i] = 0.0f;              // den1 / loss1 / loss2 accumulators
}

// ---------------------------------------------- edge degree histograms
__global__ void k_cnt(const int* __restrict__ ei, int* __restrict__ cs, int* __restrict__ cd) {
    int e = blockIdx.x * 256 + threadIdx.x;
    if (e < ET) {
        atomicAdd(&cs[ei[e]], 1);             // out-degree (src)  = adj.sum(-1)
        atomicAdd(&cd[ei[ET + e]], 1);        // in-degree  (dst)  for GCN norm
    }
}

// ---------------- per-graph exclusive scan of both degree histograms
__global__ __launch_bounds__(512) void k_scan(const int* __restrict__ cs, const int* __restrict__ cd,
                                              int* __restrict__ os, int* __restrict__ od,
                                              int* __restrict__ curs, int* __restrict__ curd) {
    __shared__ int sa[512], sb[512];
    int g = blockIdx.x, tid = threadIdx.x, i = g * NN + tid;
    int vs = cs[i], vd = cd[i];
    sa[tid] = vs; sb[tid] = vd; __syncthreads();
    for (int off = 1; off < 512; off <<= 1) {
        int xa = sa[tid], xb = sb[tid];
        if (tid >= off) { xa += sa[tid - off]; xb += sb[tid - off]; }
        __syncthreads(); sa[tid] = xa; sb[tid] = xb; __syncthreads();
    }
    int es = g * EPER + sa[tid] - vs;         // exclusive scan, global position
    int ed = g * EPER + sb[tid] - vd;
    os[i] = es; od[i] = ed; curs[i] = es; curd[i] = ed;
}

// ----------------- counting-sort scatter: edges by src and by dst
__global__ void k_scatter(const int* __restrict__ ei, int* __restrict__ curs, int* __restrict__ curd,
                          int* __restrict__ sdst, int* __restrict__ ssrc) {
    int e = blockIdx.x * 256 + threadIdx.x;
    if (e < ET) {
        int s = ei[e], d = ei[ET + e];
        int p = atomicAdd(&curs[s], 1); sdst[p] = d;   // src-sorted: store dst
        int q = atomicAdd(&curd[d], 1); ssrc[q] = s;   // dst-sorted: store src
    }
}

__global__ void k_dis(const int* __restrict__ cd, float* __restrict__ dis) {
    int i = blockIdx.x * 256 + threadIdx.x;
    if (i < NT) dis[i] = rsqrtf(1.0f + (float)cd[i]);  // +1 self loop
}

// ------------------------------------------------ xw = x @ conv1_W  [NT,32]
__global__ __launch_bounds__(256) void k_xw(const float* __restrict__ x, const float* __restrict__ W,
                                            float* __restrict__ xw) {
    __shared__ float sWT[32][132];           // W^T, padded stride
    int tid = threadIdx.x;
    for (int i = tid; i < INC * HH; i += 256) { int k = i >> 5, c = i & 31; sWT[c][k] = W[i]; }
    __syncthreads();
    int id = blockIdx.x * 256 + tid;
    int row = id >> 5, c = id & 31;
    const float4* xp = (const float4*)(x + (size_t)row * INC);
    float acc = 0.f;
#pragma unroll
    for (int kq = 0; kq < INC / 4; kq++) {
        float4 xv = xp[kq];
        float4 wv = *(const float4*)&sWT[c][kq * 4];
        acc += xv.x * wv.x + xv.y * wv.y + xv.z * wv.z + xv.w * wv.w;
    }
    xw[id] = acc;
}

// -------- GCN gather: h[d] = relu(dis[d]*(sum_in dis[s]*xw[s] + dis[d]*xw[d]) + b)
__global__ __launch_bounds__(256) void k_gcng(const int* __restrict__ ssrc, const int* __restrict__ od,
                                              const int* __restrict__ cd, const float* __restrict__ xw,
                                              const float* __restrict__ dis, const float* __restrict__ bias,
                                              float* __restrict__ h) {
    int tid = threadIdx.x;
    int n = blockIdx.x * 8 + (tid >> 5), c = tid & 31;
    int base = od[n], cnt = cd[n];
    float dn = dis[n];
    float acc = dn * xw[(size_t)n * HH + c];  // self-loop term (before outer dn)
    int i = 0;
    for (; i + 4 <= cnt; i += 4) {
        int s0 = ssrc[base + i], s1v = ssrc[base + i + 1];
        int s2 = ssrc[base + i + 2], s3 = ssrc[base + i + 3];
        float a0 = dis[s0] * xw[(size_t)s0 * HH + c];
        float a1 = dis[s1v] * xw[(size_t)s1v * HH + c];
        float a2 = dis[s2] * xw[(size_t)s2 * HH + c];
        float a3 = dis[s3] * xw[(size_t)s3 * HH + c];
        acc += (a0 + a1) + (a2 + a3);
    }
    for (; i < cnt; i++) { int s0 = ssrc[base + i]; acc += dis[s0] * xw[(size_t)s0 * HH + c]; }
    h[(size_t)n * HH + c] = fmaxf(dn * acc + bias[c], 0.f);
}

// ------- s1 = softmax(h @ pool1_W + b): THREAD-per-row, W via uniform loads
// No explicit max-subtraction (logits O(1) in fp32; ratios identical).
__global__ __launch_bounds__(128) void k_s1(const float* __restrict__ h, const float* __restrict__ W,
                                            const float* __restrict__ bias, const int* __restrict__ csrc,
                                            float* __restrict__ s1, float* __restrict__ den1) {
    int tid = threadIdx.x;
    int row = blockIdx.x * 128 + tid;
    float hr[HH];
    const float4* hp = (const float4*)(h + (size_t)row * HH);
#pragma unroll
    for (int q = 0; q < HH / 4; q++) {
        float4 a = hp[q];
        hr[4*q] = a.x; hr[4*q+1] = a.y; hr[4*q+2] = a.z; hr[4*q+3] = a.w;
    }
    float e[KP1];
    float sum = 0.f, qq = 0.f;
#pragma unroll
    for (int g8 = 0; g8 < 12; g8++) {
        const int c0 = g8 * 8;
        float a[8];
#pragma unroll
        for (int j = 0; j < 8; j++) a[j] = bias[c0 + j];
#pragma unroll
        for (int k = 0; k < HH; k++) {
            const float* wr = W + k * KP1 + c0;
#pragma unroll
            for (int j = 0; j < 8; j++) a[j] = fmaf(hr[k], wr[j], a[j]);
        }
#pragma unroll
        for (int j = 0; j < 8; j++) {
            float ev = __expf(a[j]);
            e[c0 + j] = ev; sum += ev; qq = fmaf(ev, ev, qq);
        }
    }
    { // tail group: channels 96..99
        const int c0 = 96;
        float a[4];
#pragma unroll
        for (int j = 0; j < 4; j++) a[j] = bias[c0 + j];
#pragma unroll
        for (int k = 0; k < HH; k++) {
            const float* wr = W + k * KP1 + c0;
#pragma unroll
            for (int j = 0; j < 4; j++) a[j] = fmaf(hr[k], wr[j], a[j]);
        }
#pragma unroll
        for (int j = 0; j < 4; j++) {
            float ev = __expf(a[j]);
            e[c0 + j] = ev; sum += ev; qq = fmaf(ev, ev, qq);
        }
    }
    float inv = 1.f / sum;
    float4* sp = (float4*)(s1 + (size_t)row * KP1);
#pragma unroll
    for (int q = 0; q < KP1 / 4; q++) {
        float4 v;
        v.x = e[4*q] * inv; v.y = e[4*q+1] * inv;
        v.z = e[4*q+2] * inv; v.w = e[4*q+3] * inv;
        sp[q] = v;
    }
    float contrib = (float)csrc[row] * qq * inv * inv;
#pragma unroll
    for (int off = 32; off >= 1; off >>= 1) contrib += __shfl_xor(contrib, off);
    if ((tid & 63) == 0) atomicAdd(&den1[row >> 9], contrib);
}

// ------------- t1 gather: t1[s] = sum_{e: src=s} s1[dst_e]   (all 100 ch, 1 pass)
__global__ __launch_bounds__(256) void k_t1g(const int* __restrict__ sdst, const int* __restrict__ osr,
                                             const int* __restrict__ csr, const float* __restrict__ s1,
                                             float* __restrict__ t1) {
    int tid = threadIdx.x;
    int n = blockIdx.x * 2 + (tid >> 7), lane = tid & 127;
    if (lane >= KP1) return;
    int base = osr[n], cnt = csr[n];
    float acc = 0.f;
    int i = 0;
    for (; i + 4 <= cnt; i += 4) {
        int d0 = sdst[base + i], d1 = sdst[base + i + 1];
        int d2 = sdst[base + i + 2], d3 = sdst[base + i + 3];
        float a0 = s1[(size_t)d0 * KP1 + lane];
        float a1 = s1[(size_t)d1 * KP1 + lane];
        float a2 = s1[(size_t)d2 * KP1 + lane];
        float a3 = s1[(size_t)d3 * KP1 + lane];
        acc += (a0 + a1) + (a2 + a3);
    }
    for (; i < cnt; i++) { int d0 = sdst[base + i]; acc += s1[(size_t)d0 * KP1 + lane]; }
    t1[(size_t)n * KP1 + lane] = acc;
}

// --- gram: C = s1^T [t1 | h | s1] (100 x 232); 4 n-slabs/graph, dbuf LDS
__global__ __launch_bounds__(512, 4) void k_gram(const float* __restrict__ s1, const float* __restrict__ t1,
                                                 const float* __restrict__ h, float* __restrict__ Cp) {
    __shared__ float sZ[2][32 * ZS];         // 2 x 30.2 KB
    int g = blockIdx.x >> 2, slab = blockIdx.x & 3;
    int n0base = slab * 128;                 // 4 tiles of 32 rows
    int goff = g * NN;
    int tid = threadIdx.x;
    int wave = tid >> 6, lane = tid & 63;
    int wr = wave >> 1, wc = wave & 1;       // 4 x 2 wave grid
    int kg = wr * 4 + (lane >> 4);           // 0..15, need <13
    int lg = wc * 16 + (lane & 15);          // 0..31, need <29
    bool act = (kg < 13) && (lg < 29);
    int k0 = kg * 8, l0 = lg * 8;
    float accm[8][8];
#pragma unroll
    for (int i = 0; i < 8; i++)
#pragma unroll
        for (int j = 0; j < 8; j++) accm[i][j] = 0.f;

    // ---- prologue: stage tile 0 into buffer 0 (float4 granularity)
#pragma unroll
    for (int j = 0; j < 4; j++) {
        int i = tid + j * 512;
        if (i < 32 * ZF4) {
            int r = i / ZF4, q = i - r * ZF4;
            int n = goff + n0base + r;
            float4 v;
            if (q < 25)      v = ((const float4*)(t1 + (size_t)n * KP1))[q];
            else if (q < 33) v = ((const float4*)(h  + (size_t)n * HH ))[q - 25];
            else if (q < 58) v = ((const float4*)(s1 + (size_t)n * KP1))[q - 33];
            else             v = make_float4(0.f, 0.f, 0.f, 0.f);
            *(float4*)&sZ[0][r * ZS + q * 4] = v;
        }
    }
    __syncthreads();

    for (int nt = 0; nt < 4; nt++) {
        // ---- issue prefetch of tile nt+1 into registers
        float4 pre[4];
        if (nt < 3) {
            int n0 = n0base + (nt + 1) * 32;
#pragma unroll
            for (int j = 0; j < 4; j++) {
                int i = tid + j * 512;
                if (i < 32 * ZF4) {
                    int r = i / ZF4, q = i - r * ZF4;
                    int n = goff + n0 + r;
                    float4 v;
                    if (q < 25)      v = ((const float4*)(t1 + (size_t)n * KP1))[q];
                    else if (q < 33) v = ((const float4*)(h  + (size_t)n * HH ))[q - 25];
                    else if (q < 58) v = ((const float4*)(s1 + (size_t)n * KP1))[q - 33];
                    else             v = make_float4(0.f, 0.f, 0.f, 0.f);
                    pre[j] = v;
                }
            }
        }
        // ---- compute on current buffer
        const float* zb = sZ[nt & 1];
        if (act) {
            for (int r = 0; r < 32; r++) {
                const float* zr = &zb[r * ZS];
                float4 a0 = *(const float4*)&zr[132 + k0];
                float4 a1 = *(const float4*)&zr[132 + k0 + 4];
                float4 b0 = *(const float4*)&zr[l0];
                float4 b1 = *(const float4*)&zr[l0 + 4];
                float av[8] = {a0.x, a0.y, a0.z, a0.w, a1.x, a1.y, a1.z, a1.w};
                float bv[8] = {b0.x, b0.y, b0.z, b0.w, b1.x, b1.y, b1.z, b1.w};
#pragma unroll
                for (int i = 0; i < 8; i++)
#pragma unroll
                    for (int j = 0; j < 8; j++) accm[i][j] = fmaf(av[i], bv[j], accm[i][j]);
            }
        }
        // ---- commit prefetch to the other buffer
        if (nt < 3) {
            float* zo = sZ[(nt + 1) & 1];
#pragma unroll
            for (int j = 0; j < 4; j++) {
                int i = tid + j * 512;
                if (i < 32 * ZF4) {
                    int r = i / ZF4, q = i - r * ZF4;
                    *(float4*)&zo[r * ZS + q * 4] = pre[j];
                }
            }
        }
        __syncthreads();
    }
    if (act) {
        float* out = Cp + ((size_t)slab * TB + g) * (KP1 * 232);
#pragma unroll
        for (int i = 0; i < 8; i++) {
            int k = k0 + i;
            if (k < KP1) {
#pragma unroll
                for (int j = 0; j < 8; j++) out[k * 232 + l0 + j] = accm[i][j];
            }
        }
    }
}

// ---- finalize stage 1: sum 4 slabs, losses, normalize out_adj, emit P1
__global__ __launch_bounds__(128) void k_fin1(const float* __restrict__ Cp, const float* __restrict__ den1,
                                              float* __restrict__ A1n, float* __restrict__ P1,
                                              float* __restrict__ aux) {
    __shared__ float sA[KP1 * KP1];          // 40 KB
    __shared__ float sd[KP1];
    __shared__ float r1[128], r2[128], r3[128];
    int g = blockIdx.x, tid = threadIdx.x;
    const float* c0 = Cp + (size_t)g * (KP1 * 232);
    const float* c1 = Cp + ((size_t)TB + g) * (KP1 * 232);
    const float* c2 = Cp + ((size_t)2 * TB + g) * (KP1 * 232);
    const float* c3 = Cp + ((size_t)3 * TB + g) * (KP1 * 232);
    float ssq = 0.f, troa = 0.f, trss = 0.f;
    if (tid < KP1) {
        int k = tid;
        float rs = 0.f;
        for (int l = 0; l < KP1; l++) {
            float oa = (c0[k * 232 + l] + c1[k * 232 + l]) + (c2[k * 232 + l] + c3[k * 232 + l]);
            sA[k * KP1 + l] = oa;
            if (l != k) rs += oa; else troa += oa;
            float ssv = (c0[k * 232 + 132 + l] + c1[k * 232 + 132 + l])
                      + (c2[k * 232 + 132 + l] + c3[k * 232 + 132 + l]);
            ssq += ssv * ssv;
            if (l == k) trss += ssv;
        }
        sd[k] = sqrtf(rs) + 1e-15f;
        for (int cc = 0; cc < HH; cc++)
            P1[((size_t)g * KP1 + k) * HH + cc] =
                (c0[k * 232 + 100 + cc] + c1[k * 232 + 100 + cc])
              + (c2[k * 232 + 100 + cc] + c3[k * 232 + 100 + cc]);
    }
    r1[tid] = ssq; r2[tid] = troa; r3[tid] = trss; __syncthreads();
#pragma unroll
    for (int s = 64; s > 0; s >>= 1) {
        if (tid < s) { r1[tid] += r1[tid + s]; r2[tid] += r2[tid + s]; r3[tid] += r3[tid + s]; }
        __syncthreads();
    }
    if (tid == 0) {
        float ssF = sqrtf(r1[0]);
        float o1 = sqrtf(fmaxf(2.f - 2.f * r3[0] / (ssF * 10.f), 0.f));  // sqrt(K1)=10
        aux[128 + g] = -(r2[0] / den1[g]) + o1;
    }
    __syncthreads();
    for (int i = tid; i < KP1 * KP1; i += 128) {
        int k = i / KP1, l = i % KP1;
        A1n[(size_t)g * (KP1 * KP1) + i] = (k == l) ? 0.f : sA[i] / (sd[k] * sd[l]);
    }
}

// ------- stage 2a: conv2 + pool2 (per graph); A read from global (L2)
__global__ __launch_bounds__(512) void k_s2a(const float* __restrict__ A1n, const float* __restrict__ P1,
                                             const float* __restrict__ relW, const float* __restrict__ relB,
                                             const float* __restrict__ rootW,
                                             const float* __restrict__ p2W, const float* __restrict__ p2B,
                                             float* __restrict__ P2, float* __restrict__ A2n,
                                             float* __restrict__ aux) {
    __shared__ float sX[KP1 * HH];           // x1p then x2
    __shared__ float sY[KP1 * HH];           // y = A @ x1p
    __shared__ float sS2[KP1 * KP2];
    __shared__ float sT2[KP1 * KP2];
    __shared__ float sA2[100], sB2[100], sdd[10], red[100];
    int g = blockIdx.x, tid = threadIdx.x;
    const float* Ag = A1n + (size_t)g * (KP1 * KP1);
    for (int i = tid; i < KP1 * HH; i += 512) sX[i] = P1[(size_t)g * (KP1 * HH) + i];
    __syncthreads();

    int n = tid >> 2, cq = tid & 3;          // 400 active threads for y / x2
    // y = A @ x1p
    if (tid < 400) {
        float yv[8];
#pragma unroll
        for (int j = 0; j < 8; j++) yv[j] = 0.f;
        for (int mq = 0; mq < 25; mq++) {
            float4 a4 = *(const float4*)&Ag[n * KP1 + mq * 4];
            const float* xb = &sX[(mq * 4) * HH + cq * 8];
            float aa[4] = {a4.x, a4.y, a4.z, a4.w};
#pragma unroll
            for (int mm = 0; mm < 4; mm++) {
                const float* xr = xb + mm * HH;
#pragma unroll
                for (int j = 0; j < 8; j++) yv[j] = fmaf(aa[mm], xr[j], yv[j]);
            }
        }
#pragma unroll
        for (int j = 0; j < 8; j++) sY[n * HH + cq * 8 + j] = yv[j];
    }
    __syncthreads();
    // x2 = relu(y @ relW + relB + x1p @ rootW)
    float x2v[8];
    if (tid < 400) {
#pragma unroll
        for (int j = 0; j < 8; j++) x2v[j] = relB[cq * 8 + j];
        for (int j = 0; j < 32; j++) {
            float yj = sY[n * HH + j];
            float xj = sX[n * HH + j];
            float4 r0 = *(const float4*)&relW[j * 32 + cq * 8];
            float4 r1v = *(const float4*)&relW[j * 32 + cq * 8 + 4];
            float4 q0 = *(const float4*)&rootW[j * 32 + cq * 8];
            float4 q1 = *(const float4*)&rootW[j * 32 + cq * 8 + 4];
            x2v[0] += yj * r0.x + xj * q0.x;  x2v[1] += yj * r0.y + xj * q0.y;
            x2v[2] += yj * r0.z + xj * q0.z;  x2v[3] += yj * r0.w + xj * q0.w;
            x2v[4] += yj * r1v.x + xj * q1.x; x2v[5] += yj * r1v.y + xj * q1.y;
            x2v[6] += yj * r1v.z + xj * q1.z; x2v[7] += yj * r1v.w + xj * q1.w;
        }
    }
    __syncthreads();
    if (tid < 400) {
#pragma unroll
        for (int j = 0; j < 8; j++) sX[n * HH + cq * 8 + j] = fmaxf(x2v[j], 0.f);
    }
    __syncthreads();
    // s2 = softmax(x2 @ p2W + p2B); d2 and den2 partials
    if (tid < KP1) {
        float lg[10];
#pragma unroll
        for (int j = 0; j < 10; j++) lg[j] = p2B[j];
        for (int c = 0; c < 32; c++) {
            float xv = sX[tid * HH + c];
#pragma unroll
            for (int j = 0; j < 10; j++) lg[j] = fmaf(xv, p2W[c * 10 + j], lg[j]);
        }
        float mx = lg[0];
#pragma unroll
        for (int j = 1; j < 10; j++) mx = fmaxf(mx, lg[j]);
        float se = 0.f;
#pragma unroll
        for (int j = 0; j < 10; j++) { lg[j] = __expf(lg[j] - mx); se += lg[j]; }
        float inv = 1.f / se, sq = 0.f;
#pragma unroll
        for (int j = 0; j < 10; j++) { float sv = lg[j] * inv; sS2[tid * 10 + j] = sv; sq += sv * sv; }
        float d2 = 0.f;
        for (int mq = 0; mq < 25; mq++) {
            float4 a4 = *(const float4*)&Ag[tid * KP1 + mq * 4];
            d2 += a4.x + a4.y + a4.z + a4.w;
        }
        red[tid] = d2 * sq;
    }
    __syncthreads();
    // t2 = A @ s2 ; P2 = s2^T x2
    for (int p = tid; p < KP1 * KP2; p += 512) {
        int n2 = p / 10, jj = p % 10;
        float a = 0.f;
        for (int m = 0; m < KP1; m++) a = fmaf(Ag[n2 * KP1 + m], sS2[m * 10 + jj], a);
        sT2[p] = a;
    }
    if (tid < KP2 * HH) {
        int k = tid >> 5, cc = tid & 31;
        float a = 0.f;
        for (int n2 = 0; n2 < KP1; n2++) a = fmaf(sS2[n2 * 10 + k], sX[n2 * HH + cc], a);
        P2[(size_t)g * (KP2 * HH) + tid] = a;
    }
    __syncthreads();
    // oa2, ss2
    if (tid < 100) {
        int k = tid / 10, l = tid % 10;
        float oa = 0.f, ss = 0.f;
        for (int n2 = 0; n2 < KP1; n2++) {
            float sk = sS2[n2 * 10 + k];
            oa = fmaf(sk, sT2[n2 * 10 + l], oa);
            ss = fmaf(sk, sS2[n2 * 10 + l], ss);
        }
        sA2[tid] = oa; sB2[tid] = ss;
    }
    __syncthreads();
    if (tid == 0) {
        float den2 = 0.f;
        for (int i = 0; i < 100; i++) den2 += red[i];
        float troa = 0.f, trss = 0.f, ssq = 0.f;
        for (int k = 0; k < 10; k++) { troa += sA2[k * 10 + k]; trss += sB2[k * 10 + k]; }
        for (int i = 0; i < 100; i++) ssq += sB2[i] * sB2[i];
        float o2 = sqrtf(fmaxf(2.f - 2.f * trss / (sqrtf(ssq) * 3.16227766f), 0.f)); // sqrt(10)
        aux[256 + g] = -(troa / den2) + o2;
    }
    if (tid < 10) {
        float rs = 0.f;
        for (int l = 0; l < 10; l++) if (l != tid) rs += sA2[tid * 10 + l];
        sdd[tid] = sqrtf(rs) + 1e-15f;
    }
    __syncthreads();
    if (tid < 100) {
        int k = tid / 10, l = tid % 10;
        A2n[(size_t)g * 100 + tid] = (k == l) ? 0.f : sA2[tid] / (sdd[k] * sdd[l]);
    }
}

// ---------------- stage 2b: conv3 + mean + MLP head + log_softmax
__global__ __launch_bounds__(64) void k_s2b(const float* __restrict__ P2, const float* __restrict__ A2n,
                                            const float* __restrict__ relW3, const float* __restrict__ relb3,
                                            const float* __restrict__ rootW3,
                                            const float* __restrict__ l1W, const float* __restrict__ l1b,
                                            const float* __restrict__ l2W, const float* __restrict__ l2b,
                                            float* __restrict__ out) {
    __shared__ float sP[KP2 * HH], sA2[100], sY3[KP2 * HH], sG[32], sG1[32], sL[10], sLse;
    int g = blockIdx.x, tid = threadIdx.x;
    for (int i = tid; i < KP2 * HH; i += 64) sP[i] = P2[(size_t)g * (KP2 * HH) + i];
    for (int i = tid; i < 100; i += 64) sA2[i] = A2n[(size_t)g * 100 + i];
    if (tid < 32) sG[tid] = 0.f;
    __syncthreads();
    for (int p = tid; p < KP2 * HH; p += 64) {
        int k = p >> 5, cc = p & 31;
        float a = 0.f;
#pragma unroll
        for (int m = 0; m < 10; m++) a = fmaf(sA2[k * 10 + m], sP[m * HH + cc], a);
        sY3[p] = a;
    }
    __syncthreads();
    for (int p = tid; p < KP2 * HH; p += 64) {
        int k = p >> 5, cc = p & 31;
        float v = relb3[cc];
        for (int j = 0; j < 32; j++)
            v += sY3[k * HH + j] * relW3[j * 32 + cc] + sP[k * HH + j] * rootW3[j * 32 + cc];
        atomicAdd(&sG[cc], v * 0.1f);        // mean over 10 nodes
    }
    __syncthreads();
    if (tid < 32) {
        float v = l1b[tid];
        for (int j = 0; j < 32; j++) v = fmaf(sG[j], l1W[j * 32 + tid], v);
        sG1[tid] = fmaxf(v, 0.f);
    }
    __syncthreads();
    if (tid < 10) {
        float v = l2b[tid];
        for (int j = 0; j < 32; j++) v = fmaf(sG1[j], l2W[j * 10 + tid], v);
        sL[tid] = v;
    }
    __syncthreads();
    if (tid == 0) {
        float mx = sL[0];
        for (int j = 1; j < 10; j++) mx = fmaxf(mx, sL[j]);
        float se = 0.f;
        for (int j = 0; j < 10; j++) se += expf(sL[j] - mx);
        sLse = mx + logf(se);
    }
    __syncthreads();
    if (tid < 10) out[(size_t)g * 10 + tid] = sL[tid] - sLse;
}

// ------------------------------------------------------ total loss
__global__ void k_loss(const float* __restrict__ aux, float* __restrict__ out) {
    __shared__ float red[128];
    int tid = threadIdx.x;
    red[tid] = aux[128 + tid] + aux[256 + tid];
    __syncthreads();
#pragma unroll
    for (int s = 64; s > 0; s >>= 1) { if (tid < s) red[tid] += red[tid + s]; __syncthreads(); }
    if (tid == 0) out[1280] = red[0] * (1.f / 128.f);
}

extern "C" void kernel_launch(void* const* d_in, const int* in_sizes, int n_in,
                              void* d_out, int out_size, void* d_ws, size_t ws_size,
                              hipStream_t stream) {
    const float* x    = (const float*)d_in[0];
    const int*   ei   = (const int*)d_in[1];
    const float* c1W  = (const float*)d_in[3];
    const float* c1b  = (const float*)d_in[4];
    const float* p1W  = (const float*)d_in[5];
    const float* p1b  = (const float*)d_in[6];
    const float* relW2  = (const float*)d_in[7];
    const float* relb2  = (const float*)d_in[8];
    const float* rootW2 = (const float*)d_in[9];
    const float* p2W  = (const float*)d_in[10];
    const float* p2b  = (const float*)d_in[11];
    const float* relW3  = (const float*)d_in[12];
    const float* relb3  = (const float*)d_in[13];
    const float* rootW3 = (const float*)d_in[14];
    const float* l1W  = (const float*)d_in[15];
    const float* l1b  = (const float*)d_in[16];
    const float* l2W  = (const float*)d_in[17];
    const float* l2b  = (const float*)d_in[18];
    float* out = (float*)d_out;

    // ---- workspace layout
    int*  cnt_src = (int*)d_ws;                       // NT
    int*  cnt_dst = cnt_src + NT;                     // NT
    int*  off_src = cnt_dst + NT;                     // NT
    int*  off_dst = off_src + NT;                     // NT
    int*  cur_src = off_dst + NT;                     // NT
    int*  cur_dst = cur_src + NT;                     // NT
    int*  srt_dst = cur_dst + NT;                     // ET (src-sorted, stores dst)
    int*  srt_src = srt_dst + ET;                     // ET (dst-sorted, stores src)
    float* dis = (float*)(srt_src + ET);              // NT
    float* xw   = dis + NT;                           // NT*HH
    float* h    = xw + (size_t)NT * HH;               // NT*HH
    float* s1   = h + (size_t)NT * HH;                // NT*KP1
    float* t1   = s1 + (size_t)NT * KP1;              // NT*KP1
    float* Cp   = t1 + (size_t)NT * KP1;              // 4*TB*KP1*232
    float* A1n  = Cp + (size_t)4 * TB * (KP1 * 232);  // TB*KP1*KP1
    float* P1   = A1n + (size_t)TB * KP1 * KP1;       // TB*KP1*HH
    float* P2   = P1 + (size_t)TB * KP1 * HH;         // TB*KP2*HH
    float* A2n  = P2 + (size_t)TB * KP2 * HH;         // TB*100
    float* aux  = A2n + (size_t)TB * 100;             // 1024: den1|loss1|loss2

    k_init<<<NT / 256, 256, 0, stream>>>(cnt_src, cnt_dst, aux);
    k_cnt<<<ET / 256, 256, 0, stream>>>(ei, cnt_src, cnt_dst);
    k_scan<<<TB, 512, 0, stream>>>(cnt_src, cnt_dst, off_src, off_dst, cur_src, cur_dst);
    k_scatter<<<ET / 256, 256, 0, stream>>>(ei, cur_src, cur_dst, srt_dst, srt_src);
    k_dis<<<NT / 256, 256, 0, stream>>>(cnt_dst, dis);
    k_xw<<<(NT * HH) / 256, 256, 0, stream>>>(x, c1W, xw);
    k_gcng<<<NT / 8, 256, 0, stream>>>(srt_src, off_dst, cnt_dst, xw, dis, c1b, h);
    k_s1<<<NT / 128, 128, 0, stream>>>(h, p1W, p1b, cnt_src, s1, aux /*den1*/);
    k_t1g<<<NT / 2, 256, 0, stream>>>(srt_dst, off_src, cnt_src, s1, t1);
    k_gram<<<TB * 4, 512, 0, stream>>>(s1, t1, h, Cp);
    k_fin1<<<TB, 128, 0, stream>>>(Cp, aux /*den1*/, A1n, P1, aux);
    k_s2a<<<TB, 512, 0, stream>>>(A1n, P1, relW2, relb2, rootW2, p2W, p2b, P2, A2n, aux);
    k_s2b<<<TB, 64, 0, stream>>>(P2, A2n, relW3, relb3, rootW3, l1W, l1b, l2W, l2b, out);
    k_loss<<<1, 128, 0, stream>>>(aux, out);
}

// Round 6
// 528.762 us; speedup vs baseline: 3.1063x; 1.0844x over previous
//
#include <hip/hip_runtime.h>
#include <hip/hip_bf16.h>

// Problem constants (match reference)
#define TB   128          // batch B
#define NN   512          // nodes per graph
#define INC  128          // IN_C
#define HH   32           // HID
#define KP1  100          // K1
#define KP2  10           // K2
#define OC   10           // OUT_C
#define EPER 8192         // edges per graph
#define NT   (TB*NN)      // 65536 total nodes
#define ET   (TB*EPER)    // 1048576 total edges
#define ZSB  236          // gram Z tile stride in ushorts: [t 100|h 32|s 100|pad 4]

typedef unsigned int  u32;
typedef unsigned short u16;

// bf16 helpers (RNE encode; exact decode)
__device__ __forceinline__ u32 bfr(float f) {
    u32 b = __float_as_uint(f);
    return (b + 0x7fffu + ((b >> 16) & 1u)) >> 16;
}
__device__ __forceinline__ u32 pk2(float a, float b) { return bfr(a) | (bfr(b) << 16); }
__device__ __forceinline__ float blo(u32 u) { return __uint_as_float(u << 16); }
__device__ __forceinline__ float bhi(u32 u) { return __uint_as_float(u & 0xffff0000u); }
__device__ __forceinline__ float bss(u16 s) { return __uint_as_float(((u32)s) << 16); }

// ---------------------------------------------------------------- init
__global__ void k_init(int* __restrict__ cs, int* __restrict__ cd, float* __restrict__ aux) {
    int i = blockIdx.x * 256 + threadIdx.x;
    if (i < NT) { cs[i] = 0; cd[i] = 0; }
    if (i < 1024) aux[i] = 0.0f;              // den1 / loss1 / loss2 accumulators
}

// ---------------------------------------------- edge degree histograms
__global__ void k_cnt(const int* __restrict__ ei, int* __restrict__ cs, int* __restrict__ cd) {
    int e = blockIdx.x * 256 + threadIdx.x;
    if (e < ET) {
        atomicAdd(&cs[ei[e]], 1);             // out-degree (src)  = adj.sum(-1)
        atomicAdd(&cd[ei[ET + e]], 1);        // in-degree  (dst)  for GCN norm
    }
}

// ---------------- per-graph exclusive scan of both degree histograms
__global__ __launch_bounds__(512) void k_scan(const int* __restrict__ cs, const int* __restrict__ cd,
                                              int* __restrict__ os, int* __restrict__ od,
                                              int* __restrict__ curs, int* __restrict__ curd) {
    __shared__ int sa[512], sb[512];
    int g = blockIdx.x, tid = threadIdx.x, i = g * NN + tid;
    int vs = cs[i], vd = cd[i];
    sa[tid] = vs; sb[tid] = vd; __syncthreads();
    for (int off = 1; off < 512; off <<= 1) {
        int xa = sa[tid], xb = sb[tid];
        if (tid >= off) { xa += sa[tid - off]; xb += sb[tid - off]; }
        __syncthreads(); sa[tid] = xa; sb[tid] = xb; __syncthreads();
    }
    int es = g * EPER + sa[tid] - vs;         // exclusive scan, global position
    int ed = g * EPER + sb[tid] - vd;
    os[i] = es; od[i] = ed; curs[i] = es; curd[i] = ed;
}

// ----------------- counting-sort scatter: edges by src and by dst
__global__ void k_scatter(const int* __restrict__ ei, int* __restrict__ curs, int* __restrict__ curd,
                          int* __restrict__ sdst, int* __restrict__ ssrc) {
    int e = blockIdx.x * 256 + threadIdx.x;
    if (e < ET) {
        int s = ei[e], d = ei[ET + e];
        int p = atomicAdd(&curs[s], 1); sdst[p] = d;   // src-sorted: store dst
        int q = atomicAdd(&curd[d], 1); ssrc[q] = s;   // dst-sorted: store src
    }
}

__global__ void k_dis(const int* __restrict__ cd, float* __restrict__ dis) {
    int i = blockIdx.x * 256 + threadIdx.x;
    if (i < NT) dis[i] = rsqrtf(1.0f + (float)cd[i]);  // +1 self loop
}

// ------------------------------ xw = bf16(x @ conv1_W)  [NT,32] bf16
__global__ __launch_bounds__(256) void k_xw(const float* __restrict__ x, const float* __restrict__ W,
                                            u16* __restrict__ xwb) {
    __shared__ float sWT[32][132];           // W^T, padded stride
    int tid = threadIdx.x;
    for (int i = tid; i < INC * HH; i += 256) { int k = i >> 5, c = i & 31; sWT[c][k] = W[i]; }
    __syncthreads();
    int id = blockIdx.x * 256 + tid;
    int row = id >> 5, c = id & 31;
    const float4* xp = (const float4*)(x + (size_t)row * INC);
    float acc = 0.f;
#pragma unroll
    for (int kq = 0; kq < INC / 4; kq++) {
        float4 xv = xp[kq];
        float4 wv = *(const float4*)&sWT[c][kq * 4];
        acc += xv.x * wv.x + xv.y * wv.y + xv.z * wv.z + xv.w * wv.w;
    }
    xwb[id] = (u16)bfr(acc);
}

// -------- GCN gather (bf16 xw): h fp32 + hb bf16; 2 channels per lane
__global__ __launch_bounds__(256) void k_gcng(const int* __restrict__ ssrc, const int* __restrict__ od,
                                              const int* __restrict__ cd, const u32* __restrict__ xwb32,
                                              const float* __restrict__ dis, const float* __restrict__ bias,
                                              float* __restrict__ h, u32* __restrict__ hb32) {
    int tid = threadIdx.x;
    int n = blockIdx.x * 16 + (tid >> 4), cp = tid & 15;  // cp -> channels 2cp,2cp+1
    int base = od[n], cnt = cd[n];
    float dn = dis[n];
    u32 us = xwb32[(size_t)n * 16 + cp];
    float a0 = dn * blo(us), a1 = dn * bhi(us);           // self-loop term
    int i = 0;
    for (; i + 4 <= cnt; i += 4) {
        int s0 = ssrc[base + i], s1v = ssrc[base + i + 1];
        int s2 = ssrc[base + i + 2], s3 = ssrc[base + i + 3];
        float d0 = dis[s0], d1 = dis[s1v], d2 = dis[s2], d3 = dis[s3];
        u32 u0 = xwb32[(size_t)s0 * 16 + cp];
        u32 u1 = xwb32[(size_t)s1v * 16 + cp];
        u32 u2 = xwb32[(size_t)s2 * 16 + cp];
        u32 u3 = xwb32[(size_t)s3 * 16 + cp];
        a0 += d0 * blo(u0) + d1 * blo(u1) + d2 * blo(u2) + d3 * blo(u3);
        a1 += d0 * bhi(u0) + d1 * bhi(u1) + d2 * bhi(u2) + d3 * bhi(u3);
    }
    for (; i < cnt; i++) {
        int s0 = ssrc[base + i]; float d0 = dis[s0];
        u32 u0 = xwb32[(size_t)s0 * 16 + cp];
        a0 += d0 * blo(u0); a1 += d0 * bhi(u0);
    }
    float v0 = fmaxf(dn * a0 + bias[2 * cp], 0.f);
    float v1 = fmaxf(dn * a1 + bias[2 * cp + 1], 0.f);
    *(float2*)&h[(size_t)n * HH + 2 * cp] = make_float2(v0, v1);
    hb32[(size_t)n * 16 + cp] = pk2(v0, v1);
}

// ------- s1 = softmax(h @ pool1_W + b): thread-per-row; bf16 output
__global__ __launch_bounds__(128) void k_s1(const float* __restrict__ h, const float* __restrict__ W,
                                            const float* __restrict__ bias, const int* __restrict__ csrc,
                                            u32* __restrict__ s1b32, float* __restrict__ den1) {
    int tid = threadIdx.x;
    int row = blockIdx.x * 128 + tid;
    float hr[HH];
    const float4* hp = (const float4*)(h + (size_t)row * HH);
#pragma unroll
    for (int q = 0; q < HH / 4; q++) {
        float4 a = hp[q];
        hr[4*q] = a.x; hr[4*q+1] = a.y; hr[4*q+2] = a.z; hr[4*q+3] = a.w;
    }
    float e[KP1];
    float sum = 0.f, qq = 0.f;
#pragma unroll
    for (int g8 = 0; g8 < 12; g8++) {
        const int c0 = g8 * 8;
        float a[8];
#pragma unroll
        for (int j = 0; j < 8; j++) a[j] = bias[c0 + j];
#pragma unroll
        for (int k = 0; k < HH; k++) {
            const float* wr = W + k * KP1 + c0;
#pragma unroll
            for (int j = 0; j < 8; j++) a[j] = fmaf(hr[k], wr[j], a[j]);
        }
#pragma unroll
        for (int j = 0; j < 8; j++) {
            float ev = __expf(a[j]);
            e[c0 + j] = ev; sum += ev; qq = fmaf(ev, ev, qq);
        }
    }
    { // tail group: channels 96..99
        const int c0 = 96;
        float a[4];
#pragma unroll
        for (int j = 0; j < 4; j++) a[j] = bias[c0 + j];
#pragma unroll
        for (int k = 0; k < HH; k++) {
            const float* wr = W + k * KP1 + c0;
#pragma unroll
            for (int j = 0; j < 4; j++) a[j] = fmaf(hr[k], wr[j], a[j]);
        }
#pragma unroll
        for (int j = 0; j < 4; j++) {
            float ev = __expf(a[j]);
            e[c0 + j] = ev; sum += ev; qq = fmaf(ev, ev, qq);
        }
    }
    float inv = 1.f / sum;
    uint2* sp = (uint2*)(s1b32 + (size_t)row * 50);   // row = 200 B, 8B-aligned
#pragma unroll
    for (int q = 0; q < 25; q++) {
        uint2 v;
        v.x = pk2(e[4*q] * inv,   e[4*q+1] * inv);
        v.y = pk2(e[4*q+2] * inv, e[4*q+3] * inv);
        sp[q] = v;
    }
    float contrib = (float)csrc[row] * qq * inv * inv;
#pragma unroll
    for (int off = 32; off >= 1; off >>= 1) contrib += __shfl_xor(contrib, off);
    if ((tid & 63) == 0) atomicAdd(&den1[row >> 9], contrib);
}

// ------------- t1 gather (bf16): wave per node, lane owns 2 channels
__global__ __launch_bounds__(256) void k_t1g(const int* __restrict__ sdst, const int* __restrict__ osr,
                                             const int* __restrict__ csr, const u32* __restrict__ s1b32,
                                             u32* __restrict__ t1b32) {
    int tid = threadIdx.x;
    int n = blockIdx.x * 4 + (tid >> 6), lane = tid & 63;
    if (lane >= 50) return;
    int base = osr[n], cnt = csr[n];
    float a0 = 0.f, a1 = 0.f;
    int i = 0;
    for (; i + 4 <= cnt; i += 4) {
        int d0 = sdst[base + i], d1 = sdst[base + i + 1];
        int d2 = sdst[base + i + 2], d3 = sdst[base + i + 3];
        u32 u0 = s1b32[(size_t)d0 * 50 + lane];
        u32 u1 = s1b32[(size_t)d1 * 50 + lane];
        u32 u2 = s1b32[(size_t)d2 * 50 + lane];
        u32 u3 = s1b32[(size_t)d3 * 50 + lane];
        a0 += (blo(u0) + blo(u1)) + (blo(u2) + blo(u3));
        a1 += (bhi(u0) + bhi(u1)) + (bhi(u2) + bhi(u3));
    }
    for (; i < cnt; i++) {
        int d0 = sdst[base + i];
        u32 u0 = s1b32[(size_t)d0 * 50 + lane];
        a0 += blo(u0); a1 += bhi(u0);
    }
    t1b32[(size_t)n * 50 + lane] = pk2(a0, a1);
}

// --- gram: C = s1^T [t1 | h | s1] (100 x 232); bf16 Z, 4 slabs, dbuf LDS
__global__ __launch_bounds__(512, 4) void k_gram(const u32* __restrict__ s1b32, const u32* __restrict__ t1b32,
                                                 const u32* __restrict__ hb32, float* __restrict__ Cp) {
    __shared__ u16 sZ[2][32 * ZSB];          // 2 x 15.1 KB
    int g = blockIdx.x >> 2, slab = blockIdx.x & 3;
    int n0base = slab * 128;                 // 4 tiles of 32 rows
    int goff = g * NN;
    int tid = threadIdx.x;
    int wave = tid >> 6, lane = tid & 63;
    int wr = wave >> 1, wc = wave & 1;       // 4 x 2 wave grid
    int kg = wr * 4 + (lane >> 4);           // 0..15, need <13
    int lg = wc * 16 + (lane & 15);          // 0..31, need <29
    bool act = (kg < 13) && (lg < 29);
    int k0 = kg * 8, l0 = lg * 8;
    float accm[8][8];
#pragma unroll
    for (int i = 0; i < 8; i++)
#pragma unroll
        for (int j = 0; j < 8; j++) accm[i][j] = 0.f;

    // 58 uint2 per row: 25 t | 8 h | 25 s
#pragma unroll
    for (int j = 0; j < 4; j++) {
        int i = tid + j * 512;
        if (i < 32 * 58) {
            int r = i / 58, q = i - r * 58;
            int n = goff + n0base + r;
            uint2 v;
            if (q < 25)      v = ((const uint2*)(t1b32 + (size_t)n * 50))[q];
            else if (q < 33) v = ((const uint2*)(hb32  + (size_t)n * 16))[q - 25];
            else             v = ((const uint2*)(s1b32 + (size_t)n * 50))[q - 33];
            int off = (q < 25) ? (q * 4) : ((q < 33) ? (100 + (q - 25) * 4) : (132 + (q - 33) * 4));
            *(uint2*)&sZ[0][r * ZSB + off] = v;
        }
    }
    __syncthreads();

    for (int nt = 0; nt < 4; nt++) {
        uint2 pre[4];
        if (nt < 3) {
            int n0 = n0base + (nt + 1) * 32;
#pragma unroll
            for (int j = 0; j < 4; j++) {
                int i = tid + j * 512;
                if (i < 32 * 58) {
                    int r = i / 58, q = i - r * 58;
                    int n = goff + n0 + r;
                    uint2 v;
                    if (q < 25)      v = ((const uint2*)(t1b32 + (size_t)n * 50))[q];
                    else if (q < 33) v = ((const uint2*)(hb32  + (size_t)n * 16))[q - 25];
                    else             v = ((const uint2*)(s1b32 + (size_t)n * 50))[q - 33];
                    pre[j] = v;
                }
            }
        }
        const u16* zb = sZ[nt & 1];
        if (act) {
            for (int r = 0; r < 32; r++) {
                const u16* zr = &zb[r * ZSB];
                ushort4 aA = *(const ushort4*)&zr[132 + k0];
                ushort4 aB = *(const ushort4*)&zr[132 + k0 + 4];
                ushort4 bA = *(const ushort4*)&zr[l0];
                ushort4 bB = *(const ushort4*)&zr[l0 + 4];
                float av[8] = {bss(aA.x), bss(aA.y), bss(aA.z), bss(aA.w),
                               bss(aB.x), bss(aB.y), bss(aB.z), bss(aB.w)};
                float bv[8] = {bss(bA.x), bss(bA.y), bss(bA.z), bss(bA.w),
                               bss(bB.x), bss(bB.y), bss(bB.z), bss(bB.w)};
#pragma unroll
                for (int i = 0; i < 8; i++)
#pragma unroll
                    for (int j = 0; j < 8; j++) accm[i][j] = fmaf(av[i], bv[j], accm[i][j]);
            }
        }
        if (nt < 3) {
            u16* zo = sZ[(nt + 1) & 1];
#pragma unroll
            for (int j = 0; j < 4; j++) {
                int i = tid + j * 512;
                if (i < 32 * 58) {
                    int r = i / 58, q = i - r * 58;
                    int off = (q < 25) ? (q * 4) : ((q < 33) ? (100 + (q - 25) * 4) : (132 + (q - 33) * 4));
                    *(uint2*)&zo[r * ZSB + off] = pre[j];
                }
            }
        }
        __syncthreads();
    }
    if (act) {
        float* out = Cp + ((size_t)slab * TB + g) * (KP1 * 232);
#pragma unroll
        for (int i = 0; i < 8; i++) {
            int k = k0 + i;
            if (k < KP1) {
#pragma unroll
                for (int j = 0; j < 8; j++) out[k * 232 + l0 + j] = accm[i][j];
            }
        }
    }
}

// ---- finalize stage 1: sum 4 slabs, losses, normalize out_adj, emit P1
__global__ __launch_bounds__(128) void k_fin1(const float* __restrict__ Cp, const float* __restrict__ den1,
                                              float* __restrict__ A1n, float* __restrict__ P1,
                                              float* __restrict__ aux) {
    __shared__ float sA[KP1 * KP1];          // 40 KB
    __shared__ float sd[KP1];
    __shared__ float r1[128], r2[128], r3[128];
    int g = blockIdx.x, tid = threadIdx.x;
    const float* c0 = Cp + (size_t)g * (KP1 * 232);
    const float* c1 = Cp + ((size_t)TB + g) * (KP1 * 232);
    const float* c2 = Cp + ((size_t)2 * TB + g) * (KP1 * 232);
    const float* c3 = Cp + ((size_t)3 * TB + g) * (KP1 * 232);
    float ssq = 0.f, troa = 0.f, trss = 0.f;
    if (tid < KP1) {
        int k = tid;
        float rs = 0.f;
        for (int l = 0; l < KP1; l++) {
            float oa = (c0[k * 232 + l] + c1[k * 232 + l]) + (c2[k * 232 + l] + c3[k * 232 + l]);
            sA[k * KP1 + l] = oa;
            if (l != k) rs += oa; else troa += oa;
            float ssv = (c0[k * 232 + 132 + l] + c1[k * 232 + 132 + l])
                      + (c2[k * 232 + 132 + l] + c3[k * 232 + 132 + l]);
            ssq += ssv * ssv;
            if (l == k) trss += ssv;
        }
        sd[k] = sqrtf(rs) + 1e-15f;
        for (int cc = 0; cc < HH; cc++)
            P1[((size_t)g * KP1 + k) * HH + cc] =
                (c0[k * 232 + 100 + cc] + c1[k * 232 + 100 + cc])
              + (c2[k * 232 + 100 + cc] + c3[k * 232 + 100 + cc]);
    }
    r1[tid] = ssq; r2[tid] = troa; r3[tid] = trss; __syncthreads();
#pragma unroll
    for (int s = 64; s > 0; s >>= 1) {
        if (tid < s) { r1[tid] += r1[tid + s]; r2[tid] += r2[tid + s]; r3[tid] += r3[tid + s]; }
        __syncthreads();
    }
    if (tid == 0) {
        float ssF = sqrtf(r1[0]);
        float o1 = sqrtf(fmaxf(2.f - 2.f * r3[0] / (ssF * 10.f), 0.f));  // sqrt(K1)=10
        aux[128 + g] = -(r2[0] / den1[g]) + o1;
    }
    __syncthreads();
    for (int i = tid; i < KP1 * KP1; i += 128) {
        int k = i / KP1, l = i % KP1;
        A1n[(size_t)g * (KP1 * KP1) + i] = (k == l) ? 0.f : sA[i] / (sd[k] * sd[l]);
    }
}

// ------- stage 2a: conv2 + pool2 (per graph); A read from global (L2)
__global__ __launch_bounds__(512) void k_s2a(const float* __restrict__ A1n, const float* __restrict__ P1,
                                             const float* __restrict__ relW, const float* __restrict__ relB,
                                             const float* __restrict__ rootW,
                                             const float* __restrict__ p2W, const float* __restrict__ p2B,
                                             float* __restrict__ P2, float* __restrict__ A2n,
                                             float* __restrict__ aux) {
    __shared__ float sX[KP1 * HH];           // x1p then x2
    __shared__ float sY[KP1 * HH];           // y = A @ x1p
    __shared__ float sS2[KP1 * KP2];
    __shared__ float sT2[KP1 * KP2];
    __shared__ float sA2[100], sB2[100], sdd[10], red[100];
    int g = blockIdx.x, tid = threadIdx.x;
    const float* Ag = A1n + (size_t)g * (KP1 * KP1);
    for (int i = tid; i < KP1 * HH; i += 512) sX[i] = P1[(size_t)g * (KP1 * HH) + i];
    __syncthreads();

    int n = tid >> 2, cq = tid & 3;          // 400 active threads for y / x2
    // y = A @ x1p
    if (tid < 400) {
        float yv[8];
#pragma unroll
        for (int j = 0; j < 8; j++) yv[j] = 0.f;
        for (int mq = 0; mq < 25; mq++) {
            float4 a4 = *(const float4*)&Ag[n * KP1 + mq * 4];
            const float* xb = &sX[(mq * 4) * HH + cq * 8];
            float aa[4] = {a4.x, a4.y, a4.z, a4.w};
#pragma unroll
            for (int mm = 0; mm < 4; mm++) {
                const float* xr = xb + mm * HH;
#pragma unroll
                for (int j = 0; j < 8; j++) yv[j] = fmaf(aa[mm], xr[j], yv[j]);
            }
        }
#pragma unroll
        for (int j = 0; j < 8; j++) sY[n * HH + cq * 8 + j] = yv[j];
    }
    __syncthreads();
    // x2 = relu(y @ relW + relB + x1p @ rootW)
    float x2v[8];
    if (tid < 400) {
#pragma unroll
        for (int j = 0; j < 8; j++) x2v[j] = relB[cq * 8 + j];
        for (int j = 0; j < 32; j++) {
            float yj = sY[n * HH + j];
            float xj = sX[n * HH + j];
            float4 r0 = *(const float4*)&relW[j * 32 + cq * 8];
            float4 r1v = *(const float4*)&relW[j * 32 + cq * 8 + 4];
            float4 q0 = *(const float4*)&rootW[j * 32 + cq * 8];
            float4 q1 = *(const float4*)&rootW[j * 32 + cq * 8 + 4];
            x2v[0] += yj * r0.x + xj * q0.x;  x2v[1] += yj * r0.y + xj * q0.y;
            x2v[2] += yj * r0.z + xj * q0.z;  x2v[3] += yj * r0.w + xj * q0.w;
            x2v[4] += yj * r1v.x + xj * q1.x; x2v[5] += yj * r1v.y + xj * q1.y;
            x2v[6] += yj * r1v.z + xj * q1.z; x2v[7] += yj * r1v.w + xj * q1.w;
        }
    }
    __syncthreads();
    if (tid < 400) {
#pragma unroll
        for (int j = 0; j < 8; j++) sX[n * HH + cq * 8 + j] = fmaxf(x2v[j], 0.f);
    }
    __syncthreads();
    // s2 = softmax(x2 @ p2W + p2B); d2 and den2 partials
    if (tid < KP1) {
        float lg[10];
#pragma unroll
        for (int j = 0; j < 10; j++) lg[j] = p2B[j];
        for (int c = 0; c < 32; c++) {
            float xv = sX[tid * HH + c];
#pragma unroll
            for (int j = 0; j < 10; j++) lg[j] = fmaf(xv, p2W[c * 10 + j], lg[j]);
        }
        float mx = lg[0];
#pragma unroll
        for (int j = 1; j < 10; j++) mx = fmaxf(mx, lg[j]);
        float se = 0.f;
#pragma unroll
        for (int j = 0; j < 10; j++) { lg[j] = __expf(lg[j] - mx); se += lg[j]; }
        float inv = 1.f / se, sq = 0.f;
#pragma unroll
        for (int j = 0; j < 10; j++) { float sv = lg[j] * inv; sS2[tid * 10 + j] = sv; sq += sv * sv; }
        float d2 = 0.f;
        for (int mq = 0; mq < 25; mq++) {
            float4 a4 = *(const float4*)&Ag[tid * KP1 + mq * 4];
            d2 += a4.x + a4.y + a4.z + a4.w;
        }
        red[tid] = d2 * sq;
    }
    __syncthreads();
    // t2 = A @ s2 ; P2 = s2^T x2
    for (int p = tid; p < KP1 * KP2; p += 512) {
        int n2 = p / 10, jj = p % 10;
        float a = 0.f;
        for (int m = 0; m < KP1; m++) a = fmaf(Ag[n2 * KP1 + m], sS2[m * 10 + jj], a);
        sT2[p] = a;
    }
    if (tid < KP2 * HH) {
        int k = tid >> 5, cc = tid & 31;
        float a = 0.f;
        for (int n2 = 0; n2 < KP1; n2++) a = fmaf(sS2[n2 * 10 + k], sX[n2 * HH + cc], a);
        P2[(size_t)g * (KP2 * HH) + tid] = a;
    }
    __syncthreads();
    // oa2, ss2
    if (tid < 100) {
        int k = tid / 10, l = tid % 10;
        float oa = 0.f, ss = 0.f;
        for (int n2 = 0; n2 < KP1; n2++) {
            float sk = sS2[n2 * 10 + k];
            oa = fmaf(sk, sT2[n2 * 10 + l], oa);
            ss = fmaf(sk, sS2[n2 * 10 + l], ss);
        }
        sA2[tid] = oa; sB2[tid] = ss;
    }
    __syncthreads();
    if (tid == 0) {
        float den2 = 0.f;
        for (int i = 0; i < 100; i++) den2 += red[i];
        float troa = 0.f, trss = 0.f, ssq = 0.f;
        for (int k = 0; k < 10; k++) { troa += sA2[k * 10 + k]; trss += sB2[k * 10 + k]; }
        for (int i = 0; i < 100; i++) ssq += sB2[i] * sB2[i];
        float o2 = sqrtf(fmaxf(2.f - 2.f * trss / (sqrtf(ssq) * 3.16227766f), 0.f)); // sqrt(10)
        aux[256 + g] = -(troa / den2) + o2;
    }
    if (tid < 10) {
        float rs = 0.f;
        for (int l = 0; l < 10; l++) if (l != tid) rs += sA2[tid * 10 + l];
        sdd[tid] = sqrtf(rs) + 1e-15f;
    }
    __syncthreads();
    if (tid < 100) {
        int k = tid / 10, l = tid % 10;
        A2n[(size_t)g * 100 + tid] = (k == l) ? 0.f : sA2[tid] / (sdd[k] * sdd[l]);
    }
}

// ---------------- stage 2b: conv3 + mean + MLP head + log_softmax
__global__ __launch_bounds__(64) void k_s2b(const float* __restrict__ P2, const float* __restrict__ A2n,
                                            const float* __restrict__ relW3, const float* __restrict__ relb3,
                                            const float* __restrict__ rootW3,
                                            const float* __restrict__ l1W, const float* __restrict__ l1b,
                                            const float* __restrict__ l2W, const float* __restrict__ l2b,
                                            float* __restrict__ out) {
    __shared__ float sP[KP2 * HH], sA2[100], sY3[KP2 * HH], sG[32], sG1[32], sL[10], sLse;
    int g = blockIdx.x, tid = threadIdx.x;
    for (int i = tid; i < KP2 * HH; i += 64) sP[i] = P2[(size_t)g * (KP2 * HH) + i];
    for (int i = tid; i < 100; i += 64) sA2[i] = A2n[(size_t)g * 100 + i];
    if (tid < 32) sG[tid] = 0.f;
    __syncthreads();
    for (int p = tid; p < KP2 * HH; p += 64) {
        int k = p >> 5, cc = p & 31;
        float a = 0.f;
#pragma unroll
        for (int m = 0; m < 10; m++) a = fmaf(sA2[k * 10 + m], sP[m * HH + cc], a);
        sY3[p] = a;
    }
    __syncthreads();
    for (int p = tid; p < KP2 * HH; p += 64) {
        int k = p >> 5, cc = p & 31;
        float v = relb3[cc];
        for (int j = 0; j < 32; j++)
            v += sY3[k * HH + j] * relW3[j * 32 + cc] + sP[k * HH + j] * rootW3[j * 32 + cc];
        atomicAdd(&sG[cc], v * 0.1f);        // mean over 10 nodes
    }
    __syncthreads();
    if (tid < 32) {
        float v = l1b[tid];
        for (int j = 0; j < 32; j++) v = fmaf(sG[j], l1W[j * 32 + tid], v);
        sG1[tid] = fmaxf(v, 0.f);
    }
    __syncthreads();
    if (tid < 10) {
        float v = l2b[tid];
        for (int j = 0; j < 32; j++) v = fmaf(sG1[j], l2W[j * 10 + tid], v);
        sL[tid] = v;
    }
    __syncthreads();
    if (tid == 0) {
        float mx = sL[0];
        for (int j = 1; j < 10; j++) mx = fmaxf(mx, sL[j]);
        float se = 0.f;
        for (int j = 0; j < 10; j++) se += expf(sL[j] - mx);
        sLse = mx + logf(se);
    }
    __syncthreads();
    if (tid < 10) out[(size_t)g * 10 + tid] = sL[tid] - sLse;
}

// ------------------------------------------------------ total loss
__global__ void k_loss(const float* __restrict__ aux, float* __restrict__ out) {
    __shared__ float red[128];
    int tid = threadIdx.x;
    red[tid] = aux[128 + tid] + aux[256 + tid];
    __syncthreads();
#pragma unroll
    for (int s = 64; s > 0; s >>= 1) { if (tid < s) red[tid] += red[tid + s]; __syncthreads(); }
    if (tid == 0) out[1280] = red[0] * (1.f / 128.f);
}

extern "C" void kernel_launch(void* const* d_in, const int* in_sizes, int n_in,
                              void* d_out, int out_size, void* d_ws, size_t ws_size,
                              hipStream_t stream) {
    const float* x    = (const float*)d_in[0];
    const int*   ei   = (const int*)d_in[1];
    const float* c1W  = (const float*)d_in[3];
    const float* c1b  = (const float*)d_in[4];
    const float* p1W  = (const float*)d_in[5];
    const float* p1b  = (const float*)d_in[6];
    const float* relW2  = (const float*)d_in[7];
    const float* relb2  = (const float*)d_in[8];
    const float* rootW2 = (const float*)d_in[9];
    const float* p2W  = (const float*)d_in[10];
    const float* p2b  = (const float*)d_in[11];
    const float* relW3  = (const float*)d_in[12];
    const float* relb3  = (const float*)d_in[13];
    const float* rootW3 = (const float*)d_in[14];
    const float* l1W  = (const float*)d_in[15];
    const float* l1b  = (const float*)d_in[16];
    const float* l2W  = (const float*)d_in[17];
    const float* l2b  = (const float*)d_in[18];
    float* out = (float*)d_out;

    // ---- workspace layout
    int*  cnt_src = (int*)d_ws;                       // NT
    int*  cnt_dst = cnt_src + NT;                     // NT
    int*  off_src = cnt_dst + NT;                     // NT
    int*  off_dst = off_src + NT;                     // NT
    int*  cur_src = off_dst + NT;                     // NT
    int*  cur_dst = cur_src + NT;                     // NT
    int*  srt_dst = cur_dst + NT;                     // ET (src-sorted, stores dst)
    int*  srt_src = srt_dst + ET;                     // ET (dst-sorted, stores src)
    float* dis = (float*)(srt_src + ET);              // NT
    u32*  xwb  = (u32*)(dis + NT);                    // NT*16 (bf16 x2)
    u32*  hb   = xwb + (size_t)NT * 16;               // NT*16
    u32*  s1b  = hb + (size_t)NT * 16;                // NT*50
    u32*  t1b  = s1b + (size_t)NT * 50;               // NT*50
    float* h    = (float*)(t1b + (size_t)NT * 50);    // NT*HH fp32
    float* Cp   = h + (size_t)NT * HH;                // 4*TB*KP1*232
    float* A1n  = Cp + (size_t)4 * TB * (KP1 * 232);  // TB*KP1*KP1
    float* P1   = A1n + (size_t)TB * KP1 * KP1;       // TB*KP1*HH
    float* P2   = P1 + (size_t)TB * KP1 * HH;         // TB*KP2*HH
    float* A2n  = P2 + (size_t)TB * KP2 * HH;         // TB*100
    float* aux  = A2n + (size_t)TB * 100;             // 1024: den1|loss1|loss2

    k_init<<<NT / 256, 256, 0, stream>>>(cnt_src, cnt_dst, aux);
    k_cnt<<<ET / 256, 256, 0, stream>>>(ei, cnt_src, cnt_dst);
    k_scan<<<TB, 512, 0, stream>>>(cnt_src, cnt_dst, off_src, off_dst, cur_src, cur_dst);
    k_scatter<<<ET / 256, 256, 0, stream>>>(ei, cur_src, cur_dst, srt_dst, srt_src);
    k_dis<<<NT / 256, 256, 0, stream>>>(cnt_dst, dis);
    k_xw<<<(NT * HH) / 256, 256, 0, stream>>>(x, c1W, (u16*)xwb);
    k_gcng<<<NT / 16, 256, 0, stream>>>(srt_src, off_dst, cnt_dst, xwb, dis, c1b, h, hb);
    k_s1<<<NT / 128, 128, 0, stream>>>(h, p1W, p1b, cnt_src, s1b, aux /*den1*/);
    k_t1g<<<NT / 4, 256, 0, stream>>>(srt_dst, off_src, cnt_src, s1b, t1b);
    k_gram<<<TB * 4, 512, 0, stream>>>(s1b, t1b, hb, Cp);
    k_fin1<<<TB, 128, 0, stream>>>(Cp, aux /*den1*/, A1n, P1, aux);
    k_s2a<<<TB, 512, 0, stream>>>(A1n, P1, relW2, relb2, rootW2, p2W, p2b, P2, A2n, aux);
    k_s2b<<<TB, 64, 0, stream>>>(P2, A2n, relW3, relb3, rootW3, l1W, l1b, l2W, l2b, out);
    k_loss<<<1, 128, 0, stream>>>(aux, out);
}

// Round 7
// 482.930 us; speedup vs baseline: 3.4011x; 1.0949x over previous
//
#include <hip/hip_runtime.h>
#include <hip/hip_bf16.h>

// Problem constants (match reference)
#define TB   128          // batch B
#define NN   512          // nodes per graph
#define INC  128          // IN_C
#define HH   32           // HID
#define KP1  100          // K1
#define KP2  10           // K2
#define OC   10           // OUT_C
#define EPER 8192         // edges per graph
#define NT   (TB*NN)      // 65536 total nodes
#define ET   (TB*EPER)    // 1048576 total edges
#define ZTR  264          // gram ZT rows: 232 Z-cols + 32 zero pad (partial MFMA tiles)
#define ZTS  40           // ZT row stride in u16 (80 B, 16B-aligned for ds_read_b128)

typedef unsigned int  u32;
typedef unsigned short u16;
typedef __attribute__((ext_vector_type(8))) short bf16x8;   // 8 bf16 = 4 VGPR (MFMA A/B frag)
typedef __attribute__((ext_vector_type(16))) float f32x16;  // MFMA C/D frag

// bf16 helpers (RNE encode; exact decode)
__device__ __forceinline__ u32 bfr(float f) {
    u32 b = __float_as_uint(f);
    return (b + 0x7fffu + ((b >> 16) & 1u)) >> 16;
}
__device__ __forceinline__ u32 pk2(float a, float b) { return bfr(a) | (bfr(b) << 16); }
__device__ __forceinline__ float blo(u32 u) { return __uint_as_float(u << 16); }
__device__ __forceinline__ float bhi(u32 u) { return __uint_as_float(u & 0xffff0000u); }

// ---------------------------------------------------------------- init
__global__ void k_init(int* __restrict__ cs, int* __restrict__ cd, float* __restrict__ aux) {
    int i = blockIdx.x * 256 + threadIdx.x;
    if (i < NT) { cs[i] = 0; cd[i] = 0; }
    if (i < 1024) aux[i] = 0.0f;              // den1 / loss1 / loss2 accumulators
}

// ---------------------------------------------- edge degree histograms
__global__ void k_cnt(const int* __restrict__ ei, int* __restrict__ cs, int* __restrict__ cd) {
    int e = blockIdx.x * 256 + threadIdx.x;
    if (e < ET) {
        atomicAdd(&cs[ei[e]], 1);             // out-degree (src)  = adj.sum(-1)
        atomicAdd(&cd[ei[ET + e]], 1);        // in-degree  (dst)  for GCN norm
    }
}

// ---------------- per-graph exclusive scan of both degree histograms
__global__ __launch_bounds__(512) void k_scan(const int* __restrict__ cs, const int* __restrict__ cd,
                                              int* __restrict__ os, int* __restrict__ od,
                                              int* __restrict__ curs, int* __restrict__ curd) {
    __shared__ int sa[512], sb[512];
    int g = blockIdx.x, tid = threadIdx.x, i = g * NN + tid;
    int vs = cs[i], vd = cd[i];
    sa[tid] = vs; sb[tid] = vd; __syncthreads();
    for (int off = 1; off < 512; off <<= 1) {
        int xa = sa[tid], xb = sb[tid];
        if (tid >= off) { xa += sa[tid - off]; xb += sb[tid - off]; }
        __syncthreads(); sa[tid] = xa; sb[tid] = xb; __syncthreads();
    }
    int es = g * EPER + sa[tid] - vs;         // exclusive scan, global position
    int ed = g * EPER + sb[tid] - vd;
    os[i] = es; od[i] = ed; curs[i] = es; curd[i] = ed;
}

// ----------------- counting-sort scatter: edges by src and by dst
__global__ void k_scatter(const int* __restrict__ ei, int* __restrict__ curs, int* __restrict__ curd,
                          int* __restrict__ sdst, int* __restrict__ ssrc) {
    int e = blockIdx.x * 256 + threadIdx.x;
    if (e < ET) {
        int s = ei[e], d = ei[ET + e];
        int p = atomicAdd(&curs[s], 1); sdst[p] = d;   // src-sorted: store dst
        int q = atomicAdd(&curd[d], 1); ssrc[q] = s;   // dst-sorted: store src
    }
}

__global__ void k_dis(const int* __restrict__ cd, float* __restrict__ dis) {
    int i = blockIdx.x * 256 + threadIdx.x;
    if (i < NT) dis[i] = rsqrtf(1.0f + (float)cd[i]);  // +1 self loop
}

// ------------------------------ xw = bf16(x @ conv1_W)  [NT,32] bf16
__global__ __launch_bounds__(256) void k_xw(const float* __restrict__ x, const float* __restrict__ W,
                                            u16* __restrict__ xwb) {
    __shared__ float sWT[32][132];           // W^T, padded stride
    int tid = threadIdx.x;
    for (int i = tid; i < INC * HH; i += 256) { int k = i >> 5, c = i & 31; sWT[c][k] = W[i]; }
    __syncthreads();
    int id = blockIdx.x * 256 + tid;
    int row = id >> 5, c = id & 31;
    const float4* xp = (const float4*)(x + (size_t)row * INC);
    float acc = 0.f;
#pragma unroll
    for (int kq = 0; kq < INC / 4; kq++) {
        float4 xv = xp[kq];
        float4 wv = *(const float4*)&sWT[c][kq * 4];
        acc += xv.x * wv.x + xv.y * wv.y + xv.z * wv.z + xv.w * wv.w;
    }
    xwb[id] = (u16)bfr(acc);
}

// -------- GCN gather (bf16 xw): h fp32 + hb bf16; 2 channels per lane
__global__ __launch_bounds__(256) void k_gcng(const int* __restrict__ ssrc, const int* __restrict__ od,
                                              const int* __restrict__ cd, const u32* __restrict__ xwb32,
                                              const float* __restrict__ dis, const float* __restrict__ bias,
                                              float* __restrict__ h, u32* __restrict__ hb32) {
    int tid = threadIdx.x;
    int n = blockIdx.x * 16 + (tid >> 4), cp = tid & 15;  // cp -> channels 2cp,2cp+1
    int base = od[n], cnt = cd[n];
    float dn = dis[n];
    u32 us = xwb32[(size_t)n * 16 + cp];
    float a0 = dn * blo(us), a1 = dn * bhi(us);           // self-loop term
    int i = 0;
    for (; i + 4 <= cnt; i += 4) {
        int s0 = ssrc[base + i], s1v = ssrc[base + i + 1];
        int s2 = ssrc[base + i + 2], s3 = ssrc[base + i + 3];
        float d0 = dis[s0], d1 = dis[s1v], d2 = dis[s2], d3 = dis[s3];
        u32 u0 = xwb32[(size_t)s0 * 16 + cp];
        u32 u1 = xwb32[(size_t)s1v * 16 + cp];
        u32 u2 = xwb32[(size_t)s2 * 16 + cp];
        u32 u3 = xwb32[(size_t)s3 * 16 + cp];
        a0 += d0 * blo(u0) + d1 * blo(u1) + d2 * blo(u2) + d3 * blo(u3);
        a1 += d0 * bhi(u0) + d1 * bhi(u1) + d2 * bhi(u2) + d3 * bhi(u3);
    }
    for (; i < cnt; i++) {
        int s0 = ssrc[base + i]; float d0 = dis[s0];
        u32 u0 = xwb32[(size_t)s0 * 16 + cp];
        a0 += d0 * blo(u0); a1 += d0 * bhi(u0);
    }
    float v0 = fmaxf(dn * a0 + bias[2 * cp], 0.f);
    float v1 = fmaxf(dn * a1 + bias[2 * cp + 1], 0.f);
    *(float2*)&h[(size_t)n * HH + 2 * cp] = make_float2(v0, v1);
    hb32[(size_t)n * 16 + cp] = pk2(v0, v1);
}

// ------- s1 = softmax(h @ pool1_W + b): thread-per-row; bf16 output
__global__ __launch_bounds__(128) void k_s1(const float* __restrict__ h, const float* __restrict__ W,
                                            const float* __restrict__ bias, const int* __restrict__ csrc,
                                            u32* __restrict__ s1b32, float* __restrict__ den1) {
    int tid = threadIdx.x;
    int row = blockIdx.x * 128 + tid;
    float hr[HH];
    const float4* hp = (const float4*)(h + (size_t)row * HH);
#pragma unroll
    for (int q = 0; q < HH / 4; q++) {
        float4 a = hp[q];
        hr[4*q] = a.x; hr[4*q+1] = a.y; hr[4*q+2] = a.z; hr[4*q+3] = a.w;
    }
    float e[KP1];
    float sum = 0.f, qq = 0.f;
#pragma unroll
    for (int g8 = 0; g8 < 12; g8++) {
        const int c0 = g8 * 8;
        float a[8];
#pragma unroll
        for (int j = 0; j < 8; j++) a[j] = bias[c0 + j];
#pragma unroll
        for (int k = 0; k < HH; k++) {
            const float* wr = W + k * KP1 + c0;
#pragma unroll
            for (int j = 0; j < 8; j++) a[j] = fmaf(hr[k], wr[j], a[j]);
        }
#pragma unroll
        for (int j = 0; j < 8; j++) {
            float ev = __expf(a[j]);
            e[c0 + j] = ev; sum += ev; qq = fmaf(ev, ev, qq);
        }
    }
    { // tail group: channels 96..99
        const int c0 = 96;
        float a[4];
#pragma unroll
        for (int j = 0; j < 4; j++) a[j] = bias[c0 + j];
#pragma unroll
        for (int k = 0; k < HH; k++) {
            const float* wr = W + k * KP1 + c0;
#pragma unroll
            for (int j = 0; j < 4; j++) a[j] = fmaf(hr[k], wr[j], a[j]);
        }
#pragma unroll
        for (int j = 0; j < 4; j++) {
            float ev = __expf(a[j]);
            e[c0 + j] = ev; sum += ev; qq = fmaf(ev, ev, qq);
        }
    }
    float inv = 1.f / sum;
    uint2* sp = (uint2*)(s1b32 + (size_t)row * 50);   // row = 200 B, 8B-aligned
#pragma unroll
    for (int q = 0; q < 25; q++) {
        uint2 v;
        v.x = pk2(e[4*q] * inv,   e[4*q+1] * inv);
        v.y = pk2(e[4*q+2] * inv, e[4*q+3] * inv);
        sp[q] = v;
    }
    float contrib = (float)csrc[row] * qq * inv * inv;
#pragma unroll
    for (int off = 32; off >= 1; off >>= 1) contrib += __shfl_xor(contrib, off);
    if ((tid & 63) == 0) atomicAdd(&den1[row >> 9], contrib);
}

// ------------- t1 gather (bf16): wave per node, lane owns 2 channels
__global__ __launch_bounds__(256) void k_t1g(const int* __restrict__ sdst, const int* __restrict__ osr,
                                             const int* __restrict__ csr, const u32* __restrict__ s1b32,
                                             u32* __restrict__ t1b32) {
    int tid = threadIdx.x;
    int n = blockIdx.x * 4 + (tid >> 6), lane = tid & 63;
    if (lane >= 50) return;
    int base = osr[n], cnt = csr[n];
    float a0 = 0.f, a1 = 0.f;
    int i = 0;
    for (; i + 4 <= cnt; i += 4) {
        int d0 = sdst[base + i], d1 = sdst[base + i + 1];
        int d2 = sdst[base + i + 2], d3 = sdst[base + i + 3];
        u32 u0 = s1b32[(size_t)d0 * 50 + lane];
        u32 u1 = s1b32[(size_t)d1 * 50 + lane];
        u32 u2 = s1b32[(size_t)d2 * 50 + lane];
        u32 u3 = s1b32[(size_t)d3 * 50 + lane];
        a0 += (blo(u0) + blo(u1)) + (blo(u2) + blo(u3));
        a1 += (bhi(u0) + bhi(u1)) + (bhi(u2) + bhi(u3));
    }
    for (; i < cnt; i++) {
        int d0 = sdst[base + i];
        u32 u0 = s1b32[(size_t)d0 * 50 + lane];
        a0 += blo(u0); a1 += bhi(u0);
    }
    t1b32[(size_t)n * 50 + lane] = pk2(a0, a1);
}

// --- gram via MFMA: C = s1^T [t1 | h | s1] (100 x 232); bf16, 4 slabs.
// LDS holds ZT = Z transposed (channel-major) so A/B frags are contiguous b128.
// A = ZT rows 132.., B = ZT rows 0..; rows 232..263 zeroed (tile padding).
__global__ __launch_bounds__(512, 4) void k_gram(const u32* __restrict__ s1b32, const u32* __restrict__ t1b32,
                                                 const u32* __restrict__ hb32, float* __restrict__ Cp) {
    __shared__ u16 sZ[2][ZTR * ZTS];         // 2 x 21.1 KB
    int g = blockIdx.x >> 2, slab = blockIdx.x & 3;
    int nbase = g * NN + slab * 128;         // 4 chunks of 32 rows
    int tid = threadIdx.x;
    int wave = tid >> 6, lane = tid & 63;
    int mt = wave & 3;                       // output-row tile: k = mt*32 + row
    int nt0 = (wave >> 2) * 4;               // this wave: nt0..nt0+3
    int lc = lane & 31, half = lane >> 5;

    f32x16 acc[4];
#pragma unroll
    for (int t = 0; t < 4; t++)
#pragma unroll
        for (int r = 0; r < 16; r++) acc[t][r] = 0.f;

    // zero the padding rows of both buffers (channels 232..263)
    for (int i = tid; i < 32 * ZTS; i += 512) {
        int r = 232 + i / ZTS, c = i % ZTS;
        sZ[0][r * ZTS + c] = 0; sZ[1][r * ZTS + c] = 0;
    }
    // ---- stage chunk 0 into buffer 0 (transposing: uint2 = 4 channels of row n)
#pragma unroll
    for (int j = 0; j < 4; j++) {
        int i = tid + j * 512;
        if (i < 32 * 58) {
            int r = i / 58, q = i - r * 58;
            int n = nbase + r;
            uint2 v; int ch0;
            if (q < 25)      { v = ((const uint2*)(t1b32 + (size_t)n * 50))[q];      ch0 = 4 * q; }
            else if (q < 33) { v = ((const uint2*)(hb32  + (size_t)n * 16))[q - 25]; ch0 = 100 + 4 * (q - 25); }
            else             { v = ((const uint2*)(s1b32 + (size_t)n * 50))[q - 33]; ch0 = 132 + 4 * (q - 33); }
            sZ[0][(ch0    ) * ZTS + r] = (u16)(v.x & 0xffffu);
            sZ[0][(ch0 + 1) * ZTS + r] = (u16)(v.x >> 16);
            sZ[0][(ch0 + 2) * ZTS + r] = (u16)(v.y & 0xffffu);
            sZ[0][(ch0 + 3) * ZTS + r] = (u16)(v.y >> 16);
        }
    }
    __syncthreads();

    for (int nt = 0; nt < 4; nt++) {
        // ---- prefetch chunk nt+1 into registers
        uint2 pre[4];
        if (nt < 3) {
#pragma unroll
            for (int j = 0; j < 4; j++) {
                int i = tid + j * 512;
                if (i < 32 * 58) {
                    int r = i / 58, q = i - r * 58;
                    int n = nbase + (nt + 1) * 32 + r;
                    uint2 v;
                    if (q < 25)      v = ((const uint2*)(t1b32 + (size_t)n * 50))[q];
                    else if (q < 33) v = ((const uint2*)(hb32  + (size_t)n * 16))[q - 25];
                    else             v = ((const uint2*)(s1b32 + (size_t)n * 50))[q - 33];
                    pre[j] = v;
                }
            }
        }
        // ---- MFMA on current buffer
        const u16* zb = sZ[nt & 1];
#pragma unroll
        for (int mf = 0; mf < 2; mf++) {
            bf16x8 af = *(const bf16x8*)&zb[(132 + mt * 32 + lc) * ZTS + mf * 16 + half * 8];
#pragma unroll
            for (int t = 0; t < 4; t++) {
                bf16x8 bfv = *(const bf16x8*)&zb[((nt0 + t) * 32 + lc) * ZTS + mf * 16 + half * 8];
                acc[t] = __builtin_amdgcn_mfma_f32_32x32x16_bf16(af, bfv, acc[t], 0, 0, 0);
            }
        }
        // ---- commit prefetch to the other buffer
        if (nt < 3) {
            u16* zo = sZ[(nt + 1) & 1];
#pragma unroll
            for (int j = 0; j < 4; j++) {
                int i = tid + j * 512;
                if (i < 32 * 58) {
                    int r = i / 58, q = i - r * 58;
                    int ch0 = (q < 25) ? (4 * q) : ((q < 33) ? (100 + 4 * (q - 25)) : (132 + 4 * (q - 33)));
                    zo[(ch0    ) * ZTS + r] = (u16)(pre[j].x & 0xffffu);
                    zo[(ch0 + 1) * ZTS + r] = (u16)(pre[j].x >> 16);
                    zo[(ch0 + 2) * ZTS + r] = (u16)(pre[j].y & 0xffffu);
                    zo[(ch0 + 3) * ZTS + r] = (u16)(pre[j].y >> 16);
                }
            }
        }
        __syncthreads();
    }
    // ---- epilogue: C/D layout col=lane&31, row=(reg&3)+8*(reg>>2)+4*(lane>>5)
    float* outp = Cp + ((size_t)slab * TB + g) * (KP1 * 232);
#pragma unroll
    for (int t = 0; t < 4; t++) {
        int l = (nt0 + t) * 32 + lc;
        if (l < 232) {
#pragma unroll
            for (int r = 0; r < 16; r++) {
                int k = mt * 32 + (r & 3) + 8 * (r >> 2) + 4 * half;
                if (k < KP1) outp[k * 232 + l] = acc[t][r];
            }
        }
    }
}

// ---- finalize stage 1: sum 4 slabs, losses, normalize out_adj, emit P1
__global__ __launch_bounds__(128) void k_fin1(const float* __restrict__ Cp, const float* __restrict__ den1,
                                              float* __restrict__ A1n, float* __restrict__ P1,
                                              float* __restrict__ aux) {
    __shared__ float sA[KP1 * KP1];          // 40 KB
    __shared__ float sd[KP1];
    __shared__ float r1[128], r2[128], r3[128];
    int g = blockIdx.x, tid = threadIdx.x;
    const float* c0 = Cp + (size_t)g * (KP1 * 232);
    const float* c1 = Cp + ((size_t)TB + g) * (KP1 * 232);
    const float* c2 = Cp + ((size_t)2 * TB + g) * (KP1 * 232);
    const float* c3 = Cp + ((size_t)3 * TB + g) * (KP1 * 232);
    float ssq = 0.f, troa = 0.f, trss = 0.f;
    if (tid < KP1) {
        int k = tid;
        float rs = 0.f;
        for (int l = 0; l < KP1; l++) {
            float oa = (c0[k * 232 + l] + c1[k * 232 + l]) + (c2[k * 232 + l] + c3[k * 232 + l]);
            sA[k * KP1 + l] = oa;
            if (l != k) rs += oa; else troa += oa;
            float ssv = (c0[k * 232 + 132 + l] + c1[k * 232 + 132 + l])
                      + (c2[k * 232 + 132 + l] + c3[k * 232 + 132 + l]);
            ssq += ssv * ssv;
            if (l == k) trss += ssv;
        }
        sd[k] = sqrtf(rs) + 1e-15f;
        for (int cc = 0; cc < HH; cc++)
            P1[((size_t)g * KP1 + k) * HH + cc] =
                (c0[k * 232 + 100 + cc] + c1[k * 232 + 100 + cc])
              + (c2[k * 232 + 100 + cc] + c3[k * 232 + 100 + cc]);
    }
    r1[tid] = ssq; r2[tid] = troa; r3[tid] = trss; __syncthreads();
#pragma unroll
    for (int s = 64; s > 0; s >>= 1) {
        if (tid < s) { r1[tid] += r1[tid + s]; r2[tid] += r2[tid + s]; r3[tid] += r3[tid + s]; }
        __syncthreads();
    }
    if (tid == 0) {
        float ssF = sqrtf(r1[0]);
        float o1 = sqrtf(fmaxf(2.f - 2.f * r3[0] / (ssF * 10.f), 0.f));  // sqrt(K1)=10
        aux[128 + g] = -(r2[0] / den1[g]) + o1;
    }
    __syncthreads();
    for (int i = tid; i < KP1 * KP1; i += 128) {
        int k = i / KP1, l = i % KP1;
        A1n[(size_t)g * (KP1 * KP1) + i] = (k == l) ? 0.f : sA[i] / (sd[k] * sd[l]);
    }
}

// ------- stage 2a: conv2 + pool2 (per graph); A read from global (L2)
__global__ __launch_bounds__(512) void k_s2a(const float* __restrict__ A1n, const float* __restrict__ P1,
                                             const float* __restrict__ relW, const float* __restrict__ relB,
                                             const float* __restrict__ rootW,
                                             const float* __restrict__ p2W, const float* __restrict__ p2B,
                                             float* __restrict__ P2, float* __restrict__ A2n,
                                             float* __restrict__ aux) {
    __shared__ float sX[KP1 * HH];           // x1p then x2
    __shared__ float sY[KP1 * HH];           // y = A @ x1p
    __shared__ float sS2[KP1 * KP2];
    __shared__ float sT2[KP1 * KP2];
    __shared__ float sA2[100], sB2[100], sdd[10], red[100];
    int g = blockIdx.x, tid = threadIdx.x;
    const float* Ag = A1n + (size_t)g * (KP1 * KP1);
    for (int i = tid; i < KP1 * HH; i += 512) sX[i] = P1[(size_t)g * (KP1 * HH) + i];
    __syncthreads();

    int n = tid >> 2, cq = tid & 3;          // 400 active threads for y / x2
    // y = A @ x1p
    if (tid < 400) {
        float yv[8];
#pragma unroll
        for (int j = 0; j < 8; j++) yv[j] = 0.f;
        for (int mq = 0; mq < 25; mq++) {
            float4 a4 = *(const float4*)&Ag[n * KP1 + mq * 4];
            const float* xb = &sX[(mq * 4) * HH + cq * 8];
            float aa[4] = {a4.x, a4.y, a4.z, a4.w};
#pragma unroll
            for (int mm = 0; mm < 4; mm++) {
                const float* xr = xb + mm * HH;
#pragma unroll
                for (int j = 0; j < 8; j++) yv[j] = fmaf(aa[mm], xr[j], yv[j]);
            }
        }
#pragma unroll
        for (int j = 0; j < 8; j++) sY[n * HH + cq * 8 + j] = yv[j];
    }
    __syncthreads();
    // x2 = relu(y @ relW + relB + x1p @ rootW)
    float x2v[8];
    if (tid < 400) {
#pragma unroll
        for (int j = 0; j < 8; j++) x2v[j] = relB[cq * 8 + j];
        for (int j = 0; j < 32; j++) {
            float yj = sY[n * HH + j];
            float xj = sX[n * HH + j];
            float4 r0 = *(const float4*)&relW[j * 32 + cq * 8];
            float4 r1v = *(const float4*)&relW[j * 32 + cq * 8 + 4];
            float4 q0 = *(const float4*)&rootW[j * 32 + cq * 8];
            float4 q1 = *(const float4*)&rootW[j * 32 + cq * 8 + 4];
            x2v[0] += yj * r0.x + xj * q0.x;  x2v[1] += yj * r0.y + xj * q0.y;
            x2v[2] += yj * r0.z + xj * q0.z;  x2v[3] += yj * r0.w + xj * q0.w;
            x2v[4] += yj * r1v.x + xj * q1.x; x2v[5] += yj * r1v.y + xj * q1.y;
            x2v[6] += yj * r1v.z + xj * q1.z; x2v[7] += yj * r1v.w + xj * q1.w;
        }
    }
    __syncthreads();
    if (tid < 400) {
#pragma unroll
        for (int j = 0; j < 8; j++) sX[n * HH + cq * 8 + j] = fmaxf(x2v[j], 0.f);
    }
    __syncthreads();
    // s2 = softmax(x2 @ p2W + p2B); d2 and den2 partials
    if (tid < KP1) {
        float lg[10];
#pragma unroll
        for (int j = 0; j < 10; j++) lg[j] = p2B[j];
        for (int c = 0; c < 32; c++) {
            float xv = sX[tid * HH + c];
#pragma unroll
            for (int j = 0; j < 10; j++) lg[j] = fmaf(xv, p2W[c * 10 + j], lg[j]);
        }
        float mx = lg[0];
#pragma unroll
        for (int j = 1; j < 10; j++) mx = fmaxf(mx, lg[j]);
        float se = 0.f;
#pragma unroll
        for (int j = 0; j < 10; j++) { lg[j] = __expf(lg[j] - mx); se += lg[j]; }
        float inv = 1.f / se, sq = 0.f;
#pragma unroll
        for (int j = 0; j < 10; j++) { float sv = lg[j] * inv; sS2[tid * 10 + j] = sv; sq += sv * sv; }
        float d2 = 0.f;
        for (int mq = 0; mq < 25; mq++) {
            float4 a4 = *(const float4*)&Ag[tid * KP1 + mq * 4];
            d2 += a4.x + a4.y + a4.z + a4.w;
        }
        red[tid] = d2 * sq;
    }
    __syncthreads();
    // t2 = A @ s2 ; P2 = s2^T x2
    for (int p = tid; p < KP1 * KP2; p += 512) {
        int n2 = p / 10, jj = p % 10;
        float a = 0.f;
        for (int m = 0; m < KP1; m++) a = fmaf(Ag[n2 * KP1 + m], sS2[m * 10 + jj], a);
        sT2[p] = a;
    }
    if (tid < KP2 * HH) {
        int k = tid >> 5, cc = tid & 31;
        float a = 0.f;
        for (int n2 = 0; n2 < KP1; n2++) a = fmaf(sS2[n2 * 10 + k], sX[n2 * HH + cc], a);
        P2[(size_t)g * (KP2 * HH) + tid] = a;
    }
    __syncthreads();
    // oa2, ss2
    if (tid < 100) {
        int k = tid / 10, l = tid % 10;
        float oa = 0.f, ss = 0.f;
        for (int n2 = 0; n2 < KP1; n2++) {
            float sk = sS2[n2 * 10 + k];
            oa = fmaf(sk, sT2[n2 * 10 + l], oa);
            ss = fmaf(sk, sS2[n2 * 10 + l], ss);
        }
        sA2[tid] = oa; sB2[tid] = ss;
    }
    __syncthreads();
    if (tid == 0) {
        float den2 = 0.f;
        for (int i = 0; i < 100; i++) den2 += red[i];
        float troa = 0.f, trss = 0.f, ssq = 0.f;
        for (int k = 0; k < 10; k++) { troa += sA2[k * 10 + k]; trss += sB2[k * 10 + k]; }
        for (int i = 0; i < 100; i++) ssq += sB2[i] * sB2[i];
        float o2 = sqrtf(fmaxf(2.f - 2.f * trss / (sqrtf(ssq) * 3.16227766f), 0.f)); // sqrt(10)
        aux[256 + g] = -(troa / den2) + o2;
    }
    if (tid < 10) {
        float rs = 0.f;
        for (int l = 0; l < 10; l++) if (l != tid) rs += sA2[tid * 10 + l];
        sdd[tid] = sqrtf(rs) + 1e-15f;
    }
    __syncthreads();
    if (tid < 100) {
        int k = tid / 10, l = tid % 10;
        A2n[(size_t)g * 100 + tid] = (k == l) ? 0.f : sA2[tid] / (sdd[k] * sdd[l]);
    }
}

// ---------------- stage 2b: conv3 + mean + MLP head + log_softmax
__global__ __launch_bounds__(64) void k_s2b(const float* __restrict__ P2, const float* __restrict__ A2n,
                                            const float* __restrict__ relW3, const float* __restrict__ relb3,
                                            const float* __restrict__ rootW3,
                                            const float* __restrict__ l1W, const float* __restrict__ l1b,
                                            const float* __restrict__ l2W, const float* __restrict__ l2b,
                                            float* __restrict__ out) {
    __shared__ float sP[KP2 * HH], sA2[100], sY3[KP2 * HH], sG[32], sG1[32], sL[10], sLse;
    int g = blockIdx.x, tid = threadIdx.x;
    for (int i = tid; i < KP2 * HH; i += 64) sP[i] = P2[(size_t)g * (KP2 * HH) + i];
    for (int i = tid; i < 100; i += 64) sA2[i] = A2n[(size_t)g * 100 + i];
    if (tid < 32) sG[tid] = 0.f;
    __syncthreads();
    for (int p = tid; p < KP2 * HH; p += 64) {
        int k = p >> 5, cc = p & 31;
        float a = 0.f;
#pragma unroll
        for (int m = 0; m < 10; m++) a = fmaf(sA2[k * 10 + m], sP[m * HH + cc], a);
        sY3[p] = a;
    }
    __syncthreads();
    for (int p = tid; p < KP2 * HH; p += 64) {
        int k = p >> 5, cc = p & 31;
        float v = relb3[cc];
        for (int j = 0; j < 32; j++)
            v += sY3[k * HH + j] * relW3[j * 32 + cc] + sP[k * HH + j] * rootW3[j * 32 + cc];
        atomicAdd(&sG[cc], v * 0.1f);        // mean over 10 nodes
    }
    __syncthreads();
    if (tid < 32) {
        float v = l1b[tid];
        for (int j = 0; j < 32; j++) v = fmaf(sG[j], l1W[j * 32 + tid], v);
        sG1[tid] = fmaxf(v, 0.f);
    }
    __syncthreads();
    if (tid < 10) {
        float v = l2b[tid];
        for (int j = 0; j < 32; j++) v = fmaf(sG1[j], l2W[j * 10 + tid], v);
        sL[tid] = v;
    }
    __syncthreads();
    if (tid == 0) {
        float mx = sL[0];
        for (int j = 1; j < 10; j++) mx = fmaxf(mx, sL[j]);
        float se = 0.f;
        for (int j = 0; j < 10; j++) se += expf(sL[j] - mx);
        sLse = mx + logf(se);
    }
    __syncthreads();
    if (tid < 10) out[(size_t)g * 10 + tid] = sL[tid] - sLse;
}

// ------------------------------------------------------ total loss
__global__ void k_loss(const float* __restrict__ aux, float* __restrict__ out) {
    __shared__ float red[128];
    int tid = threadIdx.x;
    red[tid] = aux[128 + tid] + aux[256 + tid];
    __syncthreads();
#pragma unroll
    for (int s = 64; s > 0; s >>= 1) { if (tid < s) red[tid] += red[tid + s]; __syncthreads(); }
    if (tid == 0) out[1280] = red[0] * (1.f / 128.f);
}

extern "C" void kernel_launch(void* const* d_in, const int* in_sizes, int n_in,
                              void* d_out, int out_size, void* d_ws, size_t ws_size,
                              hipStream_t stream) {
    const float* x    = (const float*)d_in[0];
    const int*   ei   = (const int*)d_in[1];
    const float* c1W  = (const float*)d_in[3];
    const float* c1b  = (const float*)d_in[4];
    const float* p1W  = (const float*)d_in[5];
    const float* p1b  = (const float*)d_in[6];
    const float* relW2  = (const float*)d_in[7];
    const float* relb2  = (const float*)d_in[8];
    const float* rootW2 = (const float*)d_in[9];
    const float* p2W  = (const float*)d_in[10];
    const float* p2b  = (const float*)d_in[11];
    const float* relW3  = (const float*)d_in[12];
    const float* relb3  = (const float*)d_in[13];
    const float* rootW3 = (const float*)d_in[14];
    const float* l1W  = (const float*)d_in[15];
    const float* l1b  = (const float*)d_in[16];
    const float* l2W  = (const float*)d_in[17];
    const float* l2b  = (const float*)d_in[18];
    float* out = (float*)d_out;

    // ---- workspace layout
    int*  cnt_src = (int*)d_ws;                       // NT
    int*  cnt_dst = cnt_src + NT;                     // NT
    int*  off_src = cnt_dst + NT;                     // NT
    int*  off_dst = off_src + NT;                     // NT
    int*  cur_src = off_dst + NT;                     // NT
    int*  cur_dst = cur_src + NT;                     // NT
    int*  srt_dst = cur_dst + NT;                     // ET (src-sorted, stores dst)
    int*  srt_src = srt_dst + ET;                     // ET (dst-sorted, stores src)
    float* dis = (float*)(srt_src + ET);              // NT
    u32*  xwb  = (u32*)(dis + NT);                    // NT*16 (bf16 x2)
    u32*  hb   = xwb + (size_t)NT * 16;               // NT*16
    u32*  s1b  = hb + (size_t)NT * 16;                // NT*50
    u32*  t1b  = s1b + (size_t)NT * 50;               // NT*50
    float* h    = (float*)(t1b + (size_t)NT * 50);    // NT*HH fp32
    float* Cp   = h + (size_t)NT * HH;                // 4*TB*KP1*232
    float* A1n  = Cp + (size_t)4 * TB * (KP1 * 232);  // TB*KP1*KP1
    float* P1   = A1n + (size_t)TB * KP1 * KP1;       // TB*KP1*HH
    float* P2   = P1 + (size_t)TB * KP1 * HH;         // TB*KP2*HH
    float* A2n  = P2 + (size_t)TB * KP2 * HH;         // TB*100
    float* aux  = A2n + (size_t)TB * 100;             // 1024: den1|loss1|loss2

    k_init<<<NT / 256, 256, 0, stream>>>(cnt_src, cnt_dst, aux);
    k_cnt<<<ET / 256, 256, 0, stream>>>(ei, cnt_src, cnt_dst);
    k_scan<<<TB, 512, 0, stream>>>(cnt_src, cnt_dst, off_src, off_dst, cur_src, cur_dst);
    k_scatter<<<ET / 256, 256, 0, stream>>>(ei, cur_src, cur_dst, srt_dst, srt_src);
    k_dis<<<NT / 256, 256, 0, stream>>>(cnt_dst, dis);
    k_xw<<<(NT * HH) / 256, 256, 0, stream>>>(x, c1W, (u16*)xwb);
    k_gcng<<<NT / 16, 256, 0, stream>>>(srt_src, off_dst, cnt_dst, xwb, dis, c1b, h, hb);
    k_s1<<<NT / 128, 128, 0, stream>>>(h, p1W, p1b, cnt_src, s1b, aux /*den1*/);
    k_t1g<<<NT / 4, 256, 0, stream>>>(srt_dst, off_src, cnt_src, s1b, t1b);
    k_gram<<<TB * 4, 512, 0, stream>>>(s1b, t1b, hb, Cp);
    k_fin1<<<TB, 128, 0, stream>>>(Cp, aux /*den1*/, A1n, P1, aux);
    k_s2a<<<TB, 512, 0, stream>>>(A1n, P1, relW2, relb2, rootW2, p2W, p2b, P2, A2n, aux);
    k_s2b<<<TB, 64, 0, stream>>>(P2, A2n, relW3, relb3, rootW3, l1W, l1b, l2W, l2b, out);
    k_loss<<<1, 128, 0, stream>>>(aux, out);
}

// Round 8
// 451.877 us; speedup vs baseline: 3.6348x; 1.0687x over previous
//
#include <hip/hip_runtime.h>
#include <hip/hip_bf16.h>

// Problem constants (match reference)
#define TB   128          // batch B
#define NN   512          // nodes per graph
#define INC  128          // IN_C
#define HH   32           // HID
#define KP1  100          // K1
#define KP2  10           // K2
#define OC   10           // OUT_C
#define EPER 8192         // edges per graph
#define NT   (TB*NN)      // 65536 total nodes
#define ET   (TB*EPER)    // 1048576 total edges
#define ZTR  264          // gram ZT rows: 232 Z-cols + 32 zero pad (partial MFMA tiles)
#define ZTS  40           // ZT row stride in u16 (80 B, 16B-aligned for ds_read_b128)

typedef unsigned int  u32;
typedef unsigned short u16;
typedef __attribute__((ext_vector_type(8))) short bf16x8;   // 8 bf16 = 4 VGPR (MFMA A/B frag)
typedef __attribute__((ext_vector_type(16))) float f32x16;  // MFMA C/D frag

// bf16 helpers (RNE encode; exact decode)
__device__ __forceinline__ u32 bfr(float f) {
    u32 b = __float_as_uint(f);
    return (b + 0x7fffu + ((b >> 16) & 1u)) >> 16;
}
__device__ __forceinline__ u32 pk2(float a, float b) { return bfr(a) | (bfr(b) << 16); }
__device__ __forceinline__ float blo(u32 u) { return __uint_as_float(u << 16); }
__device__ __forceinline__ float bhi(u32 u) { return __uint_as_float(u & 0xffff0000u); }

// ---------------------------------------------------------------- init
__global__ void k_init(int* __restrict__ cs, int* __restrict__ cd, float* __restrict__ aux) {
    int i = blockIdx.x * 256 + threadIdx.x;
    if (i < NT) { cs[i] = 0; cd[i] = 0; }
    if (i < 1024) aux[i] = 0.0f;              // den1 / loss1 / loss2 accumulators
}

// ---------------------------------------------- edge degree histograms
__global__ void k_cnt(const int* __restrict__ ei, int* __restrict__ cs, int* __restrict__ cd) {
    int e = blockIdx.x * 256 + threadIdx.x;
    if (e < ET) {
        atomicAdd(&cs[ei[e]], 1);             // out-degree (src)  = adj.sum(-1)
        atomicAdd(&cd[ei[ET + e]], 1);        // in-degree  (dst)  for GCN norm
    }
}

// ---------------- per-graph exclusive scan of both degree histograms
__global__ __launch_bounds__(512) void k_scan(const int* __restrict__ cs, const int* __restrict__ cd,
                                              int* __restrict__ os, int* __restrict__ od,
                                              int* __restrict__ curs, int* __restrict__ curd) {
    __shared__ int sa[512], sb[512];
    int g = blockIdx.x, tid = threadIdx.x, i = g * NN + tid;
    int vs = cs[i], vd = cd[i];
    sa[tid] = vs; sb[tid] = vd; __syncthreads();
    for (int off = 1; off < 512; off <<= 1) {
        int xa = sa[tid], xb = sb[tid];
        if (tid >= off) { xa += sa[tid - off]; xb += sb[tid - off]; }
        __syncthreads(); sa[tid] = xa; sb[tid] = xb; __syncthreads();
    }
    int es = g * EPER + sa[tid] - vs;         // exclusive scan, global position
    int ed = g * EPER + sb[tid] - vd;
    os[i] = es; od[i] = ed; curs[i] = es; curd[i] = ed;
}

// ----------------- counting-sort scatter: edges by src and by dst
__global__ void k_scatter(const int* __restrict__ ei, int* __restrict__ curs, int* __restrict__ curd,
                          int* __restrict__ sdst, int* __restrict__ ssrc) {
    int e = blockIdx.x * 256 + threadIdx.x;
    if (e < ET) {
        int s = ei[e], d = ei[ET + e];
        int p = atomicAdd(&curs[s], 1); sdst[p] = d;   // src-sorted: store dst
        int q = atomicAdd(&curd[d], 1); ssrc[q] = s;   // dst-sorted: store src
    }
}

__global__ void k_dis(const int* __restrict__ cd, float* __restrict__ dis) {
    int i = blockIdx.x * 256 + threadIdx.x;
    if (i < NT) dis[i] = rsqrtf(1.0f + (float)cd[i]);  // +1 self loop
}

// ------------------------------ xw = bf16(x @ conv1_W)  [NT,32] bf16
__global__ __launch_bounds__(256) void k_xw(const float* __restrict__ x, const float* __restrict__ W,
                                            u16* __restrict__ xwb) {
    __shared__ float sWT[32][132];           // W^T, padded stride
    int tid = threadIdx.x;
    for (int i = tid; i < INC * HH; i += 256) { int k = i >> 5, c = i & 31; sWT[c][k] = W[i]; }
    __syncthreads();
    int id = blockIdx.x * 256 + tid;
    int row = id >> 5, c = id & 31;
    const float4* xp = (const float4*)(x + (size_t)row * INC);
    float acc = 0.f;
#pragma unroll
    for (int kq = 0; kq < INC / 4; kq++) {
        float4 xv = xp[kq];
        float4 wv = *(const float4*)&sWT[c][kq * 4];
        acc += xv.x * wv.x + xv.y * wv.y + xv.z * wv.z + xv.w * wv.w;
    }
    xwb[id] = (u16)bfr(acc);
}

// -------- GCN gather (bf16 xw): h fp32 + hb bf16; 2 channels per lane
__global__ __launch_bounds__(256) void k_gcng(const int* __restrict__ ssrc, const int* __restrict__ od,
                                              const int* __restrict__ cd, const u32* __restrict__ xwb32,
                                              const float* __restrict__ dis, const float* __restrict__ bias,
                                              float* __restrict__ h, u32* __restrict__ hb32) {
    int tid = threadIdx.x;
    int n = blockIdx.x * 16 + (tid >> 4), cp = tid & 15;  // cp -> channels 2cp,2cp+1
    int base = od[n], cnt = cd[n];
    float dn = dis[n];
    u32 us = xwb32[(size_t)n * 16 + cp];
    float a0 = dn * blo(us), a1 = dn * bhi(us);           // self-loop term
    int i = 0;
    for (; i + 4 <= cnt; i += 4) {
        int s0 = ssrc[base + i], s1v = ssrc[base + i + 1];
        int s2 = ssrc[base + i + 2], s3 = ssrc[base + i + 3];
        float d0 = dis[s0], d1 = dis[s1v], d2 = dis[s2], d3 = dis[s3];
        u32 u0 = xwb32[(size_t)s0 * 16 + cp];
        u32 u1 = xwb32[(size_t)s1v * 16 + cp];
        u32 u2 = xwb32[(size_t)s2 * 16 + cp];
        u32 u3 = xwb32[(size_t)s3 * 16 + cp];
        a0 += d0 * blo(u0) + d1 * blo(u1) + d2 * blo(u2) + d3 * blo(u3);
        a1 += d0 * bhi(u0) + d1 * bhi(u1) + d2 * bhi(u2) + d3 * bhi(u3);
    }
    for (; i < cnt; i++) {
        int s0 = ssrc[base + i]; float d0 = dis[s0];
        u32 u0 = xwb32[(size_t)s0 * 16 + cp];
        a0 += d0 * blo(u0); a1 += d0 * bhi(u0);
    }
    float v0 = fmaxf(dn * a0 + bias[2 * cp], 0.f);
    float v1 = fmaxf(dn * a1 + bias[2 * cp + 1], 0.f);
    *(float2*)&h[(size_t)n * HH + 2 * cp] = make_float2(v0, v1);
    hb32[(size_t)n * 16 + cp] = pk2(v0, v1);
}

// ------- s1 = softmax(h @ pool1_W + b): thread-per-row; bf16 output
__global__ __launch_bounds__(128) void k_s1(const float* __restrict__ h, const float* __restrict__ W,
                                            const float* __restrict__ bias, const int* __restrict__ csrc,
                                            u32* __restrict__ s1b32, float* __restrict__ den1) {
    int tid = threadIdx.x;
    int row = blockIdx.x * 128 + tid;
    float hr[HH];
    const float4* hp = (const float4*)(h + (size_t)row * HH);
#pragma unroll
    for (int q = 0; q < HH / 4; q++) {
        float4 a = hp[q];
        hr[4*q] = a.x; hr[4*q+1] = a.y; hr[4*q+2] = a.z; hr[4*q+3] = a.w;
    }
    float e[KP1];
    float sum = 0.f, qq = 0.f;
#pragma unroll
    for (int g8 = 0; g8 < 12; g8++) {
        const int c0 = g8 * 8;
        float a[8];
#pragma unroll
        for (int j = 0; j < 8; j++) a[j] = bias[c0 + j];
#pragma unroll
        for (int k = 0; k < HH; k++) {
            const float* wr = W + k * KP1 + c0;
#pragma unroll
            for (int j = 0; j < 8; j++) a[j] = fmaf(hr[k], wr[j], a[j]);
        }
#pragma unroll
        for (int j = 0; j < 8; j++) {
            float ev = __expf(a[j]);
            e[c0 + j] = ev; sum += ev; qq = fmaf(ev, ev, qq);
        }
    }
    { // tail group: channels 96..99
        const int c0 = 96;
        float a[4];
#pragma unroll
        for (int j = 0; j < 4; j++) a[j] = bias[c0 + j];
#pragma unroll
        for (int k = 0; k < HH; k++) {
            const float* wr = W + k * KP1 + c0;
#pragma unroll
            for (int j = 0; j < 4; j++) a[j] = fmaf(hr[k], wr[j], a[j]);
        }
#pragma unroll
        for (int j = 0; j < 4; j++) {
            float ev = __expf(a[j]);
            e[c0 + j] = ev; sum += ev; qq = fmaf(ev, ev, qq);
        }
    }
    float inv = 1.f / sum;
    uint2* sp = (uint2*)(s1b32 + (size_t)row * 50);   // row = 200 B, 8B-aligned
#pragma unroll
    for (int q = 0; q < 25; q++) {
        uint2 v;
        v.x = pk2(e[4*q] * inv,   e[4*q+1] * inv);
        v.y = pk2(e[4*q+2] * inv, e[4*q+3] * inv);
        sp[q] = v;
    }
    float contrib = (float)csrc[row] * qq * inv * inv;
#pragma unroll
    for (int off = 32; off >= 1; off >>= 1) contrib += __shfl_xor(contrib, off);
    if ((tid & 63) == 0) atomicAdd(&den1[row >> 9], contrib);
}

// ------------- t1 gather (bf16): wave per node, lane owns 2 channels
__global__ __launch_bounds__(256) void k_t1g(const int* __restrict__ sdst, const int* __restrict__ osr,
                                             const int* __restrict__ csr, const u32* __restrict__ s1b32,
                                             u32* __restrict__ t1b32) {
    int tid = threadIdx.x;
    int n = blockIdx.x * 4 + (tid >> 6), lane = tid & 63;
    if (lane >= 50) return;
    int base = osr[n], cnt = csr[n];
    float a0 = 0.f, a1 = 0.f;
    int i = 0;
    for (; i + 4 <= cnt; i += 4) {
        int d0 = sdst[base + i], d1 = sdst[base + i + 1];
        int d2 = sdst[base + i + 2], d3 = sdst[base + i + 3];
        u32 u0 = s1b32[(size_t)d0 * 50 + lane];
        u32 u1 = s1b32[(size_t)d1 * 50 + lane];
        u32 u2 = s1b32[(size_t)d2 * 50 + lane];
        u32 u3 = s1b32[(size_t)d3 * 50 + lane];
        a0 += (blo(u0) + blo(u1)) + (blo(u2) + blo(u3));
        a1 += (bhi(u0) + bhi(u1)) + (bhi(u2) + bhi(u3));
    }
    for (; i < cnt; i++) {
        int d0 = sdst[base + i];
        u32 u0 = s1b32[(size_t)d0 * 50 + lane];
        a0 += blo(u0); a1 += bhi(u0);
    }
    t1b32[(size_t)n * 50 + lane] = pk2(a0, a1);
}

// --- gram via MFMA: C = s1^T [t1 | h | s1] (100 x 232); bf16, 4 slabs.
// LDS holds ZT = Z transposed (channel-major) so A/B frags are contiguous b128.
// A = ZT rows 132.., B = ZT rows 0..; rows 232..263 zeroed (tile padding).
__global__ __launch_bounds__(512, 4) void k_gram(const u32* __restrict__ s1b32, const u32* __restrict__ t1b32,
                                                 const u32* __restrict__ hb32, float* __restrict__ Cp) {
    __shared__ u16 sZ[2][ZTR * ZTS];         // 2 x 21.1 KB
    int g = blockIdx.x >> 2, slab = blockIdx.x & 3;
    int nbase = g * NN + slab * 128;         // 4 chunks of 32 rows
    int tid = threadIdx.x;
    int wave = tid >> 6, lane = tid & 63;
    int mt = wave & 3;                       // output-row tile: k = mt*32 + row
    int nt0 = (wave >> 2) * 4;               // this wave: nt0..nt0+3
    int lc = lane & 31, half = lane >> 5;

    f32x16 acc[4];
#pragma unroll
    for (int t = 0; t < 4; t++)
#pragma unroll
        for (int r = 0; r < 16; r++) acc[t][r] = 0.f;

    // zero the padding rows of both buffers (channels 232..263)
    for (int i = tid; i < 32 * ZTS; i += 512) {
        int r = 232 + i / ZTS, c = i % ZTS;
        sZ[0][r * ZTS + c] = 0; sZ[1][r * ZTS + c] = 0;
    }
    // ---- stage chunk 0 into buffer 0 (transposing: uint2 = 4 channels of row n)
#pragma unroll
    for (int j = 0; j < 4; j++) {
        int i = tid + j * 512;
        if (i < 32 * 58) {
            int r = i / 58, q = i - r * 58;
            int n = nbase + r;
            uint2 v; int ch0;
            if (q < 25)      { v = ((const uint2*)(t1b32 + (size_t)n * 50))[q];      ch0 = 4 * q; }
            else if (q < 33) { v = ((const uint2*)(hb32  + (size_t)n * 16))[q - 25]; ch0 = 100 + 4 * (q - 25); }
            else             { v = ((const uint2*)(s1b32 + (size_t)n * 50))[q - 33]; ch0 = 132 + 4 * (q - 33); }
            sZ[0][(ch0    ) * ZTS + r] = (u16)(v.x & 0xffffu);
            sZ[0][(ch0 + 1) * ZTS + r] = (u16)(v.x >> 16);
            sZ[0][(ch0 + 2) * ZTS + r] = (u16)(v.y & 0xffffu);
            sZ[0][(ch0 + 3) * ZTS + r] = (u16)(v.y >> 16);
        }
    }
    __syncthreads();

    for (int nt = 0; nt < 4; nt++) {
        // ---- prefetch chunk nt+1 into registers
        uint2 pre[4];
        if (nt < 3) {
#pragma unroll
            for (int j = 0; j < 4; j++) {
                int i = tid + j * 512;
                if (i < 32 * 58) {
                    int r = i / 58, q = i - r * 58;
                    int n = nbase + (nt + 1) * 32 + r;
                    uint2 v;
                    if (q < 25)      v = ((const uint2*)(t1b32 + (size_t)n * 50))[q];
                    else if (q < 33) v = ((const uint2*)(hb32  + (size_t)n * 16))[q - 25];
                    else             v = ((const uint2*)(s1b32 + (size_t)n * 50))[q - 33];
                    pre[j] = v;
                }
            }
        }
        // ---- MFMA on current buffer
        const u16* zb = sZ[nt & 1];
#pragma unroll
        for (int mf = 0; mf < 2; mf++) {
            bf16x8 af = *(const bf16x8*)&zb[(132 + mt * 32 + lc) * ZTS + mf * 16 + half * 8];
#pragma unroll
            for (int t = 0; t < 4; t++) {
                bf16x8 bfv = *(const bf16x8*)&zb[((nt0 + t) * 32 + lc) * ZTS + mf * 16 + half * 8];
                acc[t] = __builtin_amdgcn_mfma_f32_32x32x16_bf16(af, bfv, acc[t], 0, 0, 0);
            }
        }
        // ---- commit prefetch to the other buffer
        if (nt < 3) {
            u16* zo = sZ[(nt + 1) & 1];
#pragma unroll
            for (int j = 0; j < 4; j++) {
                int i = tid + j * 512;
                if (i < 32 * 58) {
                    int r = i / 58, q = i - r * 58;
                    int ch0 = (q < 25) ? (4 * q) : ((q < 33) ? (100 + 4 * (q - 25)) : (132 + 4 * (q - 33)));
                    zo[(ch0    ) * ZTS + r] = (u16)(pre[j].x & 0xffffu);
                    zo[(ch0 + 1) * ZTS + r] = (u16)(pre[j].x >> 16);
                    zo[(ch0 + 2) * ZTS + r] = (u16)(pre[j].y & 0xffffu);
                    zo[(ch0 + 3) * ZTS + r] = (u16)(pre[j].y >> 16);
                }
            }
        }
        __syncthreads();
    }
    // ---- epilogue: C/D layout col=lane&31, row=(reg&3)+8*(reg>>2)+4*(lane>>5)
    float* outp = Cp + ((size_t)slab * TB + g) * (KP1 * 232);
#pragma unroll
    for (int t = 0; t < 4; t++) {
        int l = (nt0 + t) * 32 + lc;
        if (l < 232) {
#pragma unroll
            for (int r = 0; r < 16; r++) {
                int k = mt * 32 + (r & 3) + 8 * (r >> 2) + 4 * half;
                if (k < KP1) outp[k * 232 + l] = acc[t][r];
            }
        }
    }
}

// ---- finalize stage 1: coalesced float4 slab sweep; losses; normalize; P1
__global__ __launch_bounds__(256) void k_fin1(const float* __restrict__ Cp, const float* __restrict__ den1,
                                              float* __restrict__ A1n, float* __restrict__ P1,
                                              float* __restrict__ aux) {
    __shared__ float sA[KP1 * KP1];          // 40 KB
    __shared__ float red[256];
    __shared__ float rs2[256];
    __shared__ float sdv[KP1];
    int g = blockIdx.x, tid = threadIdx.x;
    const float* b0 = Cp + (size_t)g * (KP1 * 232);
    const size_t SLAB = (size_t)TB * (KP1 * 232);
    float ssq = 0.f, trss = 0.f, troa = 0.f;
    // phase 1: sweep 100 rows x 58 float4 cols, coalesced; sum 4 slabs in flight
    for (int idx = tid; idx < KP1 * 58; idx += 256) {
        int k = idx / 58, q = idx - k * 58;
        size_t off = (size_t)k * 232 + q * 4;
        float4 v0 = *(const float4*)(b0 + off);
        float4 v1 = *(const float4*)(b0 + SLAB + off);
        float4 v2 = *(const float4*)(b0 + 2 * SLAB + off);
        float4 v3 = *(const float4*)(b0 + 3 * SLAB + off);
        float4 s;
        s.x = (v0.x + v1.x) + (v2.x + v3.x);
        s.y = (v0.y + v1.y) + (v2.y + v3.y);
        s.z = (v0.z + v1.z) + (v2.z + v3.z);
        s.w = (v0.w + v1.w) + (v2.w + v3.w);
        int c = q * 4;
        if (c < 100) {                        // out_adj block
            *(float4*)&sA[k * KP1 + c] = s;
            if (k >= c && k < c + 4) troa += ((const float*)&s)[k - c];
        } else if (c < 132) {                 // pooled features -> P1 direct
            *(float4*)&P1[((size_t)g * KP1 + k) * HH + (c - 100)] = s;
        } else {                              // ss block: reduce only
            ssq += s.x * s.x + s.y * s.y + s.z * s.z + s.w * s.w;
            int l0 = c - 132;
            if (k >= l0 && k < l0 + 4) trss += ((const float*)&s)[k - l0];
        }
    }
    // block reductions for ssq / trss / troa
    red[tid] = ssq; __syncthreads();
#pragma unroll
    for (int s = 128; s > 0; s >>= 1) { if (tid < s) red[tid] += red[tid + s]; __syncthreads(); }
    float ssqT = red[0]; __syncthreads();
    red[tid] = trss; __syncthreads();
#pragma unroll
    for (int s = 128; s > 0; s >>= 1) { if (tid < s) red[tid] += red[tid + s]; __syncthreads(); }
    float trssT = red[0]; __syncthreads();
    red[tid] = troa; __syncthreads();
#pragma unroll
    for (int s = 128; s > 0; s >>= 1) { if (tid < s) red[tid] += red[tid + s]; __syncthreads(); }
    float troaT = red[0]; __syncthreads();
    // phase 2: row sums (2 threads per row) -> sd
    if (tid < 200) {
        int k = tid >> 1, hf = tid & 1;
        const float* row = &sA[k * KP1 + hf * 50];
        float rs = 0.f;
        for (int l = 0; l < 50; l++) rs += row[l];
        rs2[tid] = rs;
    }
    __syncthreads();
    if (tid < KP1) {
        float rowsum = rs2[2 * tid] + rs2[2 * tid + 1] - sA[tid * KP1 + tid];
        sdv[tid] = sqrtf(rowsum) + 1e-15f;
    }
    if (tid == 0) {
        float ssF = sqrtf(ssqT);
        float o1 = sqrtf(fmaxf(2.f - 2.f * trssT / (ssF * 10.f), 0.f));  // sqrt(K1)=10
        aux[128 + g] = -(troaT / den1[g]) + o1;
    }
    __syncthreads();
    // phase 3: normalize out_adj, coalesced
    for (int i = tid; i < KP1 * KP1; i += 256) {
        int k = i / KP1, l = i - k * KP1;
        A1n[(size_t)g * (KP1 * KP1) + i] = (k == l) ? 0.f : sA[i] / (sdv[k] * sdv[l]);
    }
}

// ------- stage 2a: conv2 + pool2 (per graph); A read from global (L2)
__global__ __launch_bounds__(512) void k_s2a(const float* __restrict__ A1n, const float* __restrict__ P1,
                                             const float* __restrict__ relW, const float* __restrict__ relB,
                                             const float* __restrict__ rootW,
                                             const float* __restrict__ p2W, const float* __restrict__ p2B,
                                             float* __restrict__ P2, float* __restrict__ A2n,
                                             float* __restrict__ aux) {
    __shared__ float sX[KP1 * HH];           // x1p then x2
    __shared__ float sY[KP1 * HH];           // y = A @ x1p
    __shared__ float sS2[KP1 * KP2];
    __shared__ float sT2[KP1 * KP2];
    __shared__ float sA2[100], sB2[100], sdd[10], red[100];
    int g = blockIdx.x, tid = threadIdx.x;
    const float* Ag = A1n + (size_t)g * (KP1 * KP1);
    for (int i = tid; i < KP1 * HH; i += 512) sX[i] = P1[(size_t)g * (KP1 * HH) + i];
    __syncthreads();

    int n = tid >> 2, cq = tid & 3;          // 400 active threads for y / x2
    // y = A @ x1p
    if (tid < 400) {
        float yv[8];
#pragma unroll
        for (int j = 0; j < 8; j++) yv[j] = 0.f;
        for (int mq = 0; mq < 25; mq++) {
            float4 a4 = *(const float4*)&Ag[n * KP1 + mq * 4];
            const float* xb = &sX[(mq * 4) * HH + cq * 8];
            float aa[4] = {a4.x, a4.y, a4.z, a4.w};
#pragma unroll
            for (int mm = 0; mm < 4; mm++) {
                const float* xr = xb + mm * HH;
#pragma unroll
                for (int j = 0; j < 8; j++) yv[j] = fmaf(aa[mm], xr[j], yv[j]);
            }
        }
#pragma unroll
        for (int j = 0; j < 8; j++) sY[n * HH + cq * 8 + j] = yv[j];
    }
    __syncthreads();
    // x2 = relu(y @ relW + relB + x1p @ rootW)
    float x2v[8];
    if (tid < 400) {
#pragma unroll
        for (int j = 0; j < 8; j++) x2v[j] = relB[cq * 8 + j];
        for (int j = 0; j < 32; j++) {
            float yj = sY[n * HH + j];
            float xj = sX[n * HH + j];
            float4 r0 = *(const float4*)&relW[j * 32 + cq * 8];
            float4 r1v = *(const float4*)&relW[j * 32 + cq * 8 + 4];
            float4 q0 = *(const float4*)&rootW[j * 32 + cq * 8];
            float4 q1 = *(const float4*)&rootW[j * 32 + cq * 8 + 4];
            x2v[0] += yj * r0.x + xj * q0.x;  x2v[1] += yj * r0.y + xj * q0.y;
            x2v[2] += yj * r0.z + xj * q0.z;  x2v[3] += yj * r0.w + xj * q0.w;
            x2v[4] += yj * r1v.x + xj * q1.x; x2v[5] += yj * r1v.y + xj * q1.y;
            x2v[6] += yj * r1v.z + xj * q1.z; x2v[7] += yj * r1v.w + xj * q1.w;
        }
    }
    __syncthreads();
    if (tid < 400) {
#pragma unroll
        for (int j = 0; j < 8; j++) sX[n * HH + cq * 8 + j] = fmaxf(x2v[j], 0.f);
    }
    __syncthreads();
    // s2 = softmax(x2 @ p2W + p2B); d2 and den2 partials
    if (tid < KP1) {
        float lg[10];
#pragma unroll
        for (int j = 0; j < 10; j++) lg[j] = p2B[j];
        for (int c = 0; c < 32; c++) {
            float xv = sX[tid * HH + c];
#pragma unroll
            for (int j = 0; j < 10; j++) lg[j] = fmaf(xv, p2W[c * 10 + j], lg[j]);
        }
        float mx = lg[0];
#pragma unroll
        for (int j = 1; j < 10; j++) mx = fmaxf(mx, lg[j]);
        float se = 0.f;
#pragma unroll
        for (int j = 0; j < 10; j++) { lg[j] = __expf(lg[j] - mx); se += lg[j]; }
        float inv = 1.f / se, sq = 0.f;
#pragma unroll
        for (int j = 0; j < 10; j++) { float sv = lg[j] * inv; sS2[tid * 10 + j] = sv; sq += sv * sv; }
        float d2 = 0.f;
        for (int mq = 0; mq < 25; mq++) {
            float4 a4 = *(const float4*)&Ag[tid * KP1 + mq * 4];
            d2 += a4.x + a4.y + a4.z + a4.w;
        }
        red[tid] = d2 * sq;
    }
    __syncthreads();
    // t2 = A @ s2 ; P2 = s2^T x2
    for (int p = tid; p < KP1 * KP2; p += 512) {
        int n2 = p / 10, jj = p % 10;
        float a = 0.f;
        for (int m = 0; m < KP1; m++) a = fmaf(Ag[n2 * KP1 + m], sS2[m * 10 + jj], a);
        sT2[p] = a;
    }
    if (tid < KP2 * HH) {
        int k = tid >> 5, cc = tid & 31;
        float a = 0.f;
        for (int n2 = 0; n2 < KP1; n2++) a = fmaf(sS2[n2 * 10 + k], sX[n2 * HH + cc], a);
        P2[(size_t)g * (KP2 * HH) + tid] = a;
    }
    __syncthreads();
    // oa2, ss2
    if (tid < 100) {
        int k = tid / 10, l = tid % 10;
        float oa = 0.f, ss = 0.f;
        for (int n2 = 0; n2 < KP1; n2++) {
            float sk = sS2[n2 * 10 + k];
            oa = fmaf(sk, sT2[n2 * 10 + l], oa);
            ss = fmaf(sk, sS2[n2 * 10 + l], ss);
        }
        sA2[tid] = oa; sB2[tid] = ss;
    }
    __syncthreads();
    if (tid == 0) {
        float den2 = 0.f;
        for (int i = 0; i < 100; i++) den2 += red[i];
        float troa = 0.f, trss = 0.f, ssq = 0.f;
        for (int k = 0; k < 10; k++) { troa += sA2[k * 10 + k]; trss += sB2[k * 10 + k]; }
        for (int i = 0; i < 100; i++) ssq += sB2[i] * sB2[i];
        float o2 = sqrtf(fmaxf(2.f - 2.f * trss / (sqrtf(ssq) * 3.16227766f), 0.f)); // sqrt(10)
        aux[256 + g] = -(troa / den2) + o2;
    }
    if (tid < 10) {
        float rs = 0.f;
        for (int l = 0; l < 10; l++) if (l != tid) rs += sA2[tid * 10 + l];
        sdd[tid] = sqrtf(rs) + 1e-15f;
    }
    __syncthreads();
    if (tid < 100) {
        int k = tid / 10, l = tid % 10;
        A2n[(size_t)g * 100 + tid] = (k == l) ? 0.f : sA2[tid] / (sdd[k] * sdd[l]);
    }
}

// ---------------- stage 2b: conv3 + mean + MLP head + log_softmax
__global__ __launch_bounds__(64) void k_s2b(const float* __restrict__ P2, const float* __restrict__ A2n,
                                            const float* __restrict__ relW3, const float* __restrict__ relb3,
                                            const float* __restrict__ rootW3,
                                            const float* __restrict__ l1W, const float* __restrict__ l1b,
                                            const float* __restrict__ l2W, const float* __restrict__ l2b,
                                            float* __restrict__ out) {
    __shared__ float sP[KP2 * HH], sA2[100], sY3[KP2 * HH], sG[32], sG1[32], sL[10], sLse;
    int g = blockIdx.x, tid = threadIdx.x;
    for (int i = tid; i < KP2 * HH; i += 64) sP[i] = P2[(size_t)g * (KP2 * HH) + i];
    for (int i = tid; i < 100; i += 64) sA2[i] = A2n[(size_t)g * 100 + i];
    if (tid < 32) sG[tid] = 0.f;
    __syncthreads();
    for (int p = tid; p < KP2 * HH; p += 64) {
        int k = p >> 5, cc = p & 31;
        float a = 0.f;
#pragma unroll
        for (int m = 0; m < 10; m++) a = fmaf(sA2[k * 10 + m], sP[m * HH + cc], a);
        sY3[p] = a;
    }
    __syncthreads();
    for (int p = tid; p < KP2 * HH; p += 64) {
        int k = p >> 5, cc = p & 31;
        float v = relb3[cc];
        for (int j = 0; j < 32; j++)
            v += sY3[k * HH + j] * relW3[j * 32 + cc] + sP[k * HH + j] * rootW3[j * 32 + cc];
        atomicAdd(&sG[cc], v * 0.1f);        // mean over 10 nodes
    }
    __syncthreads();
    if (tid < 32) {
        float v = l1b[tid];
        for (int j = 0; j < 32; j++) v = fmaf(sG[j], l1W[j * 32 + tid], v);
        sG1[tid] = fmaxf(v, 0.f);
    }
    __syncthreads();
    if (tid < 10) {
        float v = l2b[tid];
        for (int j = 0; j < 32; j++) v = fmaf(sG1[j], l2W[j * 10 + tid], v);
        sL[tid] = v;
    }
    __syncthreads();
    if (tid == 0) {
        float mx = sL[0];
        for (int j = 1; j < 10; j++) mx = fmaxf(mx, sL[j]);
        float se = 0.f;
        for (int j = 0; j < 10; j++) se += expf(sL[j] - mx);
        sLse = mx + logf(se);
    }
    __syncthreads();
    if (tid < 10) out[(size_t)g * 10 + tid] = sL[tid] - sLse;
}

// ------------------------------------------------------ total loss
__global__ void k_loss(const float* __restrict__ aux, float* __restrict__ out) {
    __shared__ float red[128];
    int tid = threadIdx.x;
    red[tid] = aux[128 + tid] + aux[256 + tid];
    __syncthreads();
#pragma unroll
    for (int s = 64; s > 0; s >>= 1) { if (tid < s) red[tid] += red[tid + s]; __syncthreads(); }
    if (tid == 0) out[1280] = red[0] * (1.f / 128.f);
}

extern "C" void kernel_launch(void* const* d_in, const int* in_sizes, int n_in,
                              void* d_out, int out_size, void* d_ws, size_t ws_size,
                              hipStream_t stream) {
    const float* x    = (const float*)d_in[0];
    const int*   ei   = (const int*)d_in[1];
    const float* c1W  = (const float*)d_in[3];
    const float* c1b  = (const float*)d_in[4];
    const float* p1W  = (const float*)d_in[5];
    const float* p1b  = (const float*)d_in[6];
    const float* relW2  = (const float*)d_in[7];
    const float* relb2  = (const float*)d_in[8];
    const float* rootW2 = (const float*)d_in[9];
    const float* p2W  = (const float*)d_in[10];
    const float* p2b  = (const float*)d_in[11];
    const float* relW3  = (const float*)d_in[12];
    const float* relb3  = (const float*)d_in[13];
    const float* rootW3 = (const float*)d_in[14];
    const float* l1W  = (const float*)d_in[15];
    const float* l1b  = (const float*)d_in[16];
    const float* l2W  = (const float*)d_in[17];
    const float* l2b  = (const float*)d_in[18];
    float* out = (float*)d_out;

    // ---- workspace layout
    int*  cnt_src = (int*)d_ws;                       // NT
    int*  cnt_dst = cnt_src + NT;                     // NT
    int*  off_src = cnt_dst + NT;                     // NT
    int*  off_dst = off_src + NT;                     // NT
    int*  cur_src = off_dst + NT;                     // NT
    int*  cur_dst = cur_src + NT;                     // NT
    int*  srt_dst = cur_dst + NT;                     // ET (src-sorted, stores dst)
    int*  srt_src = srt_dst + ET;                     // ET (dst-sorted, stores src)
    float* dis = (float*)(srt_src + ET);              // NT
    u32*  xwb  = (u32*)(dis + NT);                    // NT*16 (bf16 x2)
    u32*  hb   = xwb + (size_t)NT * 16;               // NT*16
    u32*  s1b  = hb + (size_t)NT * 16;                // NT*50
    u32*  t1b  = s1b + (size_t)NT * 50;               // NT*50
    float* h    = (float*)(t1b + (size_t)NT * 50);    // NT*HH fp32
    float* Cp   = h + (size_t)NT * HH;                // 4*TB*KP1*232
    float* A1n  = Cp + (size_t)4 * TB * (KP1 * 232);  // TB*KP1*KP1
    float* P1   = A1n + (size_t)TB * KP1 * KP1;       // TB*KP1*HH
    float* P2   = P1 + (size_t)TB * KP1 * HH;         // TB*KP2*HH
    float* A2n  = P2 + (size_t)TB * KP2 * HH;         // TB*100
    float* aux  = A2n + (size_t)TB * 100;             // 1024: den1|loss1|loss2

    k_init<<<NT / 256, 256, 0, stream>>>(cnt_src, cnt_dst, aux);
    k_cnt<<<ET / 256, 256, 0, stream>>>(ei, cnt_src, cnt_dst);
    k_scan<<<TB, 512, 0, stream>>>(cnt_src, cnt_dst, off_src, off_dst, cur_src, cur_dst);
    k_scatter<<<ET / 256, 256, 0, stream>>>(ei, cur_src, cur_dst, srt_dst, srt_src);
    k_dis<<<NT / 256, 256, 0, stream>>>(cnt_dst, dis);
    k_xw<<<(NT * HH) / 256, 256, 0, stream>>>(x, c1W, (u16*)xwb);
    k_gcng<<<NT / 16, 256, 0, stream>>>(srt_src, off_dst, cnt_dst, xwb, dis, c1b, h, hb);
    k_s1<<<NT / 128, 128, 0, stream>>>(h, p1W, p1b, cnt_src, s1b, aux /*den1*/);
    k_t1g<<<NT / 4, 256, 0, stream>>>(srt_dst, off_src, cnt_src, s1b, t1b);
    k_gram<<<TB * 4, 512, 0, stream>>>(s1b, t1b, hb, Cp);
    k_fin1<<<TB, 256, 0, stream>>>(Cp, aux /*den1*/, A1n, P1, aux);
    k_s2a<<<TB, 512, 0, stream>>>(A1n, P1, relW2, relb2, rootW2, p2W, p2b, P2, A2n, aux);
    k_s2b<<<TB, 64, 0, stream>>>(P2, A2n, relW3, relb3, rootW3, l1W, l1b, l2W, l2b, out);
    k_loss<<<1, 128, 0, stream>>>(aux, out);
}

// Round 9
// 371.020 us; speedup vs baseline: 4.4270x; 1.2179x over previous
//
#include <hip/hip_runtime.h>
#include <hip/hip_bf16.h>

// Problem constants (match reference)
#define TB   128          // batch B
#define NN   512          // nodes per graph
#define INC  128          // IN_C
#define HH   32           // HID
#define KP1  100          // K1
#define KP2  10           // K2
#define OC   10           // OUT_C
#define EPER 8192         // edges per graph
#define NT   (TB*NN)      // 65536 total nodes
#define ET   (TB*EPER)    // 1048576 total edges
#define ZTR  264          // gram ZT rows: 232 Z-cols + 32 zero pad (partial MFMA tiles)
#define ZTS  40           // ZT row stride in u16 (80 B, 16B-aligned for ds_read_b128)

typedef unsigned int  u32;
typedef unsigned short u16;
typedef __attribute__((ext_vector_type(8))) short bf16x8;   // 8 bf16 = 4 VGPR (MFMA A/B frag)
typedef __attribute__((ext_vector_type(16))) float f32x16;  // MFMA C/D frag

// bf16 helpers (RNE encode; exact decode)
__device__ __forceinline__ u32 bfr(float f) {
    u32 b = __float_as_uint(f);
    return (b + 0x7fffu + ((b >> 16) & 1u)) >> 16;
}
__device__ __forceinline__ u32 pk2(float a, float b) { return bfr(a) | (bfr(b) << 16); }
__device__ __forceinline__ float blo(u32 u) { return __uint_as_float(u << 16); }
__device__ __forceinline__ float bhi(u32 u) { return __uint_as_float(u & 0xffff0000u); }

// ---------------------------------------------------------------- init (aux only)
__global__ void k_init(float* __restrict__ aux) {
    int i = blockIdx.x * 256 + threadIdx.x;
    if (i < 1024) aux[i] = 0.0f;              // den1 / loss1 / loss2 accumulators
}

// ---- fused per-graph counting sort: histogram + scan + scatter + dis, all in LDS
__global__ __launch_bounds__(512) void k_sort(const int* __restrict__ ei,
                                              int* __restrict__ cnt_src, int* __restrict__ cnt_dst,
                                              int* __restrict__ off_src, int* __restrict__ off_dst,
                                              u16* __restrict__ srt_dst, u16* __restrict__ srt_src,
                                              float* __restrict__ dis) {
    __shared__ int hs[NN], hd[NN], ps[NN], pd[NN];              // 8 KB
    __shared__ __align__(16) u16 sdl[EPER], ssl[EPER];          // 32 KB
    int g = blockIdx.x, tid = threadIdx.x, goff = g * NN;
    hs[tid] = 0; hd[tid] = 0;
    __syncthreads();
    const int* es = ei + (size_t)g * EPER;
    const int* ed = ei + ET + (size_t)g * EPER;
    // pass 1: histograms
    for (int e = tid; e < EPER; e += 512) {
        atomicAdd(&hs[es[e] - goff], 1);
        atomicAdd(&hd[ed[e] - goff], 1);
    }
    __syncthreads();
    int vs = hs[tid], vd = hd[tid];
    ps[tid] = vs; pd[tid] = vd; __syncthreads();
    // Hillis-Steele inclusive scan of both histograms
    for (int off = 1; off < NN; off <<= 1) {
        int xa = ps[tid], xb = pd[tid];
        if (tid >= off) { xa += ps[tid - off]; xb += pd[tid - off]; }
        __syncthreads(); ps[tid] = xa; pd[tid] = xb; __syncthreads();
    }
    int eso = ps[tid] - vs, edo = pd[tid] - vd;   // exclusive offsets, graph-local
    cnt_src[goff + tid] = vs;  cnt_dst[goff + tid] = vd;
    off_src[goff + tid] = g * EPER + eso;
    off_dst[goff + tid] = g * EPER + edo;
    dis[goff + tid] = rsqrtf(1.0f + (float)vd);   // +1 self loop
    __syncthreads();
    ps[tid] = eso; pd[tid] = edo;                 // reuse as cursors
    __syncthreads();
    // pass 2: scatter into LDS (u16 local node ids)
    for (int e = tid; e < EPER; e += 512) {
        int s = es[e] - goff, d = ed[e] - goff;
        int p = atomicAdd(&ps[s], 1); sdl[p] = (u16)d;   // src-sorted: store dst
        int q = atomicAdd(&pd[d], 1); ssl[q] = (u16)s;   // dst-sorted: store src
    }
    __syncthreads();
    // coalesced write-out (u32 pairs)
    u32* wd = (u32*)(srt_dst + (size_t)g * EPER);
    u32* ws = (u32*)(srt_src + (size_t)g * EPER);
    const u32* rd = (const u32*)sdl;
    const u32* rs = (const u32*)ssl;
    for (int i = tid; i < EPER / 2; i += 512) { wd[i] = rd[i]; ws[i] = rs[i]; }
}

// ------------------------------ xw = bf16(x @ conv1_W)  [NT,32] bf16
__global__ __launch_bounds__(256) void k_xw(const float* __restrict__ x, const float* __restrict__ W,
                                            u16* __restrict__ xwb) {
    __shared__ float sWT[32][132];           // W^T, padded stride
    int tid = threadIdx.x;
    for (int i = tid; i < INC * HH; i += 256) { int k = i >> 5, c = i & 31; sWT[c][k] = W[i]; }
    __syncthreads();
    int id = blockIdx.x * 256 + tid;
    int row = id >> 5, c = id & 31;
    const float4* xp = (const float4*)(x + (size_t)row * INC);
    float acc = 0.f;
#pragma unroll
    for (int kq = 0; kq < INC / 4; kq++) {
        float4 xv = xp[kq];
        float4 wv = *(const float4*)&sWT[c][kq * 4];
        acc += xv.x * wv.x + xv.y * wv.y + xv.z * wv.z + xv.w * wv.w;
    }
    xwb[id] = (u16)bfr(acc);
}

// -------- GCN gather (bf16 xw, u16 indices): h fp32 + hb bf16
__global__ __launch_bounds__(256) void k_gcng(const u16* __restrict__ ssrc, const int* __restrict__ od,
                                              const int* __restrict__ cd, const u32* __restrict__ xwb32,
                                              const float* __restrict__ dis, const float* __restrict__ bias,
                                              float* __restrict__ h, u32* __restrict__ hb32) {
    int tid = threadIdx.x;
    int n = blockIdx.x * 16 + (tid >> 4), cp = tid & 15;  // cp -> channels 2cp,2cp+1
    int goff = n & ~(NN - 1);
    int base = od[n], cnt = cd[n];
    float dn = dis[n];
    u32 us = xwb32[(size_t)n * 16 + cp];
    float a0 = dn * blo(us), a1 = dn * bhi(us);           // self-loop term
    int i = 0;
    for (; i + 4 <= cnt; i += 4) {
        int s0 = goff + ssrc[base + i],     s1v = goff + ssrc[base + i + 1];
        int s2 = goff + ssrc[base + i + 2], s3  = goff + ssrc[base + i + 3];
        float d0 = dis[s0], d1 = dis[s1v], d2 = dis[s2], d3 = dis[s3];
        u32 u0 = xwb32[(size_t)s0 * 16 + cp];
        u32 u1 = xwb32[(size_t)s1v * 16 + cp];
        u32 u2 = xwb32[(size_t)s2 * 16 + cp];
        u32 u3 = xwb32[(size_t)s3 * 16 + cp];
        a0 += d0 * blo(u0) + d1 * blo(u1) + d2 * blo(u2) + d3 * blo(u3);
        a1 += d0 * bhi(u0) + d1 * bhi(u1) + d2 * bhi(u2) + d3 * bhi(u3);
    }
    for (; i < cnt; i++) {
        int s0 = goff + ssrc[base + i]; float d0 = dis[s0];
        u32 u0 = xwb32[(size_t)s0 * 16 + cp];
        a0 += d0 * blo(u0); a1 += d0 * bhi(u0);
    }
    float v0 = fmaxf(dn * a0 + bias[2 * cp], 0.f);
    float v1 = fmaxf(dn * a1 + bias[2 * cp + 1], 0.f);
    *(float2*)&h[(size_t)n * HH + 2 * cp] = make_float2(v0, v1);
    hb32[(size_t)n * 16 + cp] = pk2(v0, v1);
}

// ------- s1 = softmax(h @ pool1_W + b): 4 threads/row (25 ch each), bf16 out
// No explicit max-subtraction (logits O(1) in fp32; ratios identical).
__global__ __launch_bounds__(256) void k_s1(const float* __restrict__ h, const float* __restrict__ W,
                                            const float* __restrict__ bias, const int* __restrict__ csrc,
                                            u16* __restrict__ s1b, float* __restrict__ den1) {
    int tid = threadIdx.x;
    int gidx = blockIdx.x * 256 + tid;
    int row = gidx >> 2, part = gidx & 3;
    int c0 = part * 25;
    float hr[HH];
    const float4* hp = (const float4*)(h + (size_t)row * HH);
#pragma unroll
    for (int q = 0; q < HH / 4; q++) {
        float4 a = hp[q];
        hr[4*q] = a.x; hr[4*q+1] = a.y; hr[4*q+2] = a.z; hr[4*q+3] = a.w;
    }
    float a[25];
#pragma unroll
    for (int j = 0; j < 25; j++) a[j] = bias[c0 + j];
#pragma unroll
    for (int k = 0; k < HH; k++) {
        const float* wr = W + k * KP1 + c0;
        float hk = hr[k];
#pragma unroll
        for (int j = 0; j < 25; j++) a[j] = fmaf(hk, wr[j], a[j]);
    }
    float sum = 0.f, qq = 0.f;
#pragma unroll
    for (int j = 0; j < 25; j++) {
        float ev = __expf(a[j]);
        a[j] = ev; sum += ev; qq = fmaf(ev, ev, qq);
    }
    // combine across the 4 lanes of this row
    sum += __shfl_xor(sum, 1); qq += __shfl_xor(qq, 1);
    sum += __shfl_xor(sum, 2); qq += __shfl_xor(qq, 2);
    float inv = 1.f / sum;
    u16* sp = s1b + (size_t)row * KP1 + c0;
#pragma unroll
    for (int j = 0; j < 25; j++) sp[j] = (u16)bfr(a[j] * inv);
    // den1: one value per row (part 0), wave rows share a graph (512%16==0)
    float contrib = (part == 0) ? ((float)csrc[row] * qq * inv * inv) : 0.f;
#pragma unroll
    for (int off = 32; off >= 1; off >>= 1) contrib += __shfl_xor(contrib, off);
    if ((tid & 63) == 0) atomicAdd(&den1[row >> 9], contrib);
}

// ------------- t1 gather (bf16, u16 indices): wave per node, lane owns 2 channels
__global__ __launch_bounds__(256) void k_t1g(const u16* __restrict__ sdst, const int* __restrict__ osr,
                                             const int* __restrict__ csr, const u32* __restrict__ s1b32,
                                             u32* __restrict__ t1b32) {
    int tid = threadIdx.x;
    int n = blockIdx.x * 4 + (tid >> 6), lane = tid & 63;
    if (lane >= 50) return;
    int goff = n & ~(NN - 1);
    int base = osr[n], cnt = csr[n];
    float a0 = 0.f, a1 = 0.f;
    int i = 0;
    for (; i + 4 <= cnt; i += 4) {
        int d0 = goff + sdst[base + i],     d1 = goff + sdst[base + i + 1];
        int d2 = goff + sdst[base + i + 2], d3 = goff + sdst[base + i + 3];
        u32 u0 = s1b32[(size_t)d0 * 50 + lane];
        u32 u1 = s1b32[(size_t)d1 * 50 + lane];
        u32 u2 = s1b32[(size_t)d2 * 50 + lane];
        u32 u3 = s1b32[(size_t)d3 * 50 + lane];
        a0 += (blo(u0) + blo(u1)) + (blo(u2) + blo(u3));
        a1 += (bhi(u0) + bhi(u1)) + (bhi(u2) + bhi(u3));
    }
    for (; i < cnt; i++) {
        int d0 = goff + sdst[base + i];
        u32 u0 = s1b32[(size_t)d0 * 50 + lane];
        a0 += blo(u0); a1 += bhi(u0);
    }
    t1b32[(size_t)n * 50 + lane] = pk2(a0, a1);
}

// --- gram via MFMA: C = s1^T [t1 | h | s1] (100 x 232); bf16, 4 slabs.
__global__ __launch_bounds__(512, 4) void k_gram(const u32* __restrict__ s1b32, const u32* __restrict__ t1b32,
                                                 const u32* __restrict__ hb32, float* __restrict__ Cp) {
    __shared__ u16 sZ[2][ZTR * ZTS];         // 2 x 21.1 KB
    int g = blockIdx.x >> 2, slab = blockIdx.x & 3;
    int nbase = g * NN + slab * 128;         // 4 chunks of 32 rows
    int tid = threadIdx.x;
    int wave = tid >> 6, lane = tid & 63;
    int mt = wave & 3;                       // output-row tile: k = mt*32 + row
    int nt0 = (wave >> 2) * 4;               // this wave: nt0..nt0+3
    int lc = lane & 31, half = lane >> 5;

    f32x16 acc[4];
#pragma unroll
    for (int t = 0; t < 4; t++)
#pragma unroll
        for (int r = 0; r < 16; r++) acc[t][r] = 0.f;

    // zero the padding rows of both buffers (channels 232..263)
    for (int i = tid; i < 32 * ZTS; i += 512) {
        int r = 232 + i / ZTS, c = i % ZTS;
        sZ[0][r * ZTS + c] = 0; sZ[1][r * ZTS + c] = 0;
    }
    // ---- stage chunk 0 into buffer 0 (transposing: uint2 = 4 channels of row n)
#pragma unroll
    for (int j = 0; j < 4; j++) {
        int i = tid + j * 512;
        if (i < 32 * 58) {
            int r = i / 58, q = i - r * 58;
            int n = nbase + r;
            uint2 v; int ch0;
            if (q < 25)      { v = ((const uint2*)(t1b32 + (size_t)n * 50))[q];      ch0 = 4 * q; }
            else if (q < 33) { v = ((const uint2*)(hb32  + (size_t)n * 16))[q - 25]; ch0 = 100 + 4 * (q - 25); }
            else             { v = ((const uint2*)(s1b32 + (size_t)n * 50))[q - 33]; ch0 = 132 + 4 * (q - 33); }
            sZ[0][(ch0    ) * ZTS + r] = (u16)(v.x & 0xffffu);
            sZ[0][(ch0 + 1) * ZTS + r] = (u16)(v.x >> 16);
            sZ[0][(ch0 + 2) * ZTS + r] = (u16)(v.y & 0xffffu);
            sZ[0][(ch0 + 3) * ZTS + r] = (u16)(v.y >> 16);
        }
    }
    __syncthreads();

    for (int nt = 0; nt < 4; nt++) {
        // ---- prefetch chunk nt+1 into registers
        uint2 pre[4];
        if (nt < 3) {
#pragma unroll
            for (int j = 0; j < 4; j++) {
                int i = tid + j * 512;
                if (i < 32 * 58) {
                    int r = i / 58, q = i - r * 58;
                    int n = nbase + (nt + 1) * 32 + r;
                    uint2 v;
                    if (q < 25)      v = ((const uint2*)(t1b32 + (size_t)n * 50))[q];
                    else if (q < 33) v = ((const uint2*)(hb32  + (size_t)n * 16))[q - 25];
                    else             v = ((const uint2*)(s1b32 + (size_t)n * 50))[q - 33];
                    pre[j] = v;
                }
            }
        }
        // ---- MFMA on current buffer
        const u16* zb = sZ[nt & 1];
#pragma unroll
        for (int mf = 0; mf < 2; mf++) {
            bf16x8 af = *(const bf16x8*)&zb[(132 + mt * 32 + lc) * ZTS + mf * 16 + half * 8];
#pragma unroll
            for (int t = 0; t < 4; t++) {
                bf16x8 bfv = *(const bf16x8*)&zb[((nt0 + t) * 32 + lc) * ZTS + mf * 16 + half * 8];
                acc[t] = __builtin_amdgcn_mfma_f32_32x32x16_bf16(af, bfv, acc[t], 0, 0, 0);
            }
        }
        // ---- commit prefetch to the other buffer
        if (nt < 3) {
            u16* zo = sZ[(nt + 1) & 1];
#pragma unroll
            for (int j = 0; j < 4; j++) {
                int i = tid + j * 512;
                if (i < 32 * 58) {
                    int r = i / 58, q = i - r * 58;
                    int ch0 = (q < 25) ? (4 * q) : ((q < 33) ? (100 + 4 * (q - 25)) : (132 + 4 * (q - 33)));
                    zo[(ch0    ) * ZTS + r] = (u16)(pre[j].x & 0xffffu);
                    zo[(ch0 + 1) * ZTS + r] = (u16)(pre[j].x >> 16);
                    zo[(ch0 + 2) * ZTS + r] = (u16)(pre[j].y & 0xffffu);
                    zo[(ch0 + 3) * ZTS + r] = (u16)(pre[j].y >> 16);
                }
            }
        }
        __syncthreads();
    }
    // ---- epilogue: C/D layout col=lane&31, row=(reg&3)+8*(reg>>2)+4*(lane>>5)
    float* outp = Cp + ((size_t)slab * TB + g) * (KP1 * 232);
#pragma unroll
    for (int t = 0; t < 4; t++) {
        int l = (nt0 + t) * 32 + lc;
        if (l < 232) {
#pragma unroll
            for (int r = 0; r < 16; r++) {
                int k = mt * 32 + (r & 3) + 8 * (r >> 2) + 4 * half;
                if (k < KP1) outp[k * 232 + l] = acc[t][r];
            }
        }
    }
}

// ---- finalize stage 1: coalesced float4 slab sweep; losses; normalize; P1
__global__ __launch_bounds__(256) void k_fin1(const float* __restrict__ Cp, const float* __restrict__ den1,
                                              float* __restrict__ A1n, float* __restrict__ P1,
                                              float* __restrict__ aux) {
    __shared__ float sA[KP1 * KP1];          // 40 KB
    __shared__ float red[256];
    __shared__ float rs2[256];
    __shared__ float sdv[KP1];
    int g = blockIdx.x, tid = threadIdx.x;
    const float* b0 = Cp + (size_t)g * (KP1 * 232);
    const size_t SLAB = (size_t)TB * (KP1 * 232);
    float ssq = 0.f, trss = 0.f, troa = 0.f;
    // phase 1: sweep 100 rows x 58 float4 cols, coalesced; sum 4 slabs in flight
    for (int idx = tid; idx < KP1 * 58; idx += 256) {
        int k = idx / 58, q = idx - k * 58;
        size_t off = (size_t)k * 232 + q * 4;
        float4 v0 = *(const float4*)(b0 + off);
        float4 v1 = *(const float4*)(b0 + SLAB + off);
        float4 v2 = *(const float4*)(b0 + 2 * SLAB + off);
        float4 v3 = *(const float4*)(b0 + 3 * SLAB + off);
        float4 s;
        s.x = (v0.x + v1.x) + (v2.x + v3.x);
        s.y = (v0.y + v1.y) + (v2.y + v3.y);
        s.z = (v0.z + v1.z) + (v2.z + v3.z);
        s.w = (v0.w + v1.w) + (v2.w + v3.w);
        int c = q * 4;
        if (c < 100) {                        // out_adj block
            *(float4*)&sA[k * KP1 + c] = s;
            if (k >= c && k < c + 4) troa += ((const float*)&s)[k - c];
        } else if (c < 132) {                 // pooled features -> P1 direct
            *(float4*)&P1[((size_t)g * KP1 + k) * HH + (c - 100)] = s;
        } else {                              // ss block: reduce only
            ssq += s.x * s.x + s.y * s.y + s.z * s.z + s.w * s.w;
            int l0 = c - 132;
            if (k >= l0 && k < l0 + 4) trss += ((const float*)&s)[k - l0];
        }
    }
    // block reductions for ssq / trss / troa
    red[tid] = ssq; __syncthreads();
#pragma unroll
    for (int s = 128; s > 0; s >>= 1) { if (tid < s) red[tid] += red[tid + s]; __syncthreads(); }
    float ssqT = red[0]; __syncthreads();
    red[tid] = trss; __syncthreads();
#pragma unroll
    for (int s = 128; s > 0; s >>= 1) { if (tid < s) red[tid] += red[tid + s]; __syncthreads(); }
    float trssT = red[0]; __syncthreads();
    red[tid] = troa; __syncthreads();
#pragma unroll
    for (int s = 128; s > 0; s >>= 1) { if (tid < s) red[tid] += red[tid + s]; __syncthreads(); }
    float troaT = red[0]; __syncthreads();
    // phase 2: row sums (2 threads per row) -> sd
    if (tid < 200) {
        int k = tid >> 1, hf = tid & 1;
        const float* row = &sA[k * KP1 + hf * 50];
        float rs = 0.f;
        for (int l = 0; l < 50; l++) rs += row[l];
        rs2[tid] = rs;
    }
    __syncthreads();
    if (tid < KP1) {
        float rowsum = rs2[2 * tid] + rs2[2 * tid + 1] - sA[tid * KP1 + tid];
        sdv[tid] = sqrtf(rowsum) + 1e-15f;
    }
    if (tid == 0) {
        float ssF = sqrtf(ssqT);
        float o1 = sqrtf(fmaxf(2.f - 2.f * trssT / (ssF * 10.f), 0.f));  // sqrt(K1)=10
        aux[128 + g] = -(troaT / den1[g]) + o1;
    }
    __syncthreads();
    // phase 3: normalize out_adj, coalesced
    for (int i = tid; i < KP1 * KP1; i += 256) {
        int k = i / KP1, l = i - k * KP1;
        A1n[(size_t)g * (KP1 * KP1) + i] = (k == l) ? 0.f : sA[i] / (sdv[k] * sdv[l]);
    }
}

// ------- stage 2a: conv2 + pool2 (per graph); A read from global (L2)
__global__ __launch_bounds__(512) void k_s2a(const float* __restrict__ A1n, const float* __restrict__ P1,
                                             const float* __restrict__ relW, const float* __restrict__ relB,
                                             const float* __restrict__ rootW,
                                             const float* __restrict__ p2W, const float* __restrict__ p2B,
                                             float* __restrict__ P2, float* __restrict__ A2n,
                                             float* __restrict__ aux) {
    __shared__ float sX[KP1 * HH];           // x1p then x2
    __shared__ float sY[KP1 * HH];           // y = A @ x1p
    __shared__ float sS2[KP1 * KP2];
    __shared__ float sT2[KP1 * KP2];
    __shared__ float sA2[100], sB2[100], sdd[10], red[100];
    int g = blockIdx.x, tid = threadIdx.x;
    const float* Ag = A1n + (size_t)g * (KP1 * KP1);
    for (int i = tid; i < KP1 * HH; i += 512) sX[i] = P1[(size_t)g * (KP1 * HH) + i];
    __syncthreads();

    int n = tid >> 2, cq = tid & 3;          // 400 active threads for y / x2
    // y = A @ x1p
    if (tid < 400) {
        float yv[8];
#pragma unroll
        for (int j = 0; j < 8; j++) yv[j] = 0.f;
        for (int mq = 0; mq < 25; mq++) {
            float4 a4 = *(const float4*)&Ag[n * KP1 + mq * 4];
            const float* xb = &sX[(mq * 4) * HH + cq * 8];
            float aa[4] = {a4.x, a4.y, a4.z, a4.w};
#pragma unroll
            for (int mm = 0; mm < 4; mm++) {
                const float* xr = xb + mm * HH;
#pragma unroll
                for (int j = 0; j < 8; j++) yv[j] = fmaf(aa[mm], xr[j], yv[j]);
            }
        }
#pragma unroll
        for (int j = 0; j < 8; j++) sY[n * HH + cq * 8 + j] = yv[j];
    }
    __syncthreads();
    // x2 = relu(y @ relW + relB + x1p @ rootW)
    float x2v[8];
    if (tid < 400) {
#pragma unroll
        for (int j = 0; j < 8; j++) x2v[j] = relB[cq * 8 + j];
        for (int j = 0; j < 32; j++) {
            float yj = sY[n * HH + j];
            float xj = sX[n * HH + j];
            float4 r0 = *(const float4*)&relW[j * 32 + cq * 8];
            float4 r1v = *(const float4*)&relW[j * 32 + cq * 8 + 4];
            float4 q0 = *(const float4*)&rootW[j * 32 + cq * 8];
            float4 q1 = *(const float4*)&rootW[j * 32 + cq * 8 + 4];
            x2v[0] += yj * r0.x + xj * q0.x;  x2v[1] += yj * r0.y + xj * q0.y;
            x2v[2] += yj * r0.z + xj * q0.z;  x2v[3] += yj * r0.w + xj * q0.w;
            x2v[4] += yj * r1v.x + xj * q1.x; x2v[5] += yj * r1v.y + xj * q1.y;
            x2v[6] += yj * r1v.z + xj * q1.z; x2v[7] += yj * r1v.w + xj * q1.w;
        }
    }
    __syncthreads();
    if (tid < 400) {
#pragma unroll
        for (int j = 0; j < 8; j++) sX[n * HH + cq * 8 + j] = fmaxf(x2v[j], 0.f);
    }
    __syncthreads();
    // s2 = softmax(x2 @ p2W + p2B); d2 and den2 partials
    if (tid < KP1) {
        float lg[10];
#pragma unroll
        for (int j = 0; j < 10; j++) lg[j] = p2B[j];
        for (int c = 0; c < 32; c++) {
            float xv = sX[tid * HH + c];
#pragma unroll
            for (int j = 0; j < 10; j++) lg[j] = fmaf(xv, p2W[c * 10 + j], lg[j]);
        }
        float mx = lg[0];
#pragma unroll
        for (int j = 1; j < 10; j++) mx = fmaxf(mx, lg[j]);
        float se = 0.f;
#pragma unroll
        for (int j = 0; j < 10; j++) { lg[j] = __expf(lg[j] - mx); se += lg[j]; }
        float inv = 1.f / se, sq = 0.f;
#pragma unroll
        for (int j = 0; j < 10; j++) { float sv = lg[j] * inv; sS2[tid * 10 + j] = sv; sq += sv * sv; }
        float d2 = 0.f;
        for (int mq = 0; mq < 25; mq++) {
            float4 a4 = *(const float4*)&Ag[tid * KP1 + mq * 4];
            d2 += a4.x + a4.y + a4.z + a4.w;
        }
        red[tid] = d2 * sq;
    }
    __syncthreads();
    // t2 = A @ s2 ; P2 = s2^T x2
    for (int p = tid; p < KP1 * KP2; p += 512) {
        int n2 = p / 10, jj = p % 10;
        float a = 0.f;
        for (int m = 0; m < KP1; m++) a = fmaf(Ag[n2 * KP1 + m], sS2[m * 10 + jj], a);
        sT2[p] = a;
    }
    if (tid < KP2 * HH) {
        int k = tid >> 5, cc = tid & 31;
        float a = 0.f;
        for (int n2 = 0; n2 < KP1; n2++) a = fmaf(sS2[n2 * 10 + k], sX[n2 * HH + cc], a);
        P2[(size_t)g * (KP2 * HH) + tid] = a;
    }
    __syncthreads();
    // oa2, ss2
    if (tid < 100) {
        int k = tid / 10, l = tid % 10;
        float oa = 0.f, ss = 0.f;
        for (int n2 = 0; n2 < KP1; n2++) {
            float sk = sS2[n2 * 10 + k];
            oa = fmaf(sk, sT2[n2 * 10 + l], oa);
            ss = fmaf(sk, sS2[n2 * 10 + l], ss);
        }
        sA2[tid] = oa; sB2[tid] = ss;
    }
    __syncthreads();
    if (tid == 0) {
        float den2 = 0.f;
        for (int i = 0; i < 100; i++) den2 += red[i];
        float troa = 0.f, trss = 0.f, ssq = 0.f;
        for (int k = 0; k < 10; k++) { troa += sA2[k * 10 + k]; trss += sB2[k * 10 + k]; }
        for (int i = 0; i < 100; i++) ssq += sB2[i] * sB2[i];
        float o2 = sqrtf(fmaxf(2.f - 2.f * trss / (sqrtf(ssq) * 3.16227766f), 0.f)); // sqrt(10)
        aux[256 + g] = -(troa / den2) + o2;
    }
    if (tid < 10) {
        float rs = 0.f;
        for (int l = 0; l < 10; l++) if (l != tid) rs += sA2[tid * 10 + l];
        sdd[tid] = sqrtf(rs) + 1e-15f;
    }
    __syncthreads();
    if (tid < 100) {
        int k = tid / 10, l = tid % 10;
        A2n[(size_t)g * 100 + tid] = (k == l) ? 0.f : sA2[tid] / (sdd[k] * sdd[l]);
    }
}

// ---------------- stage 2b: conv3 + mean + MLP head + log_softmax
__global__ __launch_bounds__(64) void k_s2b(const float* __restrict__ P2, const float* __restrict__ A2n,
                                            const float* __restrict__ relW3, const float* __restrict__ relb3,
                                            const float* __restrict__ rootW3,
                                            const float* __restrict__ l1W, const float* __restrict__ l1b,
                                            const float* __restrict__ l2W, const float* __restrict__ l2b,
                                            float* __restrict__ out) {
    __shared__ float sP[KP2 * HH], sA2[100], sY3[KP2 * HH], sG[32], sG1[32], sL[10], sLse;
    int g = blockIdx.x, tid = threadIdx.x;
    for (int i = tid; i < KP2 * HH; i += 64) sP[i] = P2[(size_t)g * (KP2 * HH) + i];
    for (int i = tid; i < 100; i += 64) sA2[i] = A2n[(size_t)g * 100 + i];
    if (tid < 32) sG[tid] = 0.f;
    __syncthreads();
    for (int p = tid; p < KP2 * HH; p += 64) {
        int k = p >> 5, cc = p & 31;
        float a = 0.f;
#pragma unroll
        for (int m = 0; m < 10; m++) a = fmaf(sA2[k * 10 + m], sP[m * HH + cc], a);
        sY3[p] = a;
    }
    __syncthreads();
    for (int p = tid; p < KP2 * HH; p += 64) {
        int k = p >> 5, cc = p & 31;
        float v = relb3[cc];
        for (int j = 0; j < 32; j++)
            v += sY3[k * HH + j] * relW3[j * 32 + cc] + sP[k * HH + j] * rootW3[j * 32 + cc];
        atomicAdd(&sG[cc], v * 0.1f);        // mean over 10 nodes
    }
    __syncthreads();
    if (tid < 32) {
        float v = l1b[tid];
        for (int j = 0; j < 32; j++) v = fmaf(sG[j], l1W[j * 32 + tid], v);
        sG1[tid] = fmaxf(v, 0.f);
    }
    __syncthreads();
    if (tid < 10) {
        float v = l2b[tid];
        for (int j = 0; j < 32; j++) v = fmaf(sG1[j], l2W[j * 10 + tid], v);
        sL[tid] = v;
    }
    __syncthreads();
    if (tid == 0) {
        float mx = sL[0];
        for (int j = 1; j < 10; j++) mx = fmaxf(mx, sL[j]);
        float se = 0.f;
        for (int j = 0; j < 10; j++) se += expf(sL[j] - mx);
        sLse = mx + logf(se);
    }
    __syncthreads();
    if (tid < 10) out[(size_t)g * 10 + tid] = sL[tid] - sLse;
}

// ------------------------------------------------------ total loss
__global__ void k_loss(const float* __restrict__ aux, float* __restrict__ out) {
    __shared__ float red[128];
    int tid = threadIdx.x;
    red[tid] = aux[128 + tid] + aux[256 + tid];
    __syncthreads();
#pragma unroll
    for (int s = 64; s > 0; s >>= 1) { if (tid < s) red[tid] += red[tid + s]; __syncthreads(); }
    if (tid == 0) out[1280] = red[0] * (1.f / 128.f);
}

extern "C" void kernel_launch(void* const* d_in, const int* in_sizes, int n_in,
                              void* d_out, int out_size, void* d_ws, size_t ws_size,
                              hipStream_t stream) {
    const float* x    = (const float*)d_in[0];
    const int*   ei   = (const int*)d_in[1];
    const float* c1W  = (const float*)d_in[3];
    const float* c1b  = (const float*)d_in[4];
    const float* p1W  = (const float*)d_in[5];
    const float* p1b  = (const float*)d_in[6];
    const float* relW2  = (const float*)d_in[7];
    const float* relb2  = (const float*)d_in[8];
    const float* rootW2 = (const float*)d_in[9];
    const float* p2W  = (const float*)d_in[10];
    const float* p2b  = (const float*)d_in[11];
    const float* relW3  = (const float*)d_in[12];
    const float* relb3  = (const float*)d_in[13];
    const float* rootW3 = (const float*)d_in[14];
    const float* l1W  = (const float*)d_in[15];
    const float* l1b  = (const float*)d_in[16];
    const float* l2W  = (const float*)d_in[17];
    const float* l2b  = (const float*)d_in[18];
    float* out = (float*)d_out;

    // ---- workspace layout
    int*  cnt_src = (int*)d_ws;                       // NT
    int*  cnt_dst = cnt_src + NT;                     // NT
    int*  off_src = cnt_dst + NT;                     // NT
    int*  off_dst = off_src + NT;                     // NT
    u16*  srt_dst = (u16*)(off_dst + NT);             // ET u16 (src-sorted, stores local dst)
    u16*  srt_src = srt_dst + ET;                     // ET u16 (dst-sorted, stores local src)
    float* dis = (float*)(srt_src + ET);              // NT
    u32*  xwb  = (u32*)(dis + NT);                    // NT*16 (bf16 x2)
    u32*  hb   = xwb + (size_t)NT * 16;               // NT*16
    u32*  s1b  = hb + (size_t)NT * 16;                // NT*50
    u32*  t1b  = s1b + (size_t)NT * 50;               // NT*50
    float* h    = (float*)(t1b + (size_t)NT * 50);    // NT*HH fp32
    float* Cp   = h + (size_t)NT * HH;                // 4*TB*KP1*232
    float* A1n  = Cp + (size_t)4 * TB * (KP1 * 232);  // TB*KP1*KP1
    float* P1   = A1n + (size_t)TB * KP1 * KP1;       // TB*KP1*HH
    float* P2   = P1 + (size_t)TB * KP1 * HH;         // TB*KP2*HH
    float* A2n  = P2 + (size_t)TB * KP2 * HH;         // TB*100
    float* aux  = A2n + (size_t)TB * 100;             // 1024: den1|loss1|loss2

    k_init<<<4, 256, 0, stream>>>(aux);
    k_sort<<<TB, 512, 0, stream>>>(ei, cnt_src, cnt_dst, off_src, off_dst, srt_dst, srt_src, dis);
    k_xw<<<(NT * HH) / 256, 256, 0, stream>>>(x, c1W, (u16*)xwb);
    k_gcng<<<NT / 16, 256, 0, stream>>>(srt_src, off_dst, cnt_dst, xwb, dis, c1b, h, hb);
    k_s1<<<NT * 4 / 256, 256, 0, stream>>>(h, p1W, p1b, cnt_src, (u16*)s1b, aux /*den1*/);
    k_t1g<<<NT / 4, 256, 0, stream>>>(srt_dst, off_src, cnt_src, s1b, t1b);
    k_gram<<<TB * 4, 512, 0, stream>>>(s1b, t1b, hb, Cp);
    k_fin1<<<TB, 256, 0, stream>>>(Cp, aux /*den1*/, A1n, P1, aux);
    k_s2a<<<TB, 512, 0, stream>>>(A1n, P1, relW2, relb2, rootW2, p2W, p2b, P2, A2n, aux);
    k_s2b<<<TB, 64, 0, stream>>>(P2, A2n, relW3, relb3, rootW3, l1W, l1b, l2W, l2b, out);
    k_loss<<<1, 128, 0, stream>>>(aux, out);
}

// Round 10
// 341.844 us; speedup vs baseline: 4.8048x; 1.0853x over previous
//
#include <hip/hip_runtime.h>
#include <hip/hip_bf16.h>

// Problem constants (match reference)
#define TB   128          // batch B
#define NN   512          // nodes per graph
#define INC  128          // IN_C
#define HH   32           // HID
#define KP1  100          // K1
#define KP2  10           // K2
#define OC   10           // OUT_C
#define EPER 8192         // edges per graph
#define NT   (TB*NN)      // 65536 total nodes
#define ET   (TB*EPER)    // 1048576 total edges
#define ZTR  264          // gram ZT rows: 232 Z-cols + 32 zero pad (partial MFMA tiles)
#define ZTS  40           // ZT row stride in u16 (80 B, 16B-aligned for ds_read_b128)

typedef unsigned int  u32;
typedef unsigned short u16;
typedef __attribute__((ext_vector_type(8))) short bf16x8;   // 8 bf16 = 4 VGPR (MFMA A/B frag)
typedef __attribute__((ext_vector_type(16))) float f32x16;  // MFMA C/D frag

// bf16 helpers (RNE encode; exact decode)
__device__ __forceinline__ u32 bfr(float f) {
    u32 b = __float_as_uint(f);
    return (b + 0x7fffu + ((b >> 16) & 1u)) >> 16;
}
__device__ __forceinline__ u32 pk2(float a, float b) { return bfr(a) | (bfr(b) << 16); }
__device__ __forceinline__ float blo(u32 u) { return __uint_as_float(u << 16); }
__device__ __forceinline__ float bhi(u32 u) { return __uint_as_float(u & 0xffff0000u); }

// ---------------------------------------------------------------- init (aux only)
__global__ void k_init(float* __restrict__ aux) {
    int i = blockIdx.x * 256 + threadIdx.x;
    if (i < 1024) aux[i] = 0.0f;              // den1 / loss1 / loss2 accumulators
}

// ---- fused per-graph counting sort: histogram + scan + scatter + dis, all in LDS
__global__ __launch_bounds__(512) void k_sort(const int* __restrict__ ei,
                                              int* __restrict__ cnt_src, int* __restrict__ cnt_dst,
                                              int* __restrict__ off_src, int* __restrict__ off_dst,
                                              u16* __restrict__ srt_dst, u16* __restrict__ srt_src,
                                              float* __restrict__ dis) {
    __shared__ int hs[NN], hd[NN], ps[NN], pd[NN];              // 8 KB
    __shared__ __align__(16) u16 sdl[EPER], ssl[EPER];          // 32 KB
    int g = blockIdx.x, tid = threadIdx.x, goff = g * NN;
    hs[tid] = 0; hd[tid] = 0;
    __syncthreads();
    const int* es = ei + (size_t)g * EPER;
    const int* ed = ei + ET + (size_t)g * EPER;
    // pass 1: histograms
    for (int e = tid; e < EPER; e += 512) {
        atomicAdd(&hs[es[e] - goff], 1);
        atomicAdd(&hd[ed[e] - goff], 1);
    }
    __syncthreads();
    int vs = hs[tid], vd = hd[tid];
    ps[tid] = vs; pd[tid] = vd; __syncthreads();
    // Hillis-Steele inclusive scan of both histograms
    for (int off = 1; off < NN; off <<= 1) {
        int xa = ps[tid], xb = pd[tid];
        if (tid >= off) { xa += ps[tid - off]; xb += pd[tid - off]; }
        __syncthreads(); ps[tid] = xa; pd[tid] = xb; __syncthreads();
    }
    int eso = ps[tid] - vs, edo = pd[tid] - vd;   // exclusive offsets, graph-local
    cnt_src[goff + tid] = vs;  cnt_dst[goff + tid] = vd;
    off_src[goff + tid] = g * EPER + eso;
    off_dst[goff + tid] = g * EPER + edo;
    dis[goff + tid] = rsqrtf(1.0f + (float)vd);   // +1 self loop
    __syncthreads();
    ps[tid] = eso; pd[tid] = edo;                 // reuse as cursors
    __syncthreads();
    // pass 2: scatter into LDS (u16 local node ids)
    for (int e = tid; e < EPER; e += 512) {
        int s = es[e] - goff, d = ed[e] - goff;
        int p = atomicAdd(&ps[s], 1); sdl[p] = (u16)d;   // src-sorted: store dst
        int q = atomicAdd(&pd[d], 1); ssl[q] = (u16)s;   // dst-sorted: store src
    }
    __syncthreads();
    // coalesced write-out (u32 pairs)
    u32* wd = (u32*)(srt_dst + (size_t)g * EPER);
    u32* ws = (u32*)(srt_src + (size_t)g * EPER);
    const u32* rd = (const u32*)sdl;
    const u32* rs = (const u32*)ssl;
    for (int i = tid; i < EPER / 2; i += 512) { wd[i] = rd[i]; ws[i] = rs[i]; }
}

// ------------------------------ xw = bf16(x @ conv1_W)  [NT,32] bf16
__global__ __launch_bounds__(256) void k_xw(const float* __restrict__ x, const float* __restrict__ W,
                                            u16* __restrict__ xwb) {
    __shared__ float sWT[32][132];           // W^T, padded stride
    int tid = threadIdx.x;
    for (int i = tid; i < INC * HH; i += 256) { int k = i >> 5, c = i & 31; sWT[c][k] = W[i]; }
    __syncthreads();
    int id = blockIdx.x * 256 + tid;
    int row = id >> 5, c = id & 31;
    const float4* xp = (const float4*)(x + (size_t)row * INC);
    float acc = 0.f;
#pragma unroll
    for (int kq = 0; kq < INC / 4; kq++) {
        float4 xv = xp[kq];
        float4 wv = *(const float4*)&sWT[c][kq * 4];
        acc += xv.x * wv.x + xv.y * wv.y + xv.z * wv.z + xv.w * wv.w;
    }
    xwb[id] = (u16)bfr(acc);
}

// -------- GCN gather (bf16 xw, u16 indices): hb bf16 only
__global__ __launch_bounds__(256) void k_gcng(const u16* __restrict__ ssrc, const int* __restrict__ od,
                                              const int* __restrict__ cd, const u32* __restrict__ xwb32,
                                              const float* __restrict__ dis, const float* __restrict__ bias,
                                              u32* __restrict__ hb32) {
    int tid = threadIdx.x;
    int n = blockIdx.x * 16 + (tid >> 4), cp = tid & 15;  // cp -> channels 2cp,2cp+1
    int goff = n & ~(NN - 1);
    int base = od[n], cnt = cd[n];
    float dn = dis[n];
    u32 us = xwb32[(size_t)n * 16 + cp];
    float a0 = dn * blo(us), a1 = dn * bhi(us);           // self-loop term
    int i = 0;
    for (; i + 4 <= cnt; i += 4) {
        int s0 = goff + ssrc[base + i],     s1v = goff + ssrc[base + i + 1];
        int s2 = goff + ssrc[base + i + 2], s3  = goff + ssrc[base + i + 3];
        float d0 = dis[s0], d1 = dis[s1v], d2 = dis[s2], d3 = dis[s3];
        u32 u0 = xwb32[(size_t)s0 * 16 + cp];
        u32 u1 = xwb32[(size_t)s1v * 16 + cp];
        u32 u2 = xwb32[(size_t)s2 * 16 + cp];
        u32 u3 = xwb32[(size_t)s3 * 16 + cp];
        a0 += d0 * blo(u0) + d1 * blo(u1) + d2 * blo(u2) + d3 * blo(u3);
        a1 += d0 * bhi(u0) + d1 * bhi(u1) + d2 * bhi(u2) + d3 * bhi(u3);
    }
    for (; i < cnt; i++) {
        int s0 = goff + ssrc[base + i]; float d0 = dis[s0];
        u32 u0 = xwb32[(size_t)s0 * 16 + cp];
        a0 += d0 * blo(u0); a1 += d0 * bhi(u0);
    }
    float v0 = fmaxf(dn * a0 + bias[2 * cp], 0.f);
    float v1 = fmaxf(dn * a1 + bias[2 * cp + 1], 0.f);
    hb32[(size_t)n * 16 + cp] = pk2(v0, v1);
}

// ------- s1 via MFMA: logits = hb @ pool1_W + b, softmax in-register
// Block = 128 rows, 256 thr (4 waves). LDS: sH[128][40], sW^T[128][40] (rows 100..127 zero).
__global__ __launch_bounds__(256) void k_s1m(const u32* __restrict__ hb32, const float* __restrict__ W,
                                             const float* __restrict__ bias, const int* __restrict__ csrc,
                                             u16* __restrict__ s1b, float* __restrict__ den1) {
    __shared__ u16 sH[128 * ZTS];            // 10.24 KB
    __shared__ u16 sW[128 * ZTS];            // 10.24 KB
    int tid = threadIdx.x;
    int nbase = blockIdx.x * 128;
    // stage W^T bf16: sW[n][k] = W[k*100+n]; coalesced read (n fastest)
    for (int i = tid; i < HH * KP1; i += 256) {
        int k = i / KP1, n = i - k * KP1;
        sW[n * ZTS + k] = (u16)bfr(W[i]);
    }
    // zero pad rows 100..127 (k 0..31 as 16 u32)
    for (int i = tid; i < 28 * 16; i += 256) {
        int n = 100 + (i >> 4), q = i & 15;
        ((u32*)sW)[n * (ZTS / 2) + q] = 0;
    }
    // stage hb rows (coalesced u32)
    for (int i = tid; i < 128 * 16; i += 256) {
        int r = i >> 4, q = i & 15;
        ((u32*)sH)[r * (ZTS / 2) + q] = hb32[(size_t)(nbase + r) * 16 + q];
    }
    __syncthreads();
    int wave = tid >> 6, lane = tid & 63;
    int lc = lane & 31, half = lane >> 5;
    f32x16 acc[4];
#pragma unroll
    for (int t = 0; t < 4; t++)
#pragma unroll
        for (int r = 0; r < 16; r++) acc[t][r] = 0.f;
#pragma unroll
    for (int kc = 0; kc < 2; kc++) {
        bf16x8 af = *(const bf16x8*)&sH[(wave * 32 + lc) * ZTS + kc * 16 + half * 8];
#pragma unroll
        for (int t = 0; t < 4; t++) {
            bf16x8 bfv = *(const bf16x8*)&sW[(t * 32 + lc) * ZTS + kc * 16 + half * 8];
            acc[t] = __builtin_amdgcn_mfma_f32_32x32x16_bf16(af, bfv, acc[t], 0, 0, 0);
        }
    }
    // bias + exp (overwrite acc with e); row sums via lc-butterfly
    float s[16], q[16];
#pragma unroll
    for (int r = 0; r < 16; r++) { s[r] = 0.f; q[r] = 0.f; }
#pragma unroll
    for (int t = 0; t < 4; t++) {
        int ch = t * 32 + lc;
        bool valid = ch < KP1;
        float bv = valid ? bias[ch] : 0.f;
#pragma unroll
        for (int r = 0; r < 16; r++) {
            float ev = valid ? __expf(acc[t][r] + bv) : 0.f;
            acc[t][r] = ev; s[r] += ev; q[r] = fmaf(ev, ev, q[r]);
        }
    }
#pragma unroll
    for (int off = 16; off >= 1; off >>= 1) {
#pragma unroll
        for (int r = 0; r < 16; r++) { s[r] += __shfl_xor(s[r], off); q[r] += __shfl_xor(q[r], off); }
    }
    float inv[16];
#pragma unroll
    for (int r = 0; r < 16; r++) inv[r] = 1.f / s[r];
    // store s1 bf16: row = (reg&3)+8*(reg>>2)+4*half (verified C/D layout), col = t*32+lc
#pragma unroll
    for (int t = 0; t < 4; t++) {
        int ch = t * 32 + lc;
        if (ch < KP1) {
#pragma unroll
            for (int r = 0; r < 16; r++) {
                int lr = (r & 3) + 8 * (r >> 2) + 4 * half;
                int rowg = nbase + wave * 32 + lr;
                s1b[(size_t)rowg * KP1 + ch] = (u16)bfr(acc[t][r] * inv[r]);
            }
        }
    }
    // den1: deg_out[row] * sum(s1^2) per row; lc==0 lanes hold replicated sums
    float contrib = 0.f;
    if (lc == 0) {
#pragma unroll
        for (int r = 0; r < 16; r++) {
            int lr = (r & 3) + 8 * (r >> 2) + 4 * half;
            int rowg = nbase + wave * 32 + lr;
            contrib += (float)csrc[rowg] * q[r] * inv[r] * inv[r];
        }
    }
    contrib += __shfl_xor(contrib, 32);
    if (lane == 0) atomicAdd(&den1[nbase >> 9], contrib);
}

// ------------- t1 gather (bf16, u16 indices): wave per node, lane owns 2 channels
__global__ __launch_bounds__(256) void k_t1g(const u16* __restrict__ sdst, const int* __restrict__ osr,
                                             const int* __restrict__ csr, const u32* __restrict__ s1b32,
                                             u32* __restrict__ t1b32) {
    int tid = threadIdx.x;
    int n = blockIdx.x * 4 + (tid >> 6), lane = tid & 63;
    if (lane >= 50) return;
    int goff = n & ~(NN - 1);
    int base = osr[n], cnt = csr[n];
    float a0 = 0.f, a1 = 0.f;
    int i = 0;
    for (; i + 4 <= cnt; i += 4) {
        int d0 = goff + sdst[base + i],     d1 = goff + sdst[base + i + 1];
        int d2 = goff + sdst[base + i + 2], d3 = goff + sdst[base + i + 3];
        u32 u0 = s1b32[(size_t)d0 * 50 + lane];
        u32 u1 = s1b32[(size_t)d1 * 50 + lane];
        u32 u2 = s1b32[(size_t)d2 * 50 + lane];
        u32 u3 = s1b32[(size_t)d3 * 50 + lane];
        a0 += (blo(u0) + blo(u1)) + (blo(u2) + blo(u3));
        a1 += (bhi(u0) + bhi(u1)) + (bhi(u2) + bhi(u3));
    }
    for (; i < cnt; i++) {
        int d0 = goff + sdst[base + i];
        u32 u0 = s1b32[(size_t)d0 * 50 + lane];
        a0 += blo(u0); a1 += bhi(u0);
    }
    t1b32[(size_t)n * 50 + lane] = pk2(a0, a1);
}

// --- gram via MFMA: C = s1^T [t1 | h | s1] (100 x 232); bf16, 4 slabs.
__global__ __launch_bounds__(512, 4) void k_gram(const u32* __restrict__ s1b32, const u32* __restrict__ t1b32,
                                                 const u32* __restrict__ hb32, float* __restrict__ Cp) {
    __shared__ u16 sZ[2][ZTR * ZTS];         // 2 x 21.1 KB
    int g = blockIdx.x >> 2, slab = blockIdx.x & 3;
    int nbase = g * NN + slab * 128;         // 4 chunks of 32 rows
    int tid = threadIdx.x;
    int wave = tid >> 6, lane = tid & 63;
    int mt = wave & 3;                       // output-row tile: k = mt*32 + row
    int nt0 = (wave >> 2) * 4;               // this wave: nt0..nt0+3
    int lc = lane & 31, half = lane >> 5;

    f32x16 acc[4];
#pragma unroll
    for (int t = 0; t < 4; t++)
#pragma unroll
        for (int r = 0; r < 16; r++) acc[t][r] = 0.f;

    // zero the padding rows of both buffers (channels 232..263)
    for (int i = tid; i < 32 * ZTS; i += 512) {
        int r = 232 + i / ZTS, c = i % ZTS;
        sZ[0][r * ZTS + c] = 0; sZ[1][r * ZTS + c] = 0;
    }
    // ---- stage chunk 0 into buffer 0 (transposing: uint2 = 4 channels of row n)
#pragma unroll
    for (int j = 0; j < 4; j++) {
        int i = tid + j * 512;
        if (i < 32 * 58) {
            int r = i / 58, q = i - r * 58;
            int n = nbase + r;
            uint2 v; int ch0;
            if (q < 25)      { v = ((const uint2*)(t1b32 + (size_t)n * 50))[q];      ch0 = 4 * q; }
            else if (q < 33) { v = ((const uint2*)(hb32  + (size_t)n * 16))[q - 25]; ch0 = 100 + 4 * (q - 25); }
            else             { v = ((const uint2*)(s1b32 + (size_t)n * 50))[q - 33]; ch0 = 132 + 4 * (q - 33); }
            sZ[0][(ch0    ) * ZTS + r] = (u16)(v.x & 0xffffu);
            sZ[0][(ch0 + 1) * ZTS + r] = (u16)(v.x >> 16);
            sZ[0][(ch0 + 2) * ZTS + r] = (u16)(v.y & 0xffffu);
            sZ[0][(ch0 + 3) * ZTS + r] = (u16)(v.y >> 16);
        }
    }
    __syncthreads();

    for (int nt = 0; nt < 4; nt++) {
        // ---- prefetch chunk nt+1 into registers
        uint2 pre[4];
        if (nt < 3) {
#pragma unroll
            for (int j = 0; j < 4; j++) {
                int i = tid + j * 512;
                if (i < 32 * 58) {
                    int r = i / 58, q = i - r * 58;
                    int n = nbase + (nt + 1) * 32 + r;
                    uint2 v;
                    if (q < 25)      v = ((const uint2*)(t1b32 + (size_t)n * 50))[q];
                    else if (q < 33) v = ((const uint2*)(hb32  + (size_t)n * 16))[q - 25];
                    else             v = ((const uint2*)(s1b32 + (size_t)n * 50))[q - 33];
                    pre[j] = v;
                }
            }
        }
        // ---- MFMA on current buffer
        const u16* zb = sZ[nt & 1];
#pragma unroll
        for (int mf = 0; mf < 2; mf++) {
            bf16x8 af = *(const bf16x8*)&zb[(132 + mt * 32 + lc) * ZTS + mf * 16 + half * 8];
#pragma unroll
            for (int t = 0; t < 4; t++) {
                bf16x8 bfv = *(const bf16x8*)&zb[((nt0 + t) * 32 + lc) * ZTS + mf * 16 + half * 8];
                acc[t] = __builtin_amdgcn_mfma_f32_32x32x16_bf16(af, bfv, acc[t], 0, 0, 0);
            }
        }
        // ---- commit prefetch to the other buffer
        if (nt < 3) {
            u16* zo = sZ[(nt + 1) & 1];
#pragma unroll
            for (int j = 0; j < 4; j++) {
                int i = tid + j * 512;
                if (i < 32 * 58) {
                    int r = i / 58, q = i - r * 58;
                    int ch0 = (q < 25) ? (4 * q) : ((q < 33) ? (100 + 4 * (q - 25)) : (132 + 4 * (q - 33)));
                    zo[(ch0    ) * ZTS + r] = (u16)(pre[j].x & 0xffffu);
                    zo[(ch0 + 1) * ZTS + r] = (u16)(pre[j].x >> 16);
                    zo[(ch0 + 2) * ZTS + r] = (u16)(pre[j].y & 0xffffu);
                    zo[(ch0 + 3) * ZTS + r] = (u16)(pre[j].y >> 16);
                }
            }
        }
        __syncthreads();
    }
    // ---- epilogue: C/D layout col=lane&31, row=(reg&3)+8*(reg>>2)+4*(lane>>5)
    float* outp = Cp + ((size_t)slab * TB + g) * (KP1 * 232);
#pragma unroll
    for (int t = 0; t < 4; t++) {
        int l = (nt0 + t) * 32 + lc;
        if (l < 232) {
#pragma unroll
            for (int r = 0; r < 16; r++) {
                int k = mt * 32 + (r & 3) + 8 * (r >> 2) + 4 * half;
                if (k < KP1) outp[k * 232 + l] = acc[t][r];
            }
        }
    }
}

// ---- finalize stage 1: coalesced float4 slab sweep; losses; normalize; P1
__global__ __launch_bounds__(256) void k_fin1(const float* __restrict__ Cp, const float* __restrict__ den1,
                                              float* __restrict__ A1n, float* __restrict__ P1,
                                              float* __restrict__ aux) {
    __shared__ float sA[KP1 * KP1];          // 40 KB
    __shared__ float red[256];
    __shared__ float rs2[256];
    __shared__ float sdv[KP1];
    int g = blockIdx.x, tid = threadIdx.x;
    const float* b0 = Cp + (size_t)g * (KP1 * 232);
    const size_t SLAB = (size_t)TB * (KP1 * 232);
    float ssq = 0.f, trss = 0.f, troa = 0.f;
    // phase 1: sweep 100 rows x 58 float4 cols, coalesced; sum 4 slabs in flight
    for (int idx = tid; idx < KP1 * 58; idx += 256) {
        int k = idx / 58, q = idx - k * 58;
        size_t off = (size_t)k * 232 + q * 4;
        float4 v0 = *(const float4*)(b0 + off);
        float4 v1 = *(const float4*)(b0 + SLAB + off);
        float4 v2 = *(const float4*)(b0 + 2 * SLAB + off);
        float4 v3 = *(const float4*)(b0 + 3 * SLAB + off);
        float4 s;
        s.x = (v0.x + v1.x) + (v2.x + v3.x);
        s.y = (v0.y + v1.y) + (v2.y + v3.y);
        s.z = (v0.z + v1.z) + (v2.z + v3.z);
        s.w = (v0.w + v1.w) + (v2.w + v3.w);
        int c = q * 4;
        if (c < 100) {                        // out_adj block
            *(float4*)&sA[k * KP1 + c] = s;
            if (k >= c && k < c + 4) troa += ((const float*)&s)[k - c];
        } else if (c < 132) {                 // pooled features -> P1 direct
            *(float4*)&P1[((size_t)g * KP1 + k) * HH + (c - 100)] = s;
        } else {                              // ss block: reduce only
            ssq += s.x * s.x + s.y * s.y + s.z * s.z + s.w * s.w;
            int l0 = c - 132;
            if (k >= l0 && k < l0 + 4) trss += ((const float*)&s)[k - l0];
        }
    }
    // block reductions for ssq / trss / troa
    red[tid] = ssq; __syncthreads();
#pragma unroll
    for (int s = 128; s > 0; s >>= 1) { if (tid < s) red[tid] += red[tid + s]; __syncthreads(); }
    float ssqT = red[0]; __syncthreads();
    red[tid] = trss; __syncthreads();
#pragma unroll
    for (int s = 128; s > 0; s >>= 1) { if (tid < s) red[tid] += red[tid + s]; __syncthreads(); }
    float trssT = red[0]; __syncthreads();
    red[tid] = troa; __syncthreads();
#pragma unroll
    for (int s = 128; s > 0; s >>= 1) { if (tid < s) red[tid] += red[tid + s]; __syncthreads(); }
    float troaT = red[0]; __syncthreads();
    // phase 2: row sums (2 threads per row) -> sd
    if (tid < 200) {
        int k = tid >> 1, hf = tid & 1;
        const float* row = &sA[k * KP1 + hf * 50];
        float rs = 0.f;
        for (int l = 0; l < 50; l++) rs += row[l];
        rs2[tid] = rs;
    }
    __syncthreads();
    if (tid < KP1) {
        float rowsum = rs2[2 * tid] + rs2[2 * tid + 1] - sA[tid * KP1 + tid];
        sdv[tid] = sqrtf(rowsum) + 1e-15f;
    }
    if (tid == 0) {
        float ssF = sqrtf(ssqT);
        float o1 = sqrtf(fmaxf(2.f - 2.f * trssT / (ssF * 10.f), 0.f));  // sqrt(K1)=10
        aux[128 + g] = -(troaT / den1[g]) + o1;
    }
    __syncthreads();
    // phase 3: normalize out_adj, coalesced
    for (int i = tid; i < KP1 * KP1; i += 256) {
        int k = i / KP1, l = i - k * KP1;
        A1n[(size_t)g * (KP1 * KP1) + i] = (k == l) ? 0.f : sA[i] / (sdv[k] * sdv[l]);
    }
}

// ------- stage 2a: conv2 + pool2 (per graph); A read from global (L2)
__global__ __launch_bounds__(512) void k_s2a(const float* __restrict__ A1n, const float* __restrict__ P1,
                                             const float* __restrict__ relW, const float* __restrict__ relB,
                                             const float* __restrict__ rootW,
                                             const float* __restrict__ p2W, const float* __restrict__ p2B,
                                             float* __restrict__ P2, float* __restrict__ A2n,
                                             float* __restrict__ aux) {
    __shared__ float sX[KP1 * HH];           // x1p then x2
    __shared__ float sY[KP1 * HH];           // y = A @ x1p
    __shared__ float sS2[KP1 * KP2];
    __shared__ float sT2[KP1 * KP2];
    __shared__ float sA2[100], sB2[100], sdd[10], red[100];
    int g = blockIdx.x, tid = threadIdx.x;
    const float* Ag = A1n + (size_t)g * (KP1 * KP1);
    for (int i = tid; i < KP1 * HH; i += 512) sX[i] = P1[(size_t)g * (KP1 * HH) + i];
    __syncthreads();

    int n = tid >> 2, cq = tid & 3;          // 400 active threads for y / x2
    // y = A @ x1p
    if (tid < 400) {
        float yv[8];
#pragma unroll
        for (int j = 0; j < 8; j++) yv[j] = 0.f;
        for (int mq = 0; mq < 25; mq++) {
            float4 a4 = *(const float4*)&Ag[n * KP1 + mq * 4];
            const float* xb = &sX[(mq * 4) * HH + cq * 8];
            float aa[4] = {a4.x, a4.y, a4.z, a4.w};
#pragma unroll
            for (int mm = 0; mm < 4; mm++) {
                const float* xr = xb + mm * HH;
#pragma unroll
                for (int j = 0; j < 8; j++) yv[j] = fmaf(aa[mm], xr[j], yv[j]);
            }
        }
#pragma unroll
        for (int j = 0; j < 8; j++) sY[n * HH + cq * 8 + j] = yv[j];
    }
    __syncthreads();
    // x2 = relu(y @ relW + relB + x1p @ rootW)
    float x2v[8];
    if (tid < 400) {
#pragma unroll
        for (int j = 0; j < 8; j++) x2v[j] = relB[cq * 8 + j];
        for (int j = 0; j < 32; j++) {
            float yj = sY[n * HH + j];
            float xj = sX[n * HH + j];
            float4 r0 = *(const float4*)&relW[j * 32 + cq * 8];
            float4 r1v = *(const float4*)&relW[j * 32 + cq * 8 + 4];
            float4 q0 = *(const float4*)&rootW[j * 32 + cq * 8];
            float4 q1 = *(const float4*)&rootW[j * 32 + cq * 8 + 4];
            x2v[0] += yj * r0.x + xj * q0.x;  x2v[1] += yj * r0.y + xj * q0.y;
            x2v[2] += yj * r0.z + xj * q0.z;  x2v[3] += yj * r0.w + xj * q0.w;
            x2v[4] += yj * r1v.x + xj * q1.x; x2v[5] += yj * r1v.y + xj * q1.y;
            x2v[6] += yj * r1v.z + xj * q1.z; x2v[7] += yj * r1v.w + xj * q1.w;
        }
    }
    __syncthreads();
    if (tid < 400) {
#pragma unroll
        for (int j = 0; j < 8; j++) sX[n * HH + cq * 8 + j] = fmaxf(x2v[j], 0.f);
    }
    __syncthreads();
    // s2 = softmax(x2 @ p2W + p2B); d2 and den2 partials
    if (tid < KP1) {
        float lg[10];
#pragma unroll
        for (int j = 0; j < 10; j++) lg[j] = p2B[j];
        for (int c = 0; c < 32; c++) {
            float xv = sX[tid * HH + c];
#pragma unroll
            for (int j = 0; j < 10; j++) lg[j] = fmaf(xv, p2W[c * 10 + j], lg[j]);
        }
        float mx = lg[0];
#pragma unroll
        for (int j = 1; j < 10; j++) mx = fmaxf(mx, lg[j]);
        float se = 0.f;
#pragma unroll
        for (int j = 0; j < 10; j++) { lg[j] = __expf(lg[j] - mx); se += lg[j]; }
        float inv = 1.f / se, sq = 0.f;
#pragma unroll
        for (int j = 0; j < 10; j++) { float sv = lg[j] * inv; sS2[tid * 10 + j] = sv; sq += sv * sv; }
        float d2 = 0.f;
        for (int mq = 0; mq < 25; mq++) {
            float4 a4 = *(const float4*)&Ag[tid * KP1 + mq * 4];
            d2 += a4.x + a4.y + a4.z + a4.w;
        }
        red[tid] = d2 * sq;
    }
    __syncthreads();
    // t2 = A @ s2 ; P2 = s2^T x2
    for (int p = tid; p < KP1 * KP2; p += 512) {
        int n2 = p / 10, jj = p % 10;
        float a = 0.f;
        for (int m = 0; m < KP1; m++) a = fmaf(Ag[n2 * KP1 + m], sS2[m * 10 + jj], a);
        sT2[p] = a;
    }
    if (tid < KP2 * HH) {
        int k = tid >> 5, cc = tid & 31;
        float a = 0.f;
        for (int n2 = 0; n2 < KP1; n2++) a = fmaf(sS2[n2 * 10 + k], sX[n2 * HH + cc], a);
        P2[(size_t)g * (KP2 * HH) + tid] = a;
    }
    __syncthreads();
    // oa2, ss2
    if (tid < 100) {
        int k = tid / 10, l = tid % 10;
        float oa = 0.f, ss = 0.f;
        for (int n2 = 0; n2 < KP1; n2++) {
            float sk = sS2[n2 * 10 + k];
            oa = fmaf(sk, sT2[n2 * 10 + l], oa);
            ss = fmaf(sk, sS2[n2 * 10 + l], ss);
        }
        sA2[tid] = oa; sB2[tid] = ss;
    }
    __syncthreads();
    if (tid == 0) {
        float den2 = 0.f;
        for (int i = 0; i < 100; i++) den2 += red[i];
        float troa = 0.f, trss = 0.f, ssq = 0.f;
        for (int k = 0; k < 10; k++) { troa += sA2[k * 10 + k]; trss += sB2[k * 10 + k]; }
        for (int i = 0; i < 100; i++) ssq += sB2[i] * sB2[i];
        float o2 = sqrtf(fmaxf(2.f - 2.f * trss / (sqrtf(ssq) * 3.16227766f), 0.f)); // sqrt(10)
        aux[256 + g] = -(troa / den2) + o2;
    }
    if (tid < 10) {
        float rs = 0.f;
        for (int l = 0; l < 10; l++) if (l != tid) rs += sA2[tid * 10 + l];
        sdd[tid] = sqrtf(rs) + 1e-15f;
    }
    __syncthreads();
    if (tid < 100) {
        int k = tid / 10, l = tid % 10;
        A2n[(size_t)g * 100 + tid] = (k == l) ? 0.f : sA2[tid] / (sdd[k] * sdd[l]);
    }
}

// ---------------- stage 2b: conv3 + mean + MLP head + log_softmax
__global__ __launch_bounds__(64) void k_s2b(const float* __restrict__ P2, const float* __restrict__ A2n,
                                            const float* __restrict__ relW3, const float* __restrict__ relb3,
                                            const float* __restrict__ rootW3,
                                            const float* __restrict__ l1W, const float* __restrict__ l1b,
                                            const float* __restrict__ l2W, const float* __restrict__ l2b,
                                            float* __restrict__ out) {
    __shared__ float sP[KP2 * HH], sA2[100], sY3[KP2 * HH], sG[32], sG1[32], sL[10], sLse;
    int g = blockIdx.x, tid = threadIdx.x;
    for (int i = tid; i < KP2 * HH; i += 64) sP[i] = P2[(size_t)g * (KP2 * HH) + i];
    for (int i = tid; i < 100; i += 64) sA2[i] = A2n[(size_t)g * 100 + i];
    if (tid < 32) sG[tid] = 0.f;
    __syncthreads();
    for (int p = tid; p < KP2 * HH; p += 64) {
        int k = p >> 5, cc = p & 31;
        float a = 0.f;
#pragma unroll
        for (int m = 0; m < 10; m++) a = fmaf(sA2[k * 10 + m], sP[m * HH + cc], a);
        sY3[p] = a;
    }
    __syncthreads();
    for (int p = tid; p < KP2 * HH; p += 64) {
        int k = p >> 5, cc = p & 31;
        float v = relb3[cc];
        for (int j = 0; j < 32; j++)
            v += sY3[k * HH + j] * relW3[j * 32 + cc] + sP[k * HH + j] * rootW3[j * 32 + cc];
        atomicAdd(&sG[cc], v * 0.1f);        // mean over 10 nodes
    }
    __syncthreads();
    if (tid < 32) {
        float v = l1b[tid];
        for (int j = 0; j < 32; j++) v = fmaf(sG[j], l1W[j * 32 + tid], v);
        sG1[tid] = fmaxf(v, 0.f);
    }
    __syncthreads();
    if (tid < 10) {
        float v = l2b[tid];
        for (int j = 0; j < 32; j++) v = fmaf(sG1[j], l2W[j * 10 + tid], v);
        sL[tid] = v;
    }
    __syncthreads();
    if (tid == 0) {
        float mx = sL[0];
        for (int j = 1; j < 10; j++) mx = fmaxf(mx, sL[j]);
        float se = 0.f;
        for (int j = 0; j < 10; j++) se += expf(sL[j] - mx);
        sLse = mx + logf(se);
    }
    __syncthreads();
    if (tid < 10) out[(size_t)g * 10 + tid] = sL[tid] - sLse;
}

// ------------------------------------------------------ total loss
__global__ void k_loss(const float* __restrict__ aux, float* __restrict__ out) {
    __shared__ float red[128];
    int tid = threadIdx.x;
    red[tid] = aux[128 + tid] + aux[256 + tid];
    __syncthreads();
#pragma unroll
    for (int s = 64; s > 0; s >>= 1) { if (tid < s) red[tid] += red[tid + s]; __syncthreads(); }
    if (tid == 0) out[1280] = red[0] * (1.f / 128.f);
}

extern "C" void kernel_launch(void* const* d_in, const int* in_sizes, int n_in,
                              void* d_out, int out_size, void* d_ws, size_t ws_size,
                              hipStream_t stream) {
    const float* x    = (const float*)d_in[0];
    const int*   ei   = (const int*)d_in[1];
    const float* c1W  = (const float*)d_in[3];
    const float* c1b  = (const float*)d_in[4];
    const float* p1W  = (const float*)d_in[5];
    const float* p1b  = (const float*)d_in[6];
    const float* relW2  = (const float*)d_in[7];
    const float* relb2  = (const float*)d_in[8];
    const float* rootW2 = (const float*)d_in[9];
    const float* p2W  = (const float*)d_in[10];
    const float* p2b  = (const float*)d_in[11];
    const float* relW3  = (const float*)d_in[12];
    const float* relb3  = (const float*)d_in[13];
    const float* rootW3 = (const float*)d_in[14];
    const float* l1W  = (const float*)d_in[15];
    const float* l1b  = (const float*)d_in[16];
    const float* l2W  = (const float*)d_in[17];
    const float* l2b  = (const float*)d_in[18];
    float* out = (float*)d_out;

    // ---- workspace layout
    int*  cnt_src = (int*)d_ws;                       // NT
    int*  cnt_dst = cnt_src + NT;                     // NT
    int*  off_src = cnt_dst + NT;                     // NT
    int*  off_dst = off_src + NT;                     // NT
    u16*  srt_dst = (u16*)(off_dst + NT);             // ET u16 (src-sorted, stores local dst)
    u16*  srt_src = srt_dst + ET;                     // ET u16 (dst-sorted, stores local src)
    float* dis = (float*)(srt_src + ET);              // NT
    u32*  xwb  = (u32*)(dis + NT);                    // NT*16 (bf16 x2)
    u32*  hb   = xwb + (size_t)NT * 16;               // NT*16
    u32*  s1b  = hb + (size_t)NT * 16;                // NT*50
    u32*  t1b  = s1b + (size_t)NT * 50;               // NT*50
    float* Cp   = (float*)(t1b + (size_t)NT * 50);    // 4*TB*KP1*232
    float* A1n  = Cp + (size_t)4 * TB * (KP1 * 232);  // TB*KP1*KP1
    float* P1   = A1n + (size_t)TB * KP1 * KP1;       // TB*KP1*HH
    float* P2   = P1 + (size_t)TB * KP1 * HH;         // TB*KP2*HH
    float* A2n  = P2 + (size_t)TB * KP2 * HH;         // TB*100
    float* aux  = A2n + (size_t)TB * 100;             // 1024: den1|loss1|loss2

    k_init<<<4, 256, 0, stream>>>(aux);
    k_sort<<<TB, 512, 0, stream>>>(ei, cnt_src, cnt_dst, off_src, off_dst, srt_dst, srt_src, dis);
    k_xw<<<(NT * HH) / 256, 256, 0, stream>>>(x, c1W, (u16*)xwb);
    k_gcng<<<NT / 16, 256, 0, stream>>>(srt_src, off_dst, cnt_dst, xwb, dis, c1b, hb);
    k_s1m<<<NT / 128, 256, 0, stream>>>(hb, p1W, p1b, cnt_src, (u16*)s1b, aux /*den1*/);
    k_t1g<<<NT / 4, 256, 0, stream>>>(srt_dst, off_src, cnt_src, s1b, t1b);
    k_gram<<<TB * 4, 512, 0, stream>>>(s1b, t1b, hb, Cp);
    k_fin1<<<TB, 256, 0, stream>>>(Cp, aux /*den1*/, A1n, P1, aux);
    k_s2a<<<TB, 512, 0, stream>>>(A1n, P1, relW2, relb2, rootW2, p2W, p2b, P2, A2n, aux);
    k_s2b<<<TB, 64, 0, stream>>>(P2, A2n, relW3, relb3, rootW3, l1W, l1b, l2W, l2b, out);
    k_loss<<<1, 128, 0, stream>>>(aux, out);
}

// Round 11
// 307.444 us; speedup vs baseline: 5.3424x; 1.1119x over previous
//
#include <hip/hip_runtime.h>
#include <hip/hip_bf16.h>

// Problem constants (match reference)
#define TB   128          // batch B
#define NN   512          // nodes per graph
#define INC  128          // IN_C
#define HH   32           // HID
#define KP1  100          // K1
#define KP2  10           // K2
#define OC   10           // OUT_C
#define EPER 8192         // edges per graph
#define NT   (TB*NN)      // 65536 total nodes
#define ET   (TB*EPER)    // 1048576 total edges
#define ZTR  264          // gram ZT rows: 232 Z-cols + 32 zero pad (partial MFMA tiles)
#define ZTS  40           // ZT row stride in u16 (80 B, 16B-aligned for ds_read_b128)
#define XTS  136          // k_xw2 row stride in u16 (272 B, 16B-aligned)

typedef unsigned int  u32;
typedef unsigned short u16;
typedef __attribute__((ext_vector_type(8))) short bf16x8;   // 8 bf16 = 4 VGPR (MFMA A/B frag)
typedef __attribute__((ext_vector_type(16))) float f32x16;  // MFMA C/D frag

// bf16 helpers (RNE encode; exact decode)
__device__ __forceinline__ u32 bfr(float f) {
    u32 b = __float_as_uint(f);
    return (b + 0x7fffu + ((b >> 16) & 1u)) >> 16;
}
__device__ __forceinline__ u32 pk2(float a, float b) { return bfr(a) | (bfr(b) << 16); }
__device__ __forceinline__ float blo(u32 u) { return __uint_as_float(u << 16); }
__device__ __forceinline__ float bhi(u32 u) { return __uint_as_float(u & 0xffff0000u); }

// ---------------------------------------------------------------- init (aux only)
__global__ void k_init(float* __restrict__ aux) {
    int i = blockIdx.x * 256 + threadIdx.x;
    if (i < 1024) aux[i] = 0.0f;              // den1 / loss1 / loss2 accumulators
}

// ---- fused per-graph counting sort: histogram + scan + scatter + dis, all in LDS
__global__ __launch_bounds__(512) void k_sort(const int* __restrict__ ei,
                                              int* __restrict__ cnt_src, int* __restrict__ cnt_dst,
                                              int* __restrict__ off_src, int* __restrict__ off_dst,
                                              u16* __restrict__ srt_dst, u16* __restrict__ srt_src,
                                              float* __restrict__ dis) {
    __shared__ int hs[NN], hd[NN], ps[NN], pd[NN];              // 8 KB
    __shared__ __align__(16) u16 sdl[EPER], ssl[EPER];          // 32 KB
    int g = blockIdx.x, tid = threadIdx.x, goff = g * NN;
    hs[tid] = 0; hd[tid] = 0;
    __syncthreads();
    const int* es = ei + (size_t)g * EPER;
    const int* ed = ei + ET + (size_t)g * EPER;
    // pass 1: histograms
    for (int e = tid; e < EPER; e += 512) {
        atomicAdd(&hs[es[e] - goff], 1);
        atomicAdd(&hd[ed[e] - goff], 1);
    }
    __syncthreads();
    int vs = hs[tid], vd = hd[tid];
    ps[tid] = vs; pd[tid] = vd; __syncthreads();
    // Hillis-Steele inclusive scan of both histograms
    for (int off = 1; off < NN; off <<= 1) {
        int xa = ps[tid], xb = pd[tid];
        if (tid >= off) { xa += ps[tid - off]; xb += pd[tid - off]; }
        __syncthreads(); ps[tid] = xa; pd[tid] = xb; __syncthreads();
    }
    int eso = ps[tid] - vs, edo = pd[tid] - vd;   // exclusive offsets, graph-local
    cnt_src[goff + tid] = vs;  cnt_dst[goff + tid] = vd;
    off_src[goff + tid] = g * EPER + eso;
    off_dst[goff + tid] = g * EPER + edo;
    dis[goff + tid] = rsqrtf(1.0f + (float)vd);   // +1 self loop
    __syncthreads();
    ps[tid] = eso; pd[tid] = edo;                 // reuse as cursors
    __syncthreads();
    // pass 2: scatter into LDS (u16 local node ids)
    for (int e = tid; e < EPER; e += 512) {
        int s = es[e] - goff, d = ed[e] - goff;
        int p = atomicAdd(&ps[s], 1); sdl[p] = (u16)d;   // src-sorted: store dst
        int q = atomicAdd(&pd[d], 1); ssl[q] = (u16)s;   // dst-sorted: store src
    }
    __syncthreads();
    // coalesced write-out (u32 pairs)
    u32* wd = (u32*)(srt_dst + (size_t)g * EPER);
    u32* ws = (u32*)(srt_src + (size_t)g * EPER);
    const u32* rd = (const u32*)sdl;
    const u32* rs = (const u32*)ssl;
    for (int i = tid; i < EPER / 2; i += 512) { wd[i] = rd[i]; ws[i] = rs[i]; }
}

// ------- xw via MFMA: xw = bf16(x @ conv1_W), block = 128 rows, K=128
__global__ __launch_bounds__(256) void k_xw2(const float* __restrict__ x, const float* __restrict__ W,
                                             u16* __restrict__ xwb) {
    __shared__ u16 sX[128 * XTS];            // 34.8 KB
    __shared__ u16 sW[32 * XTS];             // 8.7 KB
    int tid = threadIdx.x;
    int nbase = blockIdx.x * 128;
    // stage W^T bf16: sW[n][k] = W[k*32+n]
    for (int i = tid; i < INC * HH; i += 256) {
        int k = i >> 5, n = i & 31;
        sW[n * XTS + k] = (u16)bfr(W[i]);
    }
    // stage x rows bf16 (coalesced float4 read, packed u32 LDS write)
    for (int i = tid; i < 128 * 32; i += 256) {
        int r = i >> 5, q = i & 31;
        float4 v = ((const float4*)(x + (size_t)(nbase + r) * INC))[q];
        u32* dst = (u32*)&sX[r * XTS + q * 4];
        dst[0] = pk2(v.x, v.y);
        dst[1] = pk2(v.z, v.w);
    }
    __syncthreads();
    int wave = tid >> 6, lane = tid & 63;
    int lc = lane & 31, half = lane >> 5;
    f32x16 acc;
#pragma unroll
    for (int r = 0; r < 16; r++) acc[r] = 0.f;
#pragma unroll
    for (int kc = 0; kc < 8; kc++) {
        bf16x8 af  = *(const bf16x8*)&sX[(wave * 32 + lc) * XTS + kc * 16 + half * 8];
        bf16x8 bfv = *(const bf16x8*)&sW[lc * XTS + kc * 16 + half * 8];
        acc = __builtin_amdgcn_mfma_f32_32x32x16_bf16(af, bfv, acc, 0, 0, 0);
    }
    // C/D: col n = lc, row m = (r&3)+8*(r>>2)+4*half
#pragma unroll
    for (int r = 0; r < 16; r++) {
        int m = (r & 3) + 8 * (r >> 2) + 4 * half;
        int rowg = nbase + wave * 32 + m;
        xwb[(size_t)rowg * HH + lc] = (u16)bfr(acc[r]);
    }
}

// -------- GCN gather (bf16 xw, u16 indices): hb bf16 only
__global__ __launch_bounds__(256) void k_gcng(const u16* __restrict__ ssrc, const int* __restrict__ od,
                                              const int* __restrict__ cd, const u32* __restrict__ xwb32,
                                              const float* __restrict__ dis, const float* __restrict__ bias,
                                              u32* __restrict__ hb32) {
    int tid = threadIdx.x;
    int n = blockIdx.x * 16 + (tid >> 4), cp = tid & 15;  // cp -> channels 2cp,2cp+1
    int goff = n & ~(NN - 1);
    int base = od[n], cnt = cd[n];
    float dn = dis[n];
    u32 us = xwb32[(size_t)n * 16 + cp];
    float a0 = dn * blo(us), a1 = dn * bhi(us);           // self-loop term
    int i = 0;
    for (; i + 4 <= cnt; i += 4) {
        int s0 = goff + ssrc[base + i],     s1v = goff + ssrc[base + i + 1];
        int s2 = goff + ssrc[base + i + 2], s3  = goff + ssrc[base + i + 3];
        float d0 = dis[s0], d1 = dis[s1v], d2 = dis[s2], d3 = dis[s3];
        u32 u0 = xwb32[(size_t)s0 * 16 + cp];
        u32 u1 = xwb32[(size_t)s1v * 16 + cp];
        u32 u2 = xwb32[(size_t)s2 * 16 + cp];
        u32 u3 = xwb32[(size_t)s3 * 16 + cp];
        a0 += d0 * blo(u0) + d1 * blo(u1) + d2 * blo(u2) + d3 * blo(u3);
        a1 += d0 * bhi(u0) + d1 * bhi(u1) + d2 * bhi(u2) + d3 * bhi(u3);
    }
    for (; i < cnt; i++) {
        int s0 = goff + ssrc[base + i]; float d0 = dis[s0];
        u32 u0 = xwb32[(size_t)s0 * 16 + cp];
        a0 += d0 * blo(u0); a1 += d0 * bhi(u0);
    }
    float v0 = fmaxf(dn * a0 + bias[2 * cp], 0.f);
    float v1 = fmaxf(dn * a1 + bias[2 * cp + 1], 0.f);
    hb32[(size_t)n * 16 + cp] = pk2(v0, v1);
}

// ------- s1 via MFMA: logits = hb @ pool1_W + b, softmax in-register
__global__ __launch_bounds__(256) void k_s1m(const u32* __restrict__ hb32, const float* __restrict__ W,
                                             const float* __restrict__ bias, const int* __restrict__ csrc,
                                             u16* __restrict__ s1b, float* __restrict__ den1) {
    __shared__ u16 sH[128 * ZTS];            // 10.24 KB
    __shared__ u16 sW[128 * ZTS];            // 10.24 KB
    int tid = threadIdx.x;
    int nbase = blockIdx.x * 128;
    // stage W^T bf16: sW[n][k] = W[k*100+n]; coalesced read (n fastest)
    for (int i = tid; i < HH * KP1; i += 256) {
        int k = i / KP1, n = i - k * KP1;
        sW[n * ZTS + k] = (u16)bfr(W[i]);
    }
    // zero pad rows 100..127 (k 0..31 as 16 u32)
    for (int i = tid; i < 28 * 16; i += 256) {
        int n = 100 + (i >> 4), q = i & 15;
        ((u32*)sW)[n * (ZTS / 2) + q] = 0;
    }
    // stage hb rows (coalesced u32)
    for (int i = tid; i < 128 * 16; i += 256) {
        int r = i >> 4, q = i & 15;
        ((u32*)sH)[r * (ZTS / 2) + q] = hb32[(size_t)(nbase + r) * 16 + q];
    }
    __syncthreads();
    int wave = tid >> 6, lane = tid & 63;
    int lc = lane & 31, half = lane >> 5;
    f32x16 acc[4];
#pragma unroll
    for (int t = 0; t < 4; t++)
#pragma unroll
        for (int r = 0; r < 16; r++) acc[t][r] = 0.f;
#pragma unroll
    for (int kc = 0; kc < 2; kc++) {
        bf16x8 af = *(const bf16x8*)&sH[(wave * 32 + lc) * ZTS + kc * 16 + half * 8];
#pragma unroll
        for (int t = 0; t < 4; t++) {
            bf16x8 bfv = *(const bf16x8*)&sW[(t * 32 + lc) * ZTS + kc * 16 + half * 8];
            acc[t] = __builtin_amdgcn_mfma_f32_32x32x16_bf16(af, bfv, acc[t], 0, 0, 0);
        }
    }
    // bias + exp (overwrite acc with e); row sums via lc-butterfly
    float s[16], q[16];
#pragma unroll
    for (int r = 0; r < 16; r++) { s[r] = 0.f; q[r] = 0.f; }
#pragma unroll
    for (int t = 0; t < 4; t++) {
        int ch = t * 32 + lc;
        bool valid = ch < KP1;
        float bv = valid ? bias[ch] : 0.f;
#pragma unroll
        for (int r = 0; r < 16; r++) {
            float ev = valid ? __expf(acc[t][r] + bv) : 0.f;
            acc[t][r] = ev; s[r] += ev; q[r] = fmaf(ev, ev, q[r]);
        }
    }
#pragma unroll
    for (int off = 16; off >= 1; off >>= 1) {
#pragma unroll
        for (int r = 0; r < 16; r++) { s[r] += __shfl_xor(s[r], off); q[r] += __shfl_xor(q[r], off); }
    }
    float inv[16];
#pragma unroll
    for (int r = 0; r < 16; r++) inv[r] = 1.f / s[r];
    // store s1 bf16: row = (reg&3)+8*(reg>>2)+4*half (verified C/D layout), col = t*32+lc
#pragma unroll
    for (int t = 0; t < 4; t++) {
        int ch = t * 32 + lc;
        if (ch < KP1) {
#pragma unroll
            for (int r = 0; r < 16; r++) {
                int lr = (r & 3) + 8 * (r >> 2) + 4 * half;
                int rowg = nbase + wave * 32 + lr;
                s1b[(size_t)rowg * KP1 + ch] = (u16)bfr(acc[t][r] * inv[r]);
            }
        }
    }
    // den1: deg_out[row] * sum(s1^2) per row; lc==0 lanes hold replicated sums
    float contrib = 0.f;
    if (lc == 0) {
#pragma unroll
        for (int r = 0; r < 16; r++) {
            int lr = (r & 3) + 8 * (r >> 2) + 4 * half;
            int rowg = nbase + wave * 32 + lr;
            contrib += (float)csrc[rowg] * q[r] * inv[r] * inv[r];
        }
    }
    contrib += __shfl_xor(contrib, 32);
    if (lane == 0) atomicAdd(&den1[nbase >> 9], contrib);
}

// ------------- t1 gather (bf16, u16 indices): wave per node, lane owns 2 channels
__global__ __launch_bounds__(256) void k_t1g(const u16* __restrict__ sdst, const int* __restrict__ osr,
                                             const int* __restrict__ csr, const u32* __restrict__ s1b32,
                                             u32* __restrict__ t1b32) {
    int tid = threadIdx.x;
    int n = blockIdx.x * 4 + (tid >> 6), lane = tid & 63;
    if (lane >= 50) return;
    int goff = n & ~(NN - 1);
    int base = osr[n], cnt = csr[n];
    float a0 = 0.f, a1 = 0.f;
    int i = 0;
    for (; i + 4 <= cnt; i += 4) {
        int d0 = goff + sdst[base + i],     d1 = goff + sdst[base + i + 1];
        int d2 = goff + sdst[base + i + 2], d3 = goff + sdst[base + i + 3];
        u32 u0 = s1b32[(size_t)d0 * 50 + lane];
        u32 u1 = s1b32[(size_t)d1 * 50 + lane];
        u32 u2 = s1b32[(size_t)d2 * 50 + lane];
        u32 u3 = s1b32[(size_t)d3 * 50 + lane];
        a0 += (blo(u0) + blo(u1)) + (blo(u2) + blo(u3));
        a1 += (bhi(u0) + bhi(u1)) + (bhi(u2) + bhi(u3));
    }
    for (; i < cnt; i++) {
        int d0 = goff + sdst[base + i];
        u32 u0 = s1b32[(size_t)d0 * 50 + lane];
        a0 += blo(u0); a1 += bhi(u0);
    }
    t1b32[(size_t)n * 50 + lane] = pk2(a0, a1);
}

// --- gram via MFMA: C = s1^T [t1 | h | s1] (100 x 232); bf16, 4 slabs.
__global__ __launch_bounds__(512, 4) void k_gram(const u32* __restrict__ s1b32, const u32* __restrict__ t1b32,
                                                 const u32* __restrict__ hb32, float* __restrict__ Cp) {
    __shared__ u16 sZ[2][ZTR * ZTS];         // 2 x 21.1 KB
    int g = blockIdx.x >> 2, slab = blockIdx.x & 3;
    int nbase = g * NN + slab * 128;         // 4 chunks of 32 rows
    int tid = threadIdx.x;
    int wave = tid >> 6, lane = tid & 63;
    int mt = wave & 3;                       // output-row tile: k = mt*32 + row
    int nt0 = (wave >> 2) * 4;               // this wave: nt0..nt0+3
    int lc = lane & 31, half = lane >> 5;

    f32x16 acc[4];
#pragma unroll
    for (int t = 0; t < 4; t++)
#pragma unroll
        for (int r = 0; r < 16; r++) acc[t][r] = 0.f;

    // zero the padding rows of both buffers (channels 232..263)
    for (int i = tid; i < 32 * ZTS; i += 512) {
        int r = 232 + i / ZTS, c = i % ZTS;
        sZ[0][r * ZTS + c] = 0; sZ[1][r * ZTS + c] = 0;
    }
    // ---- stage chunk 0 into buffer 0 (transposing: uint2 = 4 channels of row n)
#pragma unroll
    for (int j = 0; j < 4; j++) {
        int i = tid + j * 512;
        if (i < 32 * 58) {
            int r = i / 58, q = i - r * 58;
            int n = nbase + r;
            uint2 v; int ch0;
            if (q < 25)      { v = ((const uint2*)(t1b32 + (size_t)n * 50))[q];      ch0 = 4 * q; }
            else if (q < 33) { v = ((const uint2*)(hb32  + (size_t)n * 16))[q - 25]; ch0 = 100 + 4 * (q - 25); }
            else             { v = ((const uint2*)(s1b32 + (size_t)n * 50))[q - 33]; ch0 = 132 + 4 * (q - 33); }
            sZ[0][(ch0    ) * ZTS + r] = (u16)(v.x & 0xffffu);
            sZ[0][(ch0 + 1) * ZTS + r] = (u16)(v.x >> 16);
            sZ[0][(ch0 + 2) * ZTS + r] = (u16)(v.y & 0xffffu);
            sZ[0][(ch0 + 3) * ZTS + r] = (u16)(v.y >> 16);
        }
    }
    __syncthreads();

    for (int nt = 0; nt < 4; nt++) {
        // ---- prefetch chunk nt+1 into registers
        uint2 pre[4];
        if (nt < 3) {
#pragma unroll
            for (int j = 0; j < 4; j++) {
                int i = tid + j * 512;
                if (i < 32 * 58) {
                    int r = i / 58, q = i - r * 58;
                    int n = nbase + (nt + 1) * 32 + r;
                    uint2 v;
                    if (q < 25)      v = ((const uint2*)(t1b32 + (size_t)n * 50))[q];
                    else if (q < 33) v = ((const uint2*)(hb32  + (size_t)n * 16))[q - 25];
                    else             v = ((const uint2*)(s1b32 + (size_t)n * 50))[q - 33];
                    pre[j] = v;
                }
            }
        }
        // ---- MFMA on current buffer
        const u16* zb = sZ[nt & 1];
#pragma unroll
        for (int mf = 0; mf < 2; mf++) {
            bf16x8 af = *(const bf16x8*)&zb[(132 + mt * 32 + lc) * ZTS + mf * 16 + half * 8];
#pragma unroll
            for (int t = 0; t < 4; t++) {
                bf16x8 bfv = *(const bf16x8*)&zb[((nt0 + t) * 32 + lc) * ZTS + mf * 16 + half * 8];
                acc[t] = __builtin_amdgcn_mfma_f32_32x32x16_bf16(af, bfv, acc[t], 0, 0, 0);
            }
        }
        // ---- commit prefetch to the other buffer
        if (nt < 3) {
            u16* zo = sZ[(nt + 1) & 1];
#pragma unroll
            for (int j = 0; j < 4; j++) {
                int i = tid + j * 512;
                if (i < 32 * 58) {
                    int r = i / 58, q = i - r * 58;
                    int ch0 = (q < 25) ? (4 * q) : ((q < 33) ? (100 + 4 * (q - 25)) : (132 + 4 * (q - 33)));
                    zo[(ch0    ) * ZTS + r] = (u16)(pre[j].x & 0xffffu);
                    zo[(ch0 + 1) * ZTS + r] = (u16)(pre[j].x >> 16);
                    zo[(ch0 + 2) * ZTS + r] = (u16)(pre[j].y & 0xffffu);
                    zo[(ch0 + 3) * ZTS + r] = (u16)(pre[j].y >> 16);
                }
            }
        }
        __syncthreads();
    }
    // ---- epilogue: C/D layout col=lane&31, row=(reg&3)+8*(reg>>2)+4*(lane>>5)
    float* outp = Cp + ((size_t)slab * TB + g) * (KP1 * 232);
#pragma unroll
    for (int t = 0; t < 4; t++) {
        int l = (nt0 + t) * 32 + lc;
        if (l < 232) {
#pragma unroll
            for (int r = 0; r < 16; r++) {
                int k = mt * 32 + (r & 3) + 8 * (r >> 2) + 4 * half;
                if (k < KP1) outp[k * 232 + l] = acc[t][r];
            }
        }
    }
}

// ---- finalize stage 1: coalesced float4 slab sweep; losses; normalize; P1
__global__ __launch_bounds__(256) void k_fin1(const float* __restrict__ Cp, const float* __restrict__ den1,
                                              float* __restrict__ A1n, float* __restrict__ P1,
                                              float* __restrict__ aux) {
    __shared__ float sA[KP1 * KP1];          // 40 KB
    __shared__ float red[256];
    __shared__ float rs2[256];
    __shared__ float sdv[KP1];
    int g = blockIdx.x, tid = threadIdx.x;
    const float* b0 = Cp + (size_t)g * (KP1 * 232);
    const size_t SLAB = (size_t)TB * (KP1 * 232);
    float ssq = 0.f, trss = 0.f, troa = 0.f;
    // phase 1: sweep 100 rows x 58 float4 cols, coalesced; sum 4 slabs in flight
    for (int idx = tid; idx < KP1 * 58; idx += 256) {
        int k = idx / 58, q = idx - k * 58;
        size_t off = (size_t)k * 232 + q * 4;
        float4 v0 = *(const float4*)(b0 + off);
        float4 v1 = *(const float4*)(b0 + SLAB + off);
        float4 v2 = *(const float4*)(b0 + 2 * SLAB + off);
        float4 v3 = *(const float4*)(b0 + 3 * SLAB + off);
        float4 s;
        s.x = (v0.x + v1.x) + (v2.x + v3.x);
        s.y = (v0.y + v1.y) + (v2.y + v3.y);
        s.z = (v0.z + v1.z) + (v2.z + v3.z);
        s.w = (v0.w + v1.w) + (v2.w + v3.w);
        int c = q * 4;
        if (c < 100) {                        // out_adj block
            *(float4*)&sA[k * KP1 + c] = s;
            if (k >= c && k < c + 4) troa += ((const float*)&s)[k - c];
        } else if (c < 132) {                 // pooled features -> P1 direct
            *(float4*)&P1[((size_t)g * KP1 + k) * HH + (c - 100)] = s;
        } else {                              // ss block: reduce only
            ssq += s.x * s.x + s.y * s.y + s.z * s.z + s.w * s.w;
            int l0 = c - 132;
            if (k >= l0 && k < l0 + 4) trss += ((const float*)&s)[k - l0];
        }
    }
    // block reductions for ssq / trss / troa
    red[tid] = ssq; __syncthreads();
#pragma unroll
    for (int s = 128; s > 0; s >>= 1) { if (tid < s) red[tid] += red[tid + s]; __syncthreads(); }
    float ssqT = red[0]; __syncthreads();
    red[tid] = trss; __syncthreads();
#pragma unroll
    for (int s = 128; s > 0; s >>= 1) { if (tid < s) red[tid] += red[tid + s]; __syncthreads(); }
    float trssT = red[0]; __syncthreads();
    red[tid] = troa; __syncthreads();
#pragma unroll
    for (int s = 128; s > 0; s >>= 1) { if (tid < s) red[tid] += red[tid + s]; __syncthreads(); }
    float troaT = red[0]; __syncthreads();
    // phase 2: row sums (2 threads per row) -> sd
    if (tid < 200) {
        int k = tid >> 1, hf = tid & 1;
        const float* row = &sA[k * KP1 + hf * 50];
        float rs = 0.f;
        for (int l = 0; l < 50; l++) rs += row[l];
        rs2[tid] = rs;
    }
    __syncthreads();
    if (tid < KP1) {
        float rowsum = rs2[2 * tid] + rs2[2 * tid + 1] - sA[tid * KP1 + tid];
        sdv[tid] = sqrtf(rowsum) + 1e-15f;
    }
    if (tid == 0) {
        float ssF = sqrtf(ssqT);
        float o1 = sqrtf(fmaxf(2.f - 2.f * trssT / (ssF * 10.f), 0.f));  // sqrt(K1)=10
        aux[128 + g] = -(troaT / den1[g]) + o1;
    }
    __syncthreads();
    // phase 3: normalize out_adj, coalesced
    for (int i = tid; i < KP1 * KP1; i += 256) {
        int k = i / KP1, l = i - k * KP1;
        A1n[(size_t)g * (KP1 * KP1) + i] = (k == l) ? 0.f : sA[i] / (sdv[k] * sdv[l]);
    }
}

// ------- stage 2a: conv2 + pool2 (per graph); A read from global (L2)
__global__ __launch_bounds__(512) void k_s2a(const float* __restrict__ A1n, const float* __restrict__ P1,
                                             const float* __restrict__ relW, const float* __restrict__ relB,
                                             const float* __restrict__ rootW,
                                             const float* __restrict__ p2W, const float* __restrict__ p2B,
                                             float* __restrict__ P2, float* __restrict__ A2n,
                                             float* __restrict__ aux) {
    __shared__ float sX[KP1 * HH];           // x1p then x2
    __shared__ float sY[KP1 * HH];           // y = A @ x1p
    __shared__ float sS2[KP1 * KP2];
    __shared__ float sT2[KP1 * KP2];
    __shared__ float sA2[100], sB2[100], sdd[10], red[100];
    int g = blockIdx.x, tid = threadIdx.x;
    const float* Ag = A1n + (size_t)g * (KP1 * KP1);
    for (int i = tid; i < KP1 * HH; i += 512) sX[i] = P1[(size_t)g * (KP1 * HH) + i];
    __syncthreads();

    int n = tid >> 2, cq = tid & 3;          // 400 active threads for y / x2
    // y = A @ x1p
    if (tid < 400) {
        float yv[8];
#pragma unroll
        for (int j = 0; j < 8; j++) yv[j] = 0.f;
        for (int mq = 0; mq < 25; mq++) {
            float4 a4 = *(const float4*)&Ag[n * KP1 + mq * 4];
            const float* xb = &sX[(mq * 4) * HH + cq * 8];
            float aa[4] = {a4.x, a4.y, a4.z, a4.w};
#pragma unroll
            for (int mm = 0; mm < 4; mm++) {
                const float* xr = xb + mm * HH;
#pragma unroll
                for (int j = 0; j < 8; j++) yv[j] = fmaf(aa[mm], xr[j], yv[j]);
            }
        }
#pragma unroll
        for (int j = 0; j < 8; j++) sY[n * HH + cq * 8 + j] = yv[j];
    }
    __syncthreads();
    // x2 = relu(y @ relW + relB + x1p @ rootW)
    float x2v[8];
    if (tid < 400) {
#pragma unroll
        for (int j = 0; j < 8; j++) x2v[j] = relB[cq * 8 + j];
        for (int j = 0; j < 32; j++) {
            float yj = sY[n * HH + j];
            float xj = sX[n * HH + j];
            float4 r0 = *(const float4*)&relW[j * 32 + cq * 8];
            float4 r1v = *(const float4*)&relW[j * 32 + cq * 8 + 4];
            float4 q0 = *(const float4*)&rootW[j * 32 + cq * 8];
            float4 q1 = *(const float4*)&rootW[j * 32 + cq * 8 + 4];
            x2v[0] += yj * r0.x + xj * q0.x;  x2v[1] += yj * r0.y + xj * q0.y;
            x2v[2] += yj * r0.z + xj * q0.z;  x2v[3] += yj * r0.w + xj * q0.w;
            x2v[4] += yj * r1v.x + xj * q1.x; x2v[5] += yj * r1v.y + xj * q1.y;
            x2v[6] += yj * r1v.z + xj * q1.z; x2v[7] += yj * r1v.w + xj * q1.w;
        }
    }
    __syncthreads();
    if (tid < 400) {
#pragma unroll
        for (int j = 0; j < 8; j++) sX[n * HH + cq * 8 + j] = fmaxf(x2v[j], 0.f);
    }
    __syncthreads();
    // s2 = softmax(x2 @ p2W + p2B); d2 and den2 partials
    if (tid < KP1) {
        float lg[10];
#pragma unroll
        for (int j = 0; j < 10; j++) lg[j] = p2B[j];
        for (int c = 0; c < 32; c++) {
            float xv = sX[tid * HH + c];
#pragma unroll
            for (int j = 0; j < 10; j++) lg[j] = fmaf(xv, p2W[c * 10 + j], lg[j]);
        }
        float mx = lg[0];
#pragma unroll
        for (int j = 1; j < 10; j++) mx = fmaxf(mx, lg[j]);
        float se = 0.f;
#pragma unroll
        for (int j = 0; j < 10; j++) { lg[j] = __expf(lg[j] - mx); se += lg[j]; }
        float inv = 1.f / se, sq = 0.f;
#pragma unroll
        for (int j = 0; j < 10; j++) { float sv = lg[j] * inv; sS2[tid * 10 + j] = sv; sq += sv * sv; }
        float d2 = 0.f;
        for (int mq = 0; mq < 25; mq++) {
            float4 a4 = *(const float4*)&Ag[tid * KP1 + mq * 4];
            d2 += a4.x + a4.y + a4.z + a4.w;
        }
        red[tid] = d2 * sq;
    }
    __syncthreads();
    // t2 = A @ s2 ; P2 = s2^T x2
    for (int p = tid; p < KP1 * KP2; p += 512) {
        int n2 = p / 10, jj = p % 10;
        float a = 0.f;
        for (int m = 0; m < KP1; m++) a = fmaf(Ag[n2 * KP1 + m], sS2[m * 10 + jj], a);
        sT2[p] = a;
    }
    if (tid < KP2 * HH) {
        int k = tid >> 5, cc = tid & 31;
        float a = 0.f;
        for (int n2 = 0; n2 < KP1; n2++) a = fmaf(sS2[n2 * 10 + k], sX[n2 * HH + cc], a);
        P2[(size_t)g * (KP2 * HH) + tid] = a;
    }
    __syncthreads();
    // oa2, ss2
    if (tid < 100) {
        int k = tid / 10, l = tid % 10;
        float oa = 0.f, ss = 0.f;
        for (int n2 = 0; n2 < KP1; n2++) {
            float sk = sS2[n2 * 10 + k];
            oa = fmaf(sk, sT2[n2 * 10 + l], oa);
            ss = fmaf(sk, sS2[n2 * 10 + l], ss);
        }
        sA2[tid] = oa; sB2[tid] = ss;
    }
    __syncthreads();
    if (tid == 0) {
        float den2 = 0.f;
        for (int i = 0; i < 100; i++) den2 += red[i];
        float troa = 0.f, trss = 0.f, ssq = 0.f;
        for (int k = 0; k < 10; k++) { troa += sA2[k * 10 + k]; trss += sB2[k * 10 + k]; }
        for (int i = 0; i < 100; i++) ssq += sB2[i] * sB2[i];
        float o2 = sqrtf(fmaxf(2.f - 2.f * trss / (sqrtf(ssq) * 3.16227766f), 0.f)); // sqrt(10)
        aux[256 + g] = -(troa / den2) + o2;
    }
    if (tid < 10) {
        float rs = 0.f;
        for (int l = 0; l < 10; l++) if (l != tid) rs += sA2[tid * 10 + l];
        sdd[tid] = sqrtf(rs) + 1e-15f;
    }
    __syncthreads();
    if (tid < 100) {
        int k = tid / 10, l = tid % 10;
        A2n[(size_t)g * 100 + tid] = (k == l) ? 0.f : sA2[tid] / (sdd[k] * sdd[l]);
    }
}

// ---------------- stage 2b: conv3 + mean + MLP head + log_softmax
__global__ __launch_bounds__(64) void k_s2b(const float* __restrict__ P2, const float* __restrict__ A2n,
                                            const float* __restrict__ relW3, const float* __restrict__ relb3,
                                            const float* __restrict__ rootW3,
                                            const float* __restrict__ l1W, const float* __restrict__ l1b,
                                            const float* __restrict__ l2W, const float* __restrict__ l2b,
                                            float* __restrict__ out) {
    __shared__ float sP[KP2 * HH], sA2[100], sY3[KP2 * HH], sG[32], sG1[32], sL[10], sLse;
    int g = blockIdx.x, tid = threadIdx.x;
    for (int i = tid; i < KP2 * HH; i += 64) sP[i] = P2[(size_t)g * (KP2 * HH) + i];
    for (int i = tid; i < 100; i += 64) sA2[i] = A2n[(size_t)g * 100 + i];
    if (tid < 32) sG[tid] = 0.f;
    __syncthreads();
    for (int p = tid; p < KP2 * HH; p += 64) {
        int k = p >> 5, cc = p & 31;
        float a = 0.f;
#pragma unroll
        for (int m = 0; m < 10; m++) a = fmaf(sA2[k * 10 + m], sP[m * HH + cc], a);
        sY3[p] = a;
    }
    __syncthreads();
    for (int p = tid; p < KP2 * HH; p += 64) {
        int k = p >> 5, cc = p & 31;
        float v = relb3[cc];
        for (int j = 0; j < 32; j++)
            v += sY3[k * HH + j] * relW3[j * 32 + cc] + sP[k * HH + j] * rootW3[j * 32 + cc];
        atomicAdd(&sG[cc], v * 0.1f);        // mean over 10 nodes
    }
    __syncthreads();
    if (tid < 32) {
        float v = l1b[tid];
        for (int j = 0; j < 32; j++) v = fmaf(sG[j], l1W[j * 32 + tid], v);
        sG1[tid] = fmaxf(v, 0.f);
    }
    __syncthreads();
    if (tid < 10) {
        float v = l2b[tid];
        for (int j = 0; j < 32; j++) v = fmaf(sG1[j], l2W[j * 10 + tid], v);
        sL[tid] = v;
    }
    __syncthreads();
    if (tid == 0) {
        float mx = sL[0];
        for (int j = 1; j < 10; j++) mx = fmaxf(mx, sL[j]);
        float se = 0.f;
        for (int j = 0; j < 10; j++) se += expf(sL[j] - mx);
        sLse = mx + logf(se);
    }
    __syncthreads();
    if (tid < 10) out[(size_t)g * 10 + tid] = sL[tid] - sLse;
}

// ------------------------------------------------------ total loss
__global__ void k_loss(const float* __restrict__ aux, float* __restrict__ out) {
    __shared__ float red[128];
    int tid = threadIdx.x;
    red[tid] = aux[128 + tid] + aux[256 + tid];
    __syncthreads();
#pragma unroll
    for (int s = 64; s > 0; s >>= 1) { if (tid < s) red[tid] += red[tid + s]; __syncthreads(); }
    if (tid == 0) out[1280] = red[0] * (1.f / 128.f);
}

extern "C" void kernel_launch(void* const* d_in, const int* in_sizes, int n_in,
                              void* d_out, int out_size, void* d_ws, size_t ws_size,
                              hipStream_t stream) {
    const float* x    = (const float*)d_in[0];
    const int*   ei   = (const int*)d_in[1];
    const float* c1W  = (const float*)d_in[3];
    const float* c1b  = (const float*)d_in[4];
    const float* p1W  = (const float*)d_in[5];
    const float* p1b  = (const float*)d_in[6];
    const float* relW2  = (const float*)d_in[7];
    const float* relb2  = (const float*)d_in[8];
    const float* rootW2 = (const float*)d_in[9];
    const float* p2W  = (const float*)d_in[10];
    const float* p2b  = (const float*)d_in[11];
    const float* relW3  = (const float*)d_in[12];
    const float* relb3  = (const float*)d_in[13];
    const float* rootW3 = (const float*)d_in[14];
    const float* l1W  = (const float*)d_in[15];
    const float* l1b  = (const float*)d_in[16];
    const float* l2W  = (const float*)d_in[17];
    const float* l2b  = (const float*)d_in[18];
    float* out = (float*)d_out;

    // ---- workspace layout
    int*  cnt_src = (int*)d_ws;                       // NT
    int*  cnt_dst = cnt_src + NT;                     // NT
    int*  off_src = cnt_dst + NT;                     // NT
    int*  off_dst = off_src + NT;                     // NT
    u16*  srt_dst = (u16*)(off_dst + NT);             // ET u16 (src-sorted, stores local dst)
    u16*  srt_src = srt_dst + ET;                     // ET u16 (dst-sorted, stores local src)
    float* dis = (float*)(srt_src + ET);              // NT
    u32*  xwb  = (u32*)(dis + NT);                    // NT*16 (bf16 x2)
    u32*  hb   = xwb + (size_t)NT * 16;               // NT*16
    u32*  s1b  = hb + (size_t)NT * 16;                // NT*50
    u32*  t1b  = s1b + (size_t)NT * 50;               // NT*50
    float* Cp   = (float*)(t1b + (size_t)NT * 50);    // 4*TB*KP1*232
    float* A1n  = Cp + (size_t)4 * TB * (KP1 * 232);  // TB*KP1*KP1
    float* P1   = A1n + (size_t)TB * KP1 * KP1;       // TB*KP1*HH
    float* P2   = P1 + (size_t)TB * KP1 * HH;         // TB*KP2*HH
    float* A2n  = P2 + (size_t)TB * KP2 * HH;         // TB*100
    float* aux  = A2n + (size_t)TB * 100;             // 1024: den1|loss1|loss2

    k_init<<<4, 256, 0, stream>>>(aux);
    k_sort<<<TB, 512, 0, stream>>>(ei, cnt_src, cnt_dst, off_src, off_dst, srt_dst, srt_src, dis);
    k_xw2<<<NT / 128, 256, 0, stream>>>(x, c1W, (u16*)xwb);
    k_gcng<<<NT / 16, 256, 0, stream>>>(srt_src, off_dst, cnt_dst, xwb, dis, c1b, hb);
    k_s1m<<<NT / 128, 256, 0, stream>>>(hb, p1W, p1b, cnt_src, (u16*)s1b, aux /*den1*/);
    k_t1g<<<NT / 4, 256, 0, stream>>>(srt_dst, off_src, cnt_src, s1b, t1b);
    k_gram<<<TB * 4, 512, 0, stream>>>(s1b, t1b, hb, Cp);
    k_fin1<<<TB, 256, 0, stream>>>(Cp, aux /*den1*/, A1n, P1, aux);
    k_s2a<<<TB, 512, 0, stream>>>(A1n, P1, relW2, relb2, rootW2, p2W, p2b, P2, A2n, aux);
    k_s2b<<<TB, 64, 0, stream>>>(P2, A2n, relW3, relb3, rootW3, l1W, l1b, l2W, l2b, out);
    k_loss<<<1, 128, 0, stream>>>(aux, out);
}